// Round 4
// baseline (1246.156 us; speedup 1.0000x reference)
//
#include <hip/hip_runtime.h>

#define TSEQ 2048
#define DM   768
#define NH   12
#define NKV  4
#define HD   64
#define FFD  2048
#define NL   4
#define VOC  32000
#define QKVN 1280   // 768 q + 256 k + 256 v

typedef __attribute__((ext_vector_type(8))) short short8;
typedef __attribute__((ext_vector_type(4))) float f32x4;

__device__ __forceinline__ unsigned short f2b(float f) {
  unsigned int u = __float_as_uint(f);
  u += 0x7fffu + ((u >> 16) & 1u);
  return (unsigned short)(u >> 16);
}
__device__ __forceinline__ float b2f(unsigned short u) {
  return __uint_as_float(((unsigned int)u) << 16);
}
__device__ __forceinline__ unsigned int packbf(float a, float b) {
  return (unsigned int)f2b(a) | ((unsigned int)f2b(b) << 16);
}

// direct global->LDS async copy, 16B per lane; lds dest must be wave-uniform,
// HW adds lane*16 (learn_hip m97/m104, rule #21: linear LDS, no pad)
__device__ __forceinline__ void gl16(const unsigned short* g, unsigned short* l) {
  __builtin_amdgcn_global_load_lds(
      (const __attribute__((address_space(1))) void*)g,
      (__attribute__((address_space(3))) void*)l, 16, 0, 0);
}

// ---------------- cast f32 -> bf16 (vectorized x4) ----------------
__global__ void cast_bf16_kernel(const float* __restrict__ src,
                                 unsigned short* __restrict__ dst, int n4) {
  int i = blockIdx.x * blockDim.x + threadIdx.x;
  if (i >= n4) return;
  float4 v = ((const float4*)src)[i];
  uint2 o; o.x = packbf(v.x, v.y); o.y = packbf(v.z, v.w);
  ((uint2*)dst)[i] = o;
}

// ---------------- transpose + cast: src [K][N] f32 -> dst [N][K] bf16 ----------------
__global__ void transpose_cast_kernel(const float* __restrict__ src,
                                      unsigned short* __restrict__ dst,
                                      int K, int N) {
  __shared__ float tile[32][33];
  int n0 = blockIdx.x * 32, k0 = blockIdx.y * 32;
  int tx = threadIdx.x, ty = threadIdx.y;  // 32 x 8
  #pragma unroll
  for (int i = 0; i < 4; ++i) {
    int r = ty + i * 8;
    tile[r][tx] = src[(size_t)(k0 + r) * N + n0 + tx];
  }
  __syncthreads();
  #pragma unroll
  for (int i = 0; i < 4; ++i) {
    int r = ty + i * 8;
    dst[(size_t)(n0 + r) * K + k0 + tx] = f2b(tile[tx][r]);
  }
}

// ---------------- embedding gather ----------------
__global__ void gather_kernel(const int* __restrict__ idx,
                              const float* __restrict__ embed,
                              float* __restrict__ x) {
  int row = blockIdx.x; int t = threadIdx.x;  // 192 threads, float4 each
  int id = idx[row];
  ((float4*)(x + (size_t)row * DM))[t] = ((const float4*)(embed + (size_t)id * DM))[t];
}

// ---------------- RMSNorm: f32 in -> bf16 out ----------------
__global__ void rmsnorm_kernel(const float* __restrict__ x,
                               const float* __restrict__ w,
                               unsigned short* __restrict__ out) {
  int row = blockIdx.x; int t = threadIdx.x;  // 256 threads, D=768
  const float* xr = x + (size_t)row * DM;
  float v0 = xr[t], v1 = xr[t + 256], v2 = xr[t + 512];
  float s = v0*v0 + v1*v1 + v2*v2;
  #pragma unroll
  for (int off = 1; off < 64; off <<= 1) s += __shfl_xor(s, off);
  __shared__ float red[4];
  if ((t & 63) == 0) red[t >> 6] = s;
  __syncthreads();
  float tot = red[0] + red[1] + red[2] + red[3];
  float rs = rsqrtf(tot * (1.0f / DM) + 1e-6f);
  unsigned short* orow = out + (size_t)row * DM;
  orow[t]       = f2b(w[t]       * v0 * rs);
  orow[t + 256] = f2b(w[t + 256] * v1 * rs);
  orow[t + 512] = f2b(w[t + 512] * v2 * rs);
}

// ---------------- GEMM: C[M][N] = A[M][K] @ Bt[N][K]^T ----------------
// 1D grid, XCD-chunked bijective swizzle (m204). global_load_lds staging
// (m97 structure). OUT: 0 = f32 store, 1 = f32 +=, 2 = bf16 store,
// 3 = bf16 store with fused RoPE on cols < 1024 (QKV epilogue).
template <int OUT>
__global__ __launch_bounds__(256) void gemm_bt_kernel(
    const unsigned short* __restrict__ A, const unsigned short* __restrict__ Bt,
    void* __restrict__ Cv, int N, int K) {
  __shared__ unsigned short As[128 * 32];
  __shared__ unsigned short Bs[128 * 32];
  int bid = blockIdx.x, nwg = gridDim.x;
  int wgid = (bid & 7) * (nwg >> 3) + (bid >> 3);
  int m0 = (wgid & 15) * 128;
  int n0 = (wgid >> 4) * 128;
  int tid = threadIdx.x;
  int lane = tid & 63, wave = tid >> 6;
  int wr = (wave >> 1) * 64, wc = (wave & 1) * 64;
  int l16 = lane & 15, lk8 = (lane >> 4) * 8;
  f32x4 acc[4][4];
  #pragma unroll
  for (int m = 0; m < 4; ++m)
    #pragma unroll
    for (int n = 0; n < 4; ++n) acc[m][n] = (f32x4){0.f, 0.f, 0.f, 0.f};
  // per-lane global source matching linear LDS dest (row = tid>>2, col = (tid&3)*8)
  const unsigned short* Ab = A + (size_t)(m0 + (tid >> 2)) * K + (tid & 3) * 8;
  const unsigned short* Bb = Bt + (size_t)(n0 + (tid >> 2)) * K + (tid & 3) * 8;
  unsigned short* AsW = As + wave * 512;   // wave-uniform base (1KB per wave)
  unsigned short* BsW = Bs + wave * 512;
  for (int k0 = 0; k0 < K; k0 += 32) {
    gl16(Ab + k0,                  AsW);
    gl16(Ab + (size_t)64 * K + k0, AsW + 2048);
    gl16(Bb + k0,                  BsW);
    gl16(Bb + (size_t)64 * K + k0, BsW + 2048);
    __syncthreads();
    short8 af[4], bfr[4];
    #pragma unroll
    for (int m = 0; m < 4; ++m) af[m]  = *(const short8*)&As[(wr + m*16 + l16) * 32 + lk8];
    #pragma unroll
    for (int n = 0; n < 4; ++n) bfr[n] = *(const short8*)&Bs[(wc + n*16 + l16) * 32 + lk8];
    #pragma unroll
    for (int m = 0; m < 4; ++m)
      #pragma unroll
      for (int n = 0; n < 4; ++n)
        acc[m][n] = __builtin_amdgcn_mfma_f32_16x16x32_bf16(af[m], bfr[n], acc[m][n], 0, 0, 0);
    __syncthreads();
  }
  // C/D layout: col = lane&15, row = (lane>>4)*4 + reg   [learn_hip m89/m91]
  if (OUT == 2) {
    unsigned short* C = (unsigned short*)Cv;
    #pragma unroll
    for (int m = 0; m < 4; ++m)
      #pragma unroll
      for (int r = 0; r < 4; ++r) {
        size_t row = (size_t)(m0 + wr + m*16 + ((lane >> 4) << 2) + r);
        unsigned short* Cr = C + row * N + n0 + wc + l16;
        #pragma unroll
        for (int n = 0; n < 4; ++n) Cr[n * 16] = f2b(acc[m][n][r]);
      }
  } else if (OUT == 3) {
    unsigned short* C = (unsigned short*)Cv;
    bool qk = (n0 + wc) < 1024;   // whole 64-col group is one q/k head
    #pragma unroll
    for (int m = 0; m < 4; ++m)
      #pragma unroll
      for (int r = 0; r < 4; ++r) {
        int pos = m0 + wr + m*16 + ((lane >> 4) << 2) + r;
        unsigned short* Cr = C + (size_t)pos * N + n0 + wc + l16;
        if (qk) {
          float pf = (float)pos;
          #pragma unroll
          for (int n = 0; n < 2; ++n) {
            int d = n * 16 + l16;                 // 0..31 within head
            float inv = exp2f(-(float)d * (13.287712379549449f / 32.0f));
            float sv, cv; sincosf(pf * inv, &sv, &cv);
            float x1 = acc[m][n][r], x2 = acc[m][n + 2][r];
            Cr[n * 16]       = f2b(x1 * cv - x2 * sv);
            Cr[(n + 2) * 16] = f2b(x2 * cv + x1 * sv);
          }
        } else {
          #pragma unroll
          for (int n = 0; n < 4; ++n) Cr[n * 16] = f2b(acc[m][n][r]);
        }
      }
  } else {
    float* C = (float*)Cv;
    #pragma unroll
    for (int m = 0; m < 4; ++m)
      #pragma unroll
      for (int r = 0; r < 4; ++r) {
        size_t row = (size_t)(m0 + wr + m*16 + ((lane >> 4) << 2) + r);
        float* Cr = C + row * N + n0 + wc + l16;
        #pragma unroll
        for (int n = 0; n < 4; ++n) {
          if (OUT == 1) Cr[n * 16] += acc[m][n][r];
          else          Cr[n * 16]  = acc[m][n][r];
        }
      }
  }
}

// ---------------- gelu ----------------
__device__ __forceinline__ float gelu_t(float x) {
  float x3 = x * x * x;
  return 0.5f * x * (1.0f + tanhf(0.7978845608028654f * (x + 0.044715f * x3)));
}

// ---------------- fused gate/up GEMM + gelu-mul: m = gelu(h@Wg) * (h@Wu) ----------------
__global__ __launch_bounds__(256) void gemm_gu_kernel(
    const unsigned short* __restrict__ A, const unsigned short* __restrict__ BtG,
    const unsigned short* __restrict__ BtU, unsigned short* __restrict__ Cm) {
  __shared__ unsigned short As[128 * 32];
  __shared__ unsigned short Bg[128 * 32];
  __shared__ unsigned short Bu[128 * 32];
  const int K = DM;
  int bid = blockIdx.x, nwg = gridDim.x;        // 256 blocks
  int wgid = (bid & 7) * (nwg >> 3) + (bid >> 3);
  int m0 = (wgid & 15) * 128;
  int n0 = (wgid >> 4) * 128;                   // over FF (2048)
  int tid = threadIdx.x;
  int lane = tid & 63, wave = tid >> 6;
  int wr = (wave >> 1) * 64, wc = (wave & 1) * 64;
  int l16 = lane & 15, lk8 = (lane >> 4) * 8;
  f32x4 accg[4][4], accu[4][4];
  #pragma unroll
  for (int m = 0; m < 4; ++m)
    #pragma unroll
    for (int n = 0; n < 4; ++n) {
      accg[m][n] = (f32x4){0.f, 0.f, 0.f, 0.f};
      accu[m][n] = (f32x4){0.f, 0.f, 0.f, 0.f};
    }
  const unsigned short* Ab = A + (size_t)(m0 + (tid >> 2)) * K + (tid & 3) * 8;
  const unsigned short* Gb = BtG + (size_t)(n0 + (tid >> 2)) * K + (tid & 3) * 8;
  const unsigned short* Ub = BtU + (size_t)(n0 + (tid >> 2)) * K + (tid & 3) * 8;
  unsigned short* AsW = As + wave * 512;
  unsigned short* BgW = Bg + wave * 512;
  unsigned short* BuW = Bu + wave * 512;
  for (int k0 = 0; k0 < K; k0 += 32) {
    gl16(Ab + k0,                  AsW);
    gl16(Ab + (size_t)64 * K + k0, AsW + 2048);
    gl16(Gb + k0,                  BgW);
    gl16(Gb + (size_t)64 * K + k0, BgW + 2048);
    gl16(Ub + k0,                  BuW);
    gl16(Ub + (size_t)64 * K + k0, BuW + 2048);
    __syncthreads();
    short8 af[4], bg[4], bu[4];
    #pragma unroll
    for (int m = 0; m < 4; ++m) af[m] = *(const short8*)&As[(wr + m*16 + l16) * 32 + lk8];
    #pragma unroll
    for (int n = 0; n < 4; ++n) {
      bg[n] = *(const short8*)&Bg[(wc + n*16 + l16) * 32 + lk8];
      bu[n] = *(const short8*)&Bu[(wc + n*16 + l16) * 32 + lk8];
    }
    #pragma unroll
    for (int m = 0; m < 4; ++m)
      #pragma unroll
      for (int n = 0; n < 4; ++n) {
        accg[m][n] = __builtin_amdgcn_mfma_f32_16x16x32_bf16(af[m], bg[n], accg[m][n], 0, 0, 0);
        accu[m][n] = __builtin_amdgcn_mfma_f32_16x16x32_bf16(af[m], bu[n], accu[m][n], 0, 0, 0);
      }
    __syncthreads();
  }
  #pragma unroll
  for (int m = 0; m < 4; ++m)
    #pragma unroll
    for (int r = 0; r < 4; ++r) {
      size_t row = (size_t)(m0 + wr + m*16 + ((lane >> 4) << 2) + r);
      unsigned short* Cr = Cm + row * FFD + n0 + wc + l16;
      #pragma unroll
      for (int n = 0; n < 4; ++n)
        Cr[n * 16] = f2b(gelu_t(accg[m][n][r]) * accu[m][n][r]);
    }
}

// ---------------- MFMA flash attention, causal, GQA ----------------
__global__ __launch_bounds__(256) void attn_mfma_kernel(
    const unsigned short* __restrict__ qkv, unsigned short* __restrict__ out) {
  __shared__ unsigned short Ks[64 * 64];
  __shared__ unsigned short Vt[64 * 64];
  __shared__ unsigned short Ps[4][16 * 64];
  int h = blockIdx.y;
  int qt = gridDim.x - 1 - blockIdx.x;   // heavy (deep-causal) blocks dispatch first
  int r0 = qt * 64;
  int kvh = h / 3;           // N_REP = 3
  int t = threadIdx.x;
  int lane = t & 63, w = t >> 6;
  int l16 = lane & 15, g = lane >> 4;

  int qr = r0 + w * 16 + l16;
  const unsigned short* qrow = qkv + (size_t)qr * QKVN + h * HD;
  short8 aq0 = *(const short8*)(qrow + 8 * g);
  short8 aq1 = *(const short8*)(qrow + 32 + 8 * g);

  f32x4 o_acc[4];
  float mrun[4], lrun[4];
  #pragma unroll
  for (int i = 0; i < 4; ++i) { o_acc[i] = (f32x4){0.f,0.f,0.f,0.f}; mrun[i] = -1e30f; lrun[i] = 0.f; }

  int nt = qt + 1;
  for (int kt = 0; kt < nt; ++kt) {
    int kb = kt * 64;
    if (kt) __syncthreads();
    {
      const unsigned short* krow = qkv + (size_t)(kb + lane) * QKVN + DM + kvh * HD + 16 * w;
      uint4 k0 = ((const uint4*)krow)[0];
      uint4 k1 = ((const uint4*)krow)[1];
      uint4 v0 = ((const uint4*)(krow + NKV * HD))[0];
      uint4 v1 = ((const uint4*)(krow + NKV * HD))[1];
      int k7 = lane & 7;
      *(uint4*)&Ks[lane * 64 + (((2*w)     ^ k7) << 3)] = k0;
      *(uint4*)&Ks[lane * 64 + (((2*w + 1) ^ k7) << 3)] = k1;
      unsigned short tv[16];
      *(uint4*)&tv[0] = v0; *(uint4*)&tv[8] = v1;
      #pragma unroll
      for (int j = 0; j < 16; ++j) {
        int d = 16 * w + j;
        Vt[d * 64 + ((((lane >> 3) ^ (d & 7)) << 3) + (lane & 7))] = tv[j];
      }
    }
    __syncthreads();

    f32x4 s_acc[4];
    #pragma unroll
    for (int nb = 0; nb < 4; ++nb) s_acc[nb] = (f32x4){0.f,0.f,0.f,0.f};
    #pragma unroll
    for (int nb = 0; nb < 4; ++nb) {
      int key = nb * 16 + l16;
      short8 bk0 = *(const short8*)&Ks[key * 64 + ((g       ^ (key & 7)) << 3)];
      short8 bk1 = *(const short8*)&Ks[key * 64 + (((4 + g) ^ (key & 7)) << 3)];
      s_acc[nb] = __builtin_amdgcn_mfma_f32_16x16x32_bf16(aq0, bk0, s_acc[nb], 0, 0, 0);
      s_acc[nb] = __builtin_amdgcn_mfma_f32_16x16x32_bf16(aq1, bk1, s_acc[nb], 0, 0, 0);
    }

    bool diag = (kt == qt);
    #pragma unroll
    for (int r = 0; r < 4; ++r) {
      int qg = r0 + w * 16 + g * 4 + r;
      float sv[4];
      #pragma unroll
      for (int nb = 0; nb < 4; ++nb) {
        sv[nb] = s_acc[nb][r] * 0.125f;
        if (diag && (kb + nb * 16 + l16 > qg)) sv[nb] = -1e30f;
      }
      float mx = fmaxf(fmaxf(sv[0], sv[1]), fmaxf(sv[2], sv[3]));
      mx = fmaxf(mx, __shfl_xor(mx, 1));
      mx = fmaxf(mx, __shfl_xor(mx, 2));
      mx = fmaxf(mx, __shfl_xor(mx, 4));
      mx = fmaxf(mx, __shfl_xor(mx, 8));
      float mnew = fmaxf(mrun[r], mx);
      float es = __expf(mrun[r] - mnew);
      float rs = 0.f;
      #pragma unroll
      for (int nb = 0; nb < 4; ++nb) { sv[nb] = __expf(sv[nb] - mnew); rs += sv[nb]; }
      rs += __shfl_xor(rs, 1);
      rs += __shfl_xor(rs, 2);
      rs += __shfl_xor(rs, 4);
      rs += __shfl_xor(rs, 8);
      lrun[r] = lrun[r] * es + rs;
      mrun[r] = mnew;
      #pragma unroll
      for (int db = 0; db < 4; ++db) o_acc[db][r] *= es;
      int qloc = g * 4 + r, q7 = qloc & 7;
      #pragma unroll
      for (int nb = 0; nb < 4; ++nb) {
        int key = nb * 16 + l16;
        Ps[w][qloc * 64 + ((((key >> 3) ^ q7) << 3) + (key & 7))] = f2b(sv[nb]);
      }
    }

    #pragma unroll
    for (int kc = 0; kc < 2; ++kc) {
      short8 pa = *(const short8*)&Ps[w][l16 * 64 + (((4 * kc + g) ^ (l16 & 7)) << 3)];
      #pragma unroll
      for (int db = 0; db < 4; ++db) {
        int d = db * 16 + l16;
        short8 bv = *(const short8*)&Vt[d * 64 + (((4 * kc + g) ^ (d & 7)) << 3)];
        o_acc[db] = __builtin_amdgcn_mfma_f32_16x16x32_bf16(pa, bv, o_acc[db], 0, 0, 0);
      }
    }
  }

  #pragma unroll
  for (int r = 0; r < 4; ++r) {
    int qg = r0 + w * 16 + g * 4 + r;
    float inv = 1.0f / lrun[r];
    unsigned short* orow = out + (size_t)qg * DM + h * HD + l16;
    #pragma unroll
    for (int db = 0; db < 4; ++db) orow[db * 16] = f2b(o_acc[db][r] * inv);
  }
}

extern "C" void kernel_launch(void* const* d_in, const int* in_sizes, int n_in,
                              void* d_out, int out_size, void* d_ws, size_t ws_size,
                              hipStream_t stream) {
  const int*   idx   = (const int*)d_in[0];
  const float* embed = (const float*)d_in[1];
  const float* ln1   = (const float*)d_in[2];
  const float* Wq    = (const float*)d_in[3];
  const float* Wk    = (const float*)d_in[4];
  const float* Wv    = (const float*)d_in[5];
  const float* Wo    = (const float*)d_in[6];
  const float* ln2   = (const float*)d_in[7];
  const float* Wg    = (const float*)d_in[8];
  const float* Wu    = (const float*)d_in[9];
  const float* Wd    = (const float*)d_in[10];
  const float* normf = (const float*)d_in[11];
  float* out = (float*)d_out;
  char* ws = (char*)d_ws;
  (void)in_sizes; (void)n_in; (void)out_size; (void)ws_size;

  // ---- workspace layout ----
  unsigned short* embed_bf = (unsigned short*)ws;
  size_t off = (size_t)VOC * DM * 2;
  unsigned short* wts = (unsigned short*)(ws + off);
  const size_t LW = (size_t)QKVN * DM + (size_t)DM * DM
                  + 2ull * FFD * DM + (size_t)DM * FFD;
  off += LW * 2ull * NL;
  float* xf = (float*)(ws + off);            off += (size_t)TSEQ * DM * 4;
  unsigned short* h_bf = (unsigned short*)(ws + off);    off += (size_t)TSEQ * DM * 2;
  unsigned short* qkv_bf = (unsigned short*)(ws + off);  off += (size_t)TSEQ * QKVN * 2;
  unsigned short* attn_bf = (unsigned short*)(ws + off); off += (size_t)TSEQ * DM * 2;
  unsigned short* m_bf = (unsigned short*)(ws + off);    off += (size_t)TSEQ * FFD * 2;

  // ---- prep: embed cast + weight transpose/cast ----
  cast_bf16_kernel<<<(VOC * DM / 4 + 255) / 256, 256, 0, stream>>>(embed, embed_bf, VOC * DM / 4);

  for (int l = 0; l < NL; ++l) {
    unsigned short* base = wts + (size_t)l * LW;
    unsigned short* qkvT = base;
    unsigned short* woT  = base + (size_t)QKVN * DM;
    unsigned short* wguT = woT + (size_t)DM * DM;
    unsigned short* wdT  = wguT + 2ull * FFD * DM;
    transpose_cast_kernel<<<dim3(24, 24), dim3(32, 8), 0, stream>>>(Wq + (size_t)l * 589824, qkvT, 768, 768);
    transpose_cast_kernel<<<dim3(8, 24),  dim3(32, 8), 0, stream>>>(Wk + (size_t)l * 196608, qkvT + 768ull * 768, 768, 256);
    transpose_cast_kernel<<<dim3(8, 24),  dim3(32, 8), 0, stream>>>(Wv + (size_t)l * 196608, qkvT + 1024ull * 768, 768, 256);
    transpose_cast_kernel<<<dim3(24, 24), dim3(32, 8), 0, stream>>>(Wo + (size_t)l * 589824, woT, 768, 768);
    transpose_cast_kernel<<<dim3(64, 24), dim3(32, 8), 0, stream>>>(Wg + (size_t)l * 1572864, wguT, 768, 2048);
    transpose_cast_kernel<<<dim3(64, 24), dim3(32, 8), 0, stream>>>(Wu + (size_t)l * 1572864, wguT + 2048ull * 768, 768, 2048);
    transpose_cast_kernel<<<dim3(24, 64), dim3(32, 8), 0, stream>>>(Wd + (size_t)l * 1572864, wdT, 2048, 768);
  }

  gather_kernel<<<TSEQ, 192, 0, stream>>>(idx, embed, xf);

  for (int l = 0; l < NL; ++l) {
    unsigned short* base = wts + (size_t)l * LW;
    unsigned short* qkvT = base;
    unsigned short* woT  = base + (size_t)QKVN * DM;
    unsigned short* wguT = woT + (size_t)DM * DM;
    unsigned short* wdT  = wguT + 2ull * FFD * DM;

    rmsnorm_kernel<<<TSEQ, 256, 0, stream>>>(xf, ln1 + (size_t)l * DM, h_bf);
    gemm_bt_kernel<3><<<(QKVN / 128) * 16, 256, 0, stream>>>(h_bf, qkvT, qkv_bf, QKVN, DM);
    attn_mfma_kernel<<<dim3(TSEQ / 64, NH), 256, 0, stream>>>(qkv_bf, attn_bf);
    gemm_bt_kernel<1><<<(DM / 128) * 16, 256, 0, stream>>>(attn_bf, woT, xf, DM, DM);
    rmsnorm_kernel<<<TSEQ, 256, 0, stream>>>(xf, ln2 + (size_t)l * DM, h_bf);
    gemm_gu_kernel<<<(FFD / 128) * 16, 256, 0, stream>>>(h_bf, wguT, wguT + (size_t)FFD * DM, m_bf);
    gemm_bt_kernel<1><<<(DM / 128) * 16, 256, 0, stream>>>(m_bf, wdT, xf, DM, FFD);
  }

  rmsnorm_kernel<<<TSEQ, 256, 0, stream>>>(xf, normf, h_bf);
  gemm_bt_kernel<0><<<(VOC / 128) * 16, 256, 0, stream>>>(h_bf, embed_bf, out, VOC, DM);
}

// Round 5
// 1088.828 us; speedup vs baseline: 1.1445x; 1.1445x over previous
//
#include <hip/hip_runtime.h>

#define TSEQ 2048
#define DM   768
#define NH   12
#define NKV  4
#define HD   64
#define FFD  2048
#define NL   4
#define VOC  32000
#define QKVN 1280   // 768 q + 256 k + 256 v

typedef __attribute__((ext_vector_type(8))) short short8;
typedef __attribute__((ext_vector_type(4))) float f32x4;

__device__ __forceinline__ unsigned short f2b(float f) {
  unsigned int u = __float_as_uint(f);
  u += 0x7fffu + ((u >> 16) & 1u);
  return (unsigned short)(u >> 16);
}
__device__ __forceinline__ float b2f(unsigned short u) {
  return __uint_as_float(((unsigned int)u) << 16);
}
__device__ __forceinline__ unsigned int packbf(float a, float b) {
  return (unsigned int)f2b(a) | ((unsigned int)f2b(b) << 16);
}

// ---------------- cast f32 -> bf16 (vectorized x4) ----------------
__global__ void cast_bf16_kernel(const float* __restrict__ src,
                                 unsigned short* __restrict__ dst, int n4) {
  int i = blockIdx.x * blockDim.x + threadIdx.x;
  if (i >= n4) return;
  float4 v = ((const float4*)src)[i];
  uint2 o; o.x = packbf(v.x, v.y); o.y = packbf(v.z, v.w);
  ((uint2*)dst)[i] = o;
}

// ---------------- RoPE cos/sin table: [pos][d] for d in 0..31 ----------------
__global__ void rope_tab_kernel(float2* __restrict__ tab) {
  int i = blockIdx.x * blockDim.x + threadIdx.x;   // over TSEQ*32
  int pos = i >> 5, d = i & 31;
  float inv = exp2f(-(float)d * (13.287712379549449f / 32.0f));
  float sv, cv; sincosf((float)pos * inv, &sv, &cv);
  tab[i] = make_float2(cv, sv);
}

// ---------------- transpose + cast (batched over layers via blockIdx.z) ----------------
__global__ void transpose_cast_kernel(const float* __restrict__ src,
                                      unsigned short* __restrict__ dst,
                                      int K, int N, size_t sstride, size_t dstride) {
  __shared__ float tile[32][33];
  src += (size_t)blockIdx.z * sstride;
  dst += (size_t)blockIdx.z * dstride;
  int n0 = blockIdx.x * 32, k0 = blockIdx.y * 32;
  int tx = threadIdx.x, ty = threadIdx.y;  // 32 x 8
  #pragma unroll
  for (int i = 0; i < 4; ++i) {
    int r = ty + i * 8;
    tile[r][tx] = src[(size_t)(k0 + r) * N + n0 + tx];
  }
  __syncthreads();
  #pragma unroll
  for (int i = 0; i < 4; ++i) {
    int r = ty + i * 8;
    dst[(size_t)(n0 + r) * K + k0 + tx] = f2b(tile[tx][r]);
  }
}

// ---------------- embedding gather ----------------
__global__ void gather_kernel(const int* __restrict__ idx,
                              const float* __restrict__ embed,
                              float* __restrict__ x) {
  int row = blockIdx.x; int t = threadIdx.x;  // 192 threads, float4 each
  int id = idx[row];
  ((float4*)(x + (size_t)row * DM))[t] = ((const float4*)(embed + (size_t)id * DM))[t];
}

// ---------------- RMSNorm: f32 in -> bf16 out ----------------
__global__ void rmsnorm_kernel(const float* __restrict__ x,
                               const float* __restrict__ w,
                               unsigned short* __restrict__ out) {
  int row = blockIdx.x; int t = threadIdx.x;  // 256 threads, D=768
  const float* xr = x + (size_t)row * DM;
  float v0 = xr[t], v1 = xr[t + 256], v2 = xr[t + 512];
  float s = v0*v0 + v1*v1 + v2*v2;
  #pragma unroll
  for (int off = 1; off < 64; off <<= 1) s += __shfl_xor(s, off);
  __shared__ float red[4];
  if ((t & 63) == 0) red[t >> 6] = s;
  __syncthreads();
  float tot = red[0] + red[1] + red[2] + red[3];
  float rs = rsqrtf(tot * (1.0f / DM) + 1e-6f);
  unsigned short* orow = out + (size_t)row * DM;
  orow[t]       = f2b(w[t]       * v0 * rs);
  orow[t + 256] = f2b(w[t + 256] * v1 * rs);
  orow[t + 512] = f2b(w[t + 512] * v2 * rs);
}

// ---------------- GEMM: C[M][N] = A[M][K] @ Bt[N][K]^T ----------------
// 1D tile grid (x) XCD-chunk-swizzled (m204); blockIdx.y = K-split chunk.
// OUT: 0 = f32 store, 2 = bf16 store, 3 = bf16 + fused RoPE (table),
// 4 = f32 atomicAdd (split-K accumulate into residual).
template <int OUT>
__global__ __launch_bounds__(256) void gemm_bt_kernel(
    const unsigned short* __restrict__ A, const unsigned short* __restrict__ Bt,
    void* __restrict__ Cv, int N, int K, int Kc,
    const float2* __restrict__ rope_tab) {
  __shared__ unsigned short As[128 * 40];
  __shared__ unsigned short Bs[128 * 40];
  int bid = blockIdx.x, nwg = gridDim.x;
  int wgid = (bid & 7) * (nwg >> 3) + (bid >> 3);
  int m0 = (wgid & 15) * 128;
  int n0 = (wgid >> 4) * 128;
  int tid = threadIdx.x;
  int lane = tid & 63, wave = tid >> 6;
  int wr = (wave >> 1) * 64, wc = (wave & 1) * 64;
  int l16 = lane & 15, lk8 = (lane >> 4) * 8;
  f32x4 acc[4][4];
  #pragma unroll
  for (int m = 0; m < 4; ++m)
    #pragma unroll
    for (int n = 0; n < 4; ++n) acc[m][n] = (f32x4){0.f, 0.f, 0.f, 0.f};
  size_t koff = (size_t)blockIdx.y * Kc;
  const unsigned short* Abase = A + (size_t)m0 * K + koff;
  const unsigned short* Bbase = Bt + (size_t)n0 * K + koff;
  int r0 = tid >> 2;            // 0..63
  int c0 = (tid & 3) * 8;       // 0,8,16,24
  for (int k0 = 0; k0 < Kc; k0 += 32) {
    uint4 a0 = *(const uint4*)(Abase + (size_t)r0 * K + k0 + c0);
    uint4 a1 = *(const uint4*)(Abase + (size_t)(r0 + 64) * K + k0 + c0);
    uint4 b0 = *(const uint4*)(Bbase + (size_t)r0 * K + k0 + c0);
    uint4 b1 = *(const uint4*)(Bbase + (size_t)(r0 + 64) * K + k0 + c0);
    *(uint4*)&As[r0 * 40 + c0] = a0;
    *(uint4*)&As[(r0 + 64) * 40 + c0] = a1;
    *(uint4*)&Bs[r0 * 40 + c0] = b0;
    *(uint4*)&Bs[(r0 + 64) * 40 + c0] = b1;
    __syncthreads();
    short8 af[4], bfr[4];
    #pragma unroll
    for (int m = 0; m < 4; ++m) af[m]  = *(const short8*)&As[(wr + m*16 + l16) * 40 + lk8];
    #pragma unroll
    for (int n = 0; n < 4; ++n) bfr[n] = *(const short8*)&Bs[(wc + n*16 + l16) * 40 + lk8];
    #pragma unroll
    for (int m = 0; m < 4; ++m)
      #pragma unroll
      for (int n = 0; n < 4; ++n)
        acc[m][n] = __builtin_amdgcn_mfma_f32_16x16x32_bf16(af[m], bfr[n], acc[m][n], 0, 0, 0);
    __syncthreads();
  }
  // C/D layout: col = lane&15, row = (lane>>4)*4 + reg   [learn_hip m89/m91]
  if (OUT == 2) {
    unsigned short* C = (unsigned short*)Cv;
    #pragma unroll
    for (int m = 0; m < 4; ++m)
      #pragma unroll
      for (int r = 0; r < 4; ++r) {
        size_t row = (size_t)(m0 + wr + m*16 + ((lane >> 4) << 2) + r);
        unsigned short* Cr = C + row * N + n0 + wc + l16;
        #pragma unroll
        for (int n = 0; n < 4; ++n) Cr[n * 16] = f2b(acc[m][n][r]);
      }
  } else if (OUT == 3) {
    unsigned short* C = (unsigned short*)Cv;
    bool qk = (n0 + wc) < 1024;   // whole 64-col group is one q/k head
    #pragma unroll
    for (int m = 0; m < 4; ++m)
      #pragma unroll
      for (int r = 0; r < 4; ++r) {
        int pos = m0 + wr + m*16 + ((lane >> 4) << 2) + r;
        unsigned short* Cr = C + (size_t)pos * N + n0 + wc + l16;
        if (qk) {
          #pragma unroll
          for (int n = 0; n < 2; ++n) {
            int d = n * 16 + l16;                 // 0..31 within head
            float2 cs = rope_tab[pos * 32 + d];
            float x1 = acc[m][n][r], x2 = acc[m][n + 2][r];
            Cr[n * 16]       = f2b(x1 * cs.x - x2 * cs.y);
            Cr[(n + 2) * 16] = f2b(x2 * cs.x + x1 * cs.y);
          }
        } else {
          #pragma unroll
          for (int n = 0; n < 4; ++n) Cr[n * 16] = f2b(acc[m][n][r]);
        }
      }
  } else if (OUT == 4) {
    float* C = (float*)Cv;
    #pragma unroll
    for (int m = 0; m < 4; ++m)
      #pragma unroll
      for (int r = 0; r < 4; ++r) {
        size_t row = (size_t)(m0 + wr + m*16 + ((lane >> 4) << 2) + r);
        float* Cr = C + row * N + n0 + wc + l16;
        #pragma unroll
        for (int n = 0; n < 4; ++n) atomicAdd(&Cr[n * 16], acc[m][n][r]);
      }
  } else {
    float* C = (float*)Cv;
    #pragma unroll
    for (int m = 0; m < 4; ++m)
      #pragma unroll
      for (int r = 0; r < 4; ++r) {
        size_t row = (size_t)(m0 + wr + m*16 + ((lane >> 4) << 2) + r);
        float* Cr = C + row * N + n0 + wc + l16;
        #pragma unroll
        for (int n = 0; n < 4; ++n) Cr[n * 16] = acc[m][n][r];
      }
  }
}

// ---------------- gelu ----------------
__device__ __forceinline__ float gelu_t(float x) {
  float x3 = x * x * x;
  return 0.5f * x * (1.0f + tanhf(0.7978845608028654f * (x + 0.044715f * x3)));
}

// ---------------- fused gate/up GEMM + gelu-mul: m = gelu(h@Wg) * (h@Wu) ----------------
__global__ __launch_bounds__(256) void gemm_gu_kernel(
    const unsigned short* __restrict__ A, const unsigned short* __restrict__ BtG,
    const unsigned short* __restrict__ BtU, unsigned short* __restrict__ Cm) {
  __shared__ unsigned short As[128 * 40];
  __shared__ unsigned short Bg[128 * 40];
  __shared__ unsigned short Bu[128 * 40];
  const int K = DM;
  int bid = blockIdx.x, nwg = gridDim.x;        // 256 blocks
  int wgid = (bid & 7) * (nwg >> 3) + (bid >> 3);
  int m0 = (wgid & 15) * 128;
  int n0 = (wgid >> 4) * 128;                   // over FF (2048)
  int tid = threadIdx.x;
  int lane = tid & 63, wave = tid >> 6;
  int wr = (wave >> 1) * 64, wc = (wave & 1) * 64;
  int l16 = lane & 15, lk8 = (lane >> 4) * 8;
  f32x4 accg[4][4], accu[4][4];
  #pragma unroll
  for (int m = 0; m < 4; ++m)
    #pragma unroll
    for (int n = 0; n < 4; ++n) {
      accg[m][n] = (f32x4){0.f, 0.f, 0.f, 0.f};
      accu[m][n] = (f32x4){0.f, 0.f, 0.f, 0.f};
    }
  const unsigned short* Abase = A + (size_t)m0 * K;
  const unsigned short* Gbase = BtG + (size_t)n0 * K;
  const unsigned short* Ubase = BtU + (size_t)n0 * K;
  int r0 = tid >> 2;
  int c0 = (tid & 3) * 8;
  for (int k0 = 0; k0 < K; k0 += 32) {
    uint4 a0 = *(const uint4*)(Abase + (size_t)r0 * K + k0 + c0);
    uint4 a1 = *(const uint4*)(Abase + (size_t)(r0 + 64) * K + k0 + c0);
    uint4 g0 = *(const uint4*)(Gbase + (size_t)r0 * K + k0 + c0);
    uint4 g1 = *(const uint4*)(Gbase + (size_t)(r0 + 64) * K + k0 + c0);
    uint4 u0 = *(const uint4*)(Ubase + (size_t)r0 * K + k0 + c0);
    uint4 u1 = *(const uint4*)(Ubase + (size_t)(r0 + 64) * K + k0 + c0);
    *(uint4*)&As[r0 * 40 + c0] = a0;
    *(uint4*)&As[(r0 + 64) * 40 + c0] = a1;
    *(uint4*)&Bg[r0 * 40 + c0] = g0;
    *(uint4*)&Bg[(r0 + 64) * 40 + c0] = g1;
    *(uint4*)&Bu[r0 * 40 + c0] = u0;
    *(uint4*)&Bu[(r0 + 64) * 40 + c0] = u1;
    __syncthreads();
    short8 af[4], bg[4], bu[4];
    #pragma unroll
    for (int m = 0; m < 4; ++m) af[m] = *(const short8*)&As[(wr + m*16 + l16) * 40 + lk8];
    #pragma unroll
    for (int n = 0; n < 4; ++n) {
      bg[n] = *(const short8*)&Bg[(wc + n*16 + l16) * 40 + lk8];
      bu[n] = *(const short8*)&Bu[(wc + n*16 + l16) * 40 + lk8];
    }
    #pragma unroll
    for (int m = 0; m < 4; ++m)
      #pragma unroll
      for (int n = 0; n < 4; ++n) {
        accg[m][n] = __builtin_amdgcn_mfma_f32_16x16x32_bf16(af[m], bg[n], accg[m][n], 0, 0, 0);
        accu[m][n] = __builtin_amdgcn_mfma_f32_16x16x32_bf16(af[m], bu[n], accu[m][n], 0, 0, 0);
      }
    __syncthreads();
  }
  #pragma unroll
  for (int m = 0; m < 4; ++m)
    #pragma unroll
    for (int r = 0; r < 4; ++r) {
      size_t row = (size_t)(m0 + wr + m*16 + ((lane >> 4) << 2) + r);
      unsigned short* Cr = Cm + row * FFD + n0 + wc + l16;
      #pragma unroll
      for (int n = 0; n < 4; ++n)
        Cr[n * 16] = f2b(gelu_t(accg[m][n][r]) * accu[m][n][r]);
    }
}

// ---------------- MFMA flash attention, causal, GQA ----------------
__global__ __launch_bounds__(256) void attn_mfma_kernel(
    const unsigned short* __restrict__ qkv, unsigned short* __restrict__ out) {
  __shared__ unsigned short Ks[64 * 64];
  __shared__ unsigned short Vt[64 * 64];
  __shared__ unsigned short Ps[4][16 * 64];
  int h = blockIdx.y;
  int qt = gridDim.x - 1 - blockIdx.x;   // heavy (deep-causal) blocks dispatch first
  int r0 = qt * 64;
  int kvh = h / 3;           // N_REP = 3
  int t = threadIdx.x;
  int lane = t & 63, w = t >> 6;
  int l16 = lane & 15, g = lane >> 4;

  int qr = r0 + w * 16 + l16;
  const unsigned short* qrow = qkv + (size_t)qr * QKVN + h * HD;
  short8 aq0 = *(const short8*)(qrow + 8 * g);
  short8 aq1 = *(const short8*)(qrow + 32 + 8 * g);

  f32x4 o_acc[4];
  float mrun[4], lrun[4];
  #pragma unroll
  for (int i = 0; i < 4; ++i) { o_acc[i] = (f32x4){0.f,0.f,0.f,0.f}; mrun[i] = -1e30f; lrun[i] = 0.f; }

  int nt = qt + 1;
  for (int kt = 0; kt < nt; ++kt) {
    int kb = kt * 64;
    if (kt) __syncthreads();
    {
      const unsigned short* krow = qkv + (size_t)(kb + lane) * QKVN + DM + kvh * HD + 16 * w;
      uint4 k0 = ((const uint4*)krow)[0];
      uint4 k1 = ((const uint4*)krow)[1];
      uint4 v0 = ((const uint4*)(krow + NKV * HD))[0];
      uint4 v1 = ((const uint4*)(krow + NKV * HD))[1];
      int k7 = lane & 7;
      *(uint4*)&Ks[lane * 64 + (((2*w)     ^ k7) << 3)] = k0;
      *(uint4*)&Ks[lane * 64 + (((2*w + 1) ^ k7) << 3)] = k1;
      unsigned short tv[16];
      *(uint4*)&tv[0] = v0; *(uint4*)&tv[8] = v1;
      #pragma unroll
      for (int j = 0; j < 16; ++j) {
        int d = 16 * w + j;
        Vt[d * 64 + ((((lane >> 3) ^ (d & 7)) << 3) + (lane & 7))] = tv[j];
      }
    }
    __syncthreads();

    f32x4 s_acc[4];
    #pragma unroll
    for (int nb = 0; nb < 4; ++nb) s_acc[nb] = (f32x4){0.f,0.f,0.f,0.f};
    #pragma unroll
    for (int nb = 0; nb < 4; ++nb) {
      int key = nb * 16 + l16;
      short8 bk0 = *(const short8*)&Ks[key * 64 + ((g       ^ (key & 7)) << 3)];
      short8 bk1 = *(const short8*)&Ks[key * 64 + (((4 + g) ^ (key & 7)) << 3)];
      s_acc[nb] = __builtin_amdgcn_mfma_f32_16x16x32_bf16(aq0, bk0, s_acc[nb], 0, 0, 0);
      s_acc[nb] = __builtin_amdgcn_mfma_f32_16x16x32_bf16(aq1, bk1, s_acc[nb], 0, 0, 0);
    }

    bool diag = (kt == qt);
    #pragma unroll
    for (int r = 0; r < 4; ++r) {
      int qg = r0 + w * 16 + g * 4 + r;
      float sv[4];
      #pragma unroll
      for (int nb = 0; nb < 4; ++nb) {
        sv[nb] = s_acc[nb][r] * 0.125f;
        if (diag && (kb + nb * 16 + l16 > qg)) sv[nb] = -1e30f;
      }
      float mx = fmaxf(fmaxf(sv[0], sv[1]), fmaxf(sv[2], sv[3]));
      mx = fmaxf(mx, __shfl_xor(mx, 1));
      mx = fmaxf(mx, __shfl_xor(mx, 2));
      mx = fmaxf(mx, __shfl_xor(mx, 4));
      mx = fmaxf(mx, __shfl_xor(mx, 8));
      float mnew = fmaxf(mrun[r], mx);
      float es = __expf(mrun[r] - mnew);
      float rs = 0.f;
      #pragma unroll
      for (int nb = 0; nb < 4; ++nb) { sv[nb] = __expf(sv[nb] - mnew); rs += sv[nb]; }
      rs += __shfl_xor(rs, 1);
      rs += __shfl_xor(rs, 2);
      rs += __shfl_xor(rs, 4);
      rs += __shfl_xor(rs, 8);
      lrun[r] = lrun[r] * es + rs;
      mrun[r] = mnew;
      #pragma unroll
      for (int db = 0; db < 4; ++db) o_acc[db][r] *= es;
      int qloc = g * 4 + r, q7 = qloc & 7;
      #pragma unroll
      for (int nb = 0; nb < 4; ++nb) {
        int key = nb * 16 + l16;
        Ps[w][qloc * 64 + ((((key >> 3) ^ q7) << 3) + (key & 7))] = f2b(sv[nb]);
      }
    }

    #pragma unroll
    for (int kc = 0; kc < 2; ++kc) {
      short8 pa = *(const short8*)&Ps[w][l16 * 64 + (((4 * kc + g) ^ (l16 & 7)) << 3)];
      #pragma unroll
      for (int db = 0; db < 4; ++db) {
        int d = db * 16 + l16;
        short8 bv = *(const short8*)&Vt[d * 64 + (((4 * kc + g) ^ (d & 7)) << 3)];
        o_acc[db] = __builtin_amdgcn_mfma_f32_16x16x32_bf16(pa, bv, o_acc[db], 0, 0, 0);
      }
    }
  }

  #pragma unroll
  for (int r = 0; r < 4; ++r) {
    int qg = r0 + w * 16 + g * 4 + r;
    float inv = 1.0f / lrun[r];
    unsigned short* orow = out + (size_t)qg * DM + h * HD + l16;
    #pragma unroll
    for (int db = 0; db < 4; ++db) orow[db * 16] = f2b(o_acc[db][r] * inv);
  }
}

extern "C" void kernel_launch(void* const* d_in, const int* in_sizes, int n_in,
                              void* d_out, int out_size, void* d_ws, size_t ws_size,
                              hipStream_t stream) {
  const int*   idx   = (const int*)d_in[0];
  const float* embed = (const float*)d_in[1];
  const float* ln1   = (const float*)d_in[2];
  const float* Wq    = (const float*)d_in[3];
  const float* Wk    = (const float*)d_in[4];
  const float* Wv    = (const float*)d_in[5];
  const float* Wo    = (const float*)d_in[6];
  const float* ln2   = (const float*)d_in[7];
  const float* Wg    = (const float*)d_in[8];
  const float* Wu    = (const float*)d_in[9];
  const float* Wd    = (const float*)d_in[10];
  const float* normf = (const float*)d_in[11];
  float* out = (float*)d_out;
  char* ws = (char*)d_ws;
  (void)in_sizes; (void)n_in; (void)out_size; (void)ws_size;

  // ---- workspace layout ----
  unsigned short* embed_bf = (unsigned short*)ws;
  size_t off = (size_t)VOC * DM * 2;
  unsigned short* wts = (unsigned short*)(ws + off);
  const size_t LW = (size_t)QKVN * DM + (size_t)DM * DM
                  + 2ull * FFD * DM + (size_t)DM * FFD;
  off += LW * 2ull * NL;
  float* xf = (float*)(ws + off);            off += (size_t)TSEQ * DM * 4;
  unsigned short* h_bf = (unsigned short*)(ws + off);    off += (size_t)TSEQ * DM * 2;
  unsigned short* qkv_bf = (unsigned short*)(ws + off);  off += (size_t)TSEQ * QKVN * 2;
  unsigned short* attn_bf = (unsigned short*)(ws + off); off += (size_t)TSEQ * DM * 2;
  unsigned short* m_bf = (unsigned short*)(ws + off);    off += (size_t)TSEQ * FFD * 2;
  float2* rope_tab = (float2*)(ws + off);    off += (size_t)TSEQ * 32 * 8;

  // ---- prep: embed cast + rope table + batched weight transpose/cast ----
  cast_bf16_kernel<<<(VOC * DM / 4 + 255) / 256, 256, 0, stream>>>(embed, embed_bf, VOC * DM / 4);
  rope_tab_kernel<<<TSEQ * 32 / 256, 256, 0, stream>>>(rope_tab);

  {
    unsigned short* qkvT = wts;
    unsigned short* woT  = wts + (size_t)QKVN * DM;
    unsigned short* wguT = woT + (size_t)DM * DM;
    unsigned short* wdT  = wguT + 2ull * FFD * DM;
    transpose_cast_kernel<<<dim3(24, 24, NL), dim3(32, 8), 0, stream>>>(Wq, qkvT, 768, 768, 589824, LW);
    transpose_cast_kernel<<<dim3(8, 24, NL),  dim3(32, 8), 0, stream>>>(Wk, qkvT + 768ull * 768, 768, 256, 196608, LW);
    transpose_cast_kernel<<<dim3(8, 24, NL),  dim3(32, 8), 0, stream>>>(Wv, qkvT + 1024ull * 768, 768, 256, 196608, LW);
    transpose_cast_kernel<<<dim3(24, 24, NL), dim3(32, 8), 0, stream>>>(Wo, woT, 768, 768, 589824, LW);
    transpose_cast_kernel<<<dim3(64, 24, NL), dim3(32, 8), 0, stream>>>(Wg, wguT, 768, 2048, 1572864, LW);
    transpose_cast_kernel<<<dim3(64, 24, NL), dim3(32, 8), 0, stream>>>(Wu, wguT + (size_t)FFD * DM, 768, 2048, 1572864, LW);
    transpose_cast_kernel<<<dim3(24, 64, NL), dim3(32, 8), 0, stream>>>(Wd, wdT, 2048, 768, 1572864, LW);
  }

  gather_kernel<<<TSEQ, 192, 0, stream>>>(idx, embed, xf);

  for (int l = 0; l < NL; ++l) {
    unsigned short* base = wts + (size_t)l * LW;
    unsigned short* qkvT = base;
    unsigned short* woT  = base + (size_t)QKVN * DM;
    unsigned short* wguT = woT + (size_t)DM * DM;
    unsigned short* wdT  = wguT + 2ull * FFD * DM;

    rmsnorm_kernel<<<TSEQ, 256, 0, stream>>>(xf, ln1 + (size_t)l * DM, h_bf);
    gemm_bt_kernel<3><<<dim3((QKVN / 128) * 16, 1), 256, 0, stream>>>(h_bf, qkvT, qkv_bf, QKVN, DM, DM, rope_tab);
    attn_mfma_kernel<<<dim3(TSEQ / 64, NH), 256, 0, stream>>>(qkv_bf, attn_bf);
    gemm_bt_kernel<4><<<dim3((DM / 128) * 16, 3), 256, 0, stream>>>(attn_bf, woT, xf, DM, DM, 256, rope_tab);
    rmsnorm_kernel<<<TSEQ, 256, 0, stream>>>(xf, ln2 + (size_t)l * DM, h_bf);
    gemm_gu_kernel<<<(FFD / 128) * 16, 256, 0, stream>>>(h_bf, wguT, wguT + (size_t)FFD * DM, m_bf);
    gemm_bt_kernel<4><<<dim3((DM / 128) * 16, 4), 256, 0, stream>>>(m_bf, wdT, xf, DM, FFD, 512, rope_tab);
  }

  rmsnorm_kernel<<<TSEQ, 256, 0, stream>>>(xf, normf, h_bf);
  gemm_bt_kernel<0><<<dim3((VOC / 128) * 16, 1), 256, 0, stream>>>(h_bf, embed_bf, out, VOC, DM, DM, rope_tab);
}

// Round 6
// 1038.680 us; speedup vs baseline: 1.1998x; 1.0483x over previous
//
#include <hip/hip_runtime.h>

#define TSEQ 2048
#define DM   768
#define NH   12
#define NKV  4
#define HD   64
#define FFD  2048
#define NL   4
#define VOC  32000
#define QKVN 1280   // 768 q + 256 k + 256 v

typedef __attribute__((ext_vector_type(8))) short short8;
typedef __attribute__((ext_vector_type(4))) float f32x4;

__device__ __forceinline__ unsigned short f2b(float f) {
  unsigned int u = __float_as_uint(f);
  u += 0x7fffu + ((u >> 16) & 1u);
  return (unsigned short)(u >> 16);
}
__device__ __forceinline__ float b2f(unsigned short u) {
  return __uint_as_float(((unsigned int)u) << 16);
}
__device__ __forceinline__ unsigned int packbf(float a, float b) {
  return (unsigned int)f2b(a) | ((unsigned int)f2b(b) << 16);
}

// direct global->LDS async copy, 16B/lane; LDS dest wave-uniform (HW adds lane*16)
__device__ __forceinline__ void gl16(const unsigned short* g, unsigned short* l) {
  __builtin_amdgcn_global_load_lds(
      (const __attribute__((address_space(1))) void*)g,
      (__attribute__((address_space(3))) void*)l, 16, 0, 0);
}

// ---------------- cast f32 -> bf16 (vectorized x4) ----------------
__global__ void cast_bf16_kernel(const float* __restrict__ src,
                                 unsigned short* __restrict__ dst, int n4) {
  int i = blockIdx.x * blockDim.x + threadIdx.x;
  if (i >= n4) return;
  float4 v = ((const float4*)src)[i];
  uint2 o; o.x = packbf(v.x, v.y); o.y = packbf(v.z, v.w);
  ((uint2*)dst)[i] = o;
}

// ---------------- RoPE cos/sin table: [pos][d] for d in 0..31 ----------------
__global__ void rope_tab_kernel(float2* __restrict__ tab) {
  int i = blockIdx.x * blockDim.x + threadIdx.x;   // over TSEQ*32
  int pos = i >> 5, d = i & 31;
  float inv = exp2f(-(float)d * (13.287712379549449f / 32.0f));
  float sv, cv; sincosf((float)pos * inv, &sv, &cv);
  tab[i] = make_float2(cv, sv);
}

// ---------------- transpose + cast (batched over layers via blockIdx.z) ----------------
__global__ void transpose_cast_kernel(const float* __restrict__ src,
                                      unsigned short* __restrict__ dst,
                                      int K, int N, size_t sstride, size_t dstride) {
  __shared__ float tile[32][33];
  src += (size_t)blockIdx.z * sstride;
  dst += (size_t)blockIdx.z * dstride;
  int n0 = blockIdx.x * 32, k0 = blockIdx.y * 32;
  int tx = threadIdx.x, ty = threadIdx.y;  // 32 x 8
  #pragma unroll
  for (int i = 0; i < 4; ++i) {
    int r = ty + i * 8;
    tile[r][tx] = src[(size_t)(k0 + r) * N + n0 + tx];
  }
  __syncthreads();
  #pragma unroll
  for (int i = 0; i < 4; ++i) {
    int r = ty + i * 8;
    dst[(size_t)(n0 + r) * K + k0 + tx] = f2b(tile[tx][r]);
  }
}

// ---------------- embedding gather ----------------
__global__ void gather_kernel(const int* __restrict__ idx,
                              const float* __restrict__ embed,
                              float* __restrict__ x) {
  int row = blockIdx.x; int t = threadIdx.x;  // 192 threads, float4 each
  int id = idx[row];
  ((float4*)(x + (size_t)row * DM))[t] = ((const float4*)(embed + (size_t)id * DM))[t];
}

// ---------------- RMSNorm: f32 in -> bf16 out ----------------
__global__ void rmsnorm_kernel(const float* __restrict__ x,
                               const float* __restrict__ w,
                               unsigned short* __restrict__ out) {
  int row = blockIdx.x; int t = threadIdx.x;  // 256 threads, D=768
  const float* xr = x + (size_t)row * DM;
  float v0 = xr[t], v1 = xr[t + 256], v2 = xr[t + 512];
  float s = v0*v0 + v1*v1 + v2*v2;
  #pragma unroll
  for (int off = 1; off < 64; off <<= 1) s += __shfl_xor(s, off);
  __shared__ float red[4];
  if ((t & 63) == 0) red[t >> 6] = s;
  __syncthreads();
  float tot = red[0] + red[1] + red[2] + red[3];
  float rs = rsqrtf(tot * (1.0f / DM) + 1e-6f);
  unsigned short* orow = out + (size_t)row * DM;
  orow[t]       = f2b(w[t]       * v0 * rs);
  orow[t + 256] = f2b(w[t + 256] * v1 * rs);
  orow[t + 512] = f2b(w[t + 512] * v2 * rs);
}

// ---------------- 256x256 deep-pipelined GEMM (logits): C = A @ Bt^T, f32 out ----
// 512 threads = 8 waves (2M x 4N), BK=64, double-buffered 128KB LDS via
// global_load_lds; T2 XOR-swizzle (colbyte ^= (row&7)<<4) applied on the
// pre-swizzled global source AND the ds_read address (rule #21); counted
// vmcnt(8) so the next tile's 8 loads stay in flight across barriers (T3+T4).
__global__ __launch_bounds__(512, 1) void gemm_l8_kernel(
    const unsigned short* __restrict__ A, const unsigned short* __restrict__ Bt,
    float* __restrict__ C, int N, int K) {
  __shared__ unsigned short lds[2][2][256 * 64];   // [dbuf][A,B][row*64+col]
  const int NT = K >> 6;
  int bid = blockIdx.x, nwg = gridDim.x;
  int wgid = (bid & 7) * (nwg >> 3) + (bid >> 3);
  int m0 = (wgid & 7) * 256;        // 8 m-tiles (TSEQ/256)
  int n0 = (wgid >> 3) * 256;
  int tid = threadIdx.x;
  int lane = tid & 63, w = tid >> 6;
  int wm = w >> 2, wn = w & 3;
  int al = lane & 15, ag = lane >> 4;
  int swz = (al & 7) << 3;          // frag-read swizzle (shorts)

  // staging source: thread t covers LDS bytes j*8192 + t*16; row = j*64 + (t>>3),
  // source col pre-swizzled so linear LDS dest holds the swizzled image.
  int rA = tid >> 3;                                  // 0..63
  int cK = ((tid & 7) * 8) ^ ((rA & 7) << 3);         // bf16 col within 64
  const unsigned short* Ag = A + (size_t)(m0 + rA) * K + cK;
  const unsigned short* Bg = Bt + (size_t)(n0 + rA) * K + cK;

  f32x4 acc[8][4];
  #pragma unroll
  for (int i = 0; i < 8; ++i)
    #pragma unroll
    for (int n = 0; n < 4; ++n) acc[i][n] = (f32x4){0.f, 0.f, 0.f, 0.f};

  #define STAGE(kt, c) { \
    size_t ko = (size_t)(kt) * 64; \
    unsigned short* dA = &lds[(c)][0][0] + w * 512; \
    unsigned short* dB = &lds[(c)][1][0] + w * 512; \
    gl16(Ag + (size_t)0   * K + ko, dA);            \
    gl16(Ag + (size_t)64  * K + ko, dA + 4096);     \
    gl16(Ag + (size_t)128 * K + ko, dA + 8192);     \
    gl16(Ag + (size_t)192 * K + ko, dA + 12288);    \
    gl16(Bg + (size_t)0   * K + ko, dB);            \
    gl16(Bg + (size_t)64  * K + ko, dB + 4096);     \
    gl16(Bg + (size_t)128 * K + ko, dB + 8192);     \
    gl16(Bg + (size_t)192 * K + ko, dB + 12288);    \
  }

  STAGE(0, 0);
  STAGE(1, 1);
  asm volatile("s_waitcnt vmcnt(8)" ::: "memory");   // tile0's 8 loads done
  __builtin_amdgcn_s_barrier();

  for (int t = 0; t < NT; ++t) {
    int cur = t & 1;
    const unsigned short* La = &lds[cur][0][0];
    const unsigned short* Lb = &lds[cur][1][0];
    short8 a0[8], b0[4], a1[8], b1[4];
    #pragma unroll
    for (int i = 0; i < 8; ++i)
      a0[i] = *(const short8*)&La[(wm*128 + i*16 + al)*64 + ((ag*8) ^ swz)];
    #pragma unroll
    for (int n = 0; n < 4; ++n)
      b0[n] = *(const short8*)&Lb[(wn*64 + n*16 + al)*64 + ((ag*8) ^ swz)];
    #pragma unroll
    for (int i = 0; i < 8; ++i)
      #pragma unroll
      for (int n = 0; n < 4; ++n)
        acc[i][n] = __builtin_amdgcn_mfma_f32_16x16x32_bf16(a0[i], b0[n], acc[i][n], 0, 0, 0);
    #pragma unroll
    for (int i = 0; i < 8; ++i)
      a1[i] = *(const short8*)&La[(wm*128 + i*16 + al)*64 + ((32 + ag*8) ^ swz)];
    #pragma unroll
    for (int n = 0; n < 4; ++n)
      b1[n] = *(const short8*)&Lb[(wn*64 + n*16 + al)*64 + ((32 + ag*8) ^ swz)];
    asm volatile("s_waitcnt lgkmcnt(0)" ::: "memory");  // all reads of buf[cur] done
    __builtin_amdgcn_s_barrier();                       // before overwriting it
    if (t + 2 < NT) STAGE(t + 2, cur);
    __builtin_amdgcn_s_setprio(1);
    #pragma unroll
    for (int i = 0; i < 8; ++i)
      #pragma unroll
      for (int n = 0; n < 4; ++n)
        acc[i][n] = __builtin_amdgcn_mfma_f32_16x16x32_bf16(a1[i], b1[n], acc[i][n], 0, 0, 0);
    __builtin_amdgcn_s_setprio(0);
    if (t + 2 < NT) { asm volatile("s_waitcnt vmcnt(8)" ::: "memory"); }  // t+1 ready
    else            { asm volatile("s_waitcnt vmcnt(0)" ::: "memory"); }
    __builtin_amdgcn_s_barrier();
  }
  #undef STAGE

  // epilogue: C row = m0 + wm*128 + i*16 + ag*4 + r ; col = n0 + wn*64 + nf*16 + al
  #pragma unroll
  for (int i = 0; i < 8; ++i)
    #pragma unroll
    for (int r = 0; r < 4; ++r) {
      float* Cr = C + (size_t)(m0 + wm*128 + i*16 + ag*4 + r) * N + n0 + wn*64 + al;
      #pragma unroll
      for (int n = 0; n < 4; ++n) Cr[n * 16] = acc[i][n][r];
    }
}

// ---------------- GEMM: C[M][N] = A[M][K] @ Bt[N][K]^T (128x128) ----------------
// OUT: 2 = bf16 store, 3 = bf16 + fused RoPE (table), 4 = f32 atomicAdd (split-K)
template <int OUT>
__global__ __launch_bounds__(256) void gemm_bt_kernel(
    const unsigned short* __restrict__ A, const unsigned short* __restrict__ Bt,
    void* __restrict__ Cv, int N, int K, int Kc,
    const float2* __restrict__ rope_tab) {
  __shared__ unsigned short As[128 * 40];
  __shared__ unsigned short Bs[128 * 40];
  int bid = blockIdx.x, nwg = gridDim.x;
  int wgid = (bid & 7) * (nwg >> 3) + (bid >> 3);
  int m0 = (wgid & 15) * 128;
  int n0 = (wgid >> 4) * 128;
  int tid = threadIdx.x;
  int lane = tid & 63, wave = tid >> 6;
  int wr = (wave >> 1) * 64, wc = (wave & 1) * 64;
  int l16 = lane & 15, lk8 = (lane >> 4) * 8;
  f32x4 acc[4][4];
  #pragma unroll
  for (int m = 0; m < 4; ++m)
    #pragma unroll
    for (int n = 0; n < 4; ++n) acc[m][n] = (f32x4){0.f, 0.f, 0.f, 0.f};
  size_t koff = (size_t)blockIdx.y * Kc;
  const unsigned short* Abase = A + (size_t)m0 * K + koff;
  const unsigned short* Bbase = Bt + (size_t)n0 * K + koff;
  int r0 = tid >> 2;            // 0..63
  int c0 = (tid & 3) * 8;       // 0,8,16,24
  for (int k0 = 0; k0 < Kc; k0 += 32) {
    uint4 a0 = *(const uint4*)(Abase + (size_t)r0 * K + k0 + c0);
    uint4 a1 = *(const uint4*)(Abase + (size_t)(r0 + 64) * K + k0 + c0);
    uint4 b0 = *(const uint4*)(Bbase + (size_t)r0 * K + k0 + c0);
    uint4 b1 = *(const uint4*)(Bbase + (size_t)(r0 + 64) * K + k0 + c0);
    *(uint4*)&As[r0 * 40 + c0] = a0;
    *(uint4*)&As[(r0 + 64) * 40 + c0] = a1;
    *(uint4*)&Bs[r0 * 40 + c0] = b0;
    *(uint4*)&Bs[(r0 + 64) * 40 + c0] = b1;
    __syncthreads();
    short8 af[4], bfr[4];
    #pragma unroll
    for (int m = 0; m < 4; ++m) af[m]  = *(const short8*)&As[(wr + m*16 + l16) * 40 + lk8];
    #pragma unroll
    for (int n = 0; n < 4; ++n) bfr[n] = *(const short8*)&Bs[(wc + n*16 + l16) * 40 + lk8];
    #pragma unroll
    for (int m = 0; m < 4; ++m)
      #pragma unroll
      for (int n = 0; n < 4; ++n)
        acc[m][n] = __builtin_amdgcn_mfma_f32_16x16x32_bf16(af[m], bfr[n], acc[m][n], 0, 0, 0);
    __syncthreads();
  }
  // C/D layout: col = lane&15, row = (lane>>4)*4 + reg   [learn_hip m89/m91]
  if (OUT == 2) {
    unsigned short* C = (unsigned short*)Cv;
    #pragma unroll
    for (int m = 0; m < 4; ++m)
      #pragma unroll
      for (int r = 0; r < 4; ++r) {
        size_t row = (size_t)(m0 + wr + m*16 + ((lane >> 4) << 2) + r);
        unsigned short* Cr = C + row * N + n0 + wc + l16;
        #pragma unroll
        for (int n = 0; n < 4; ++n) Cr[n * 16] = f2b(acc[m][n][r]);
      }
  } else if (OUT == 3) {
    unsigned short* C = (unsigned short*)Cv;
    bool qk = (n0 + wc) < 1024;   // whole 64-col group is one q/k head
    #pragma unroll
    for (int m = 0; m < 4; ++m)
      #pragma unroll
      for (int r = 0; r < 4; ++r) {
        int pos = m0 + wr + m*16 + ((lane >> 4) << 2) + r;
        unsigned short* Cr = C + (size_t)pos * N + n0 + wc + l16;
        if (qk) {
          #pragma unroll
          for (int n = 0; n < 2; ++n) {
            int d = n * 16 + l16;                 // 0..31 within head
            float2 cs = rope_tab[pos * 32 + d];
            float x1 = acc[m][n][r], x2 = acc[m][n + 2][r];
            Cr[n * 16]       = f2b(x1 * cs.x - x2 * cs.y);
            Cr[(n + 2) * 16] = f2b(x2 * cs.x + x1 * cs.y);
          }
        } else {
          #pragma unroll
          for (int n = 0; n < 4; ++n) Cr[n * 16] = f2b(acc[m][n][r]);
        }
      }
  } else {
    float* C = (float*)Cv;
    #pragma unroll
    for (int m = 0; m < 4; ++m)
      #pragma unroll
      for (int r = 0; r < 4; ++r) {
        size_t row = (size_t)(m0 + wr + m*16 + ((lane >> 4) << 2) + r);
        float* Cr = C + row * N + n0 + wc + l16;
        #pragma unroll
        for (int n = 0; n < 4; ++n) atomicAdd(&Cr[n * 16], acc[m][n][r]);
      }
  }
}

// ---------------- gelu ----------------
__device__ __forceinline__ float gelu_t(float x) {
  float x3 = x * x * x;
  return 0.5f * x * (1.0f + tanhf(0.7978845608028654f * (x + 0.044715f * x3)));
}

// ---------------- fused gate/up GEMM + gelu-mul: m = gelu(h@Wg) * (h@Wu) ----------------
__global__ __launch_bounds__(256) void gemm_gu_kernel(
    const unsigned short* __restrict__ A, const unsigned short* __restrict__ BtG,
    const unsigned short* __restrict__ BtU, unsigned short* __restrict__ Cm) {
  __shared__ unsigned short As[128 * 40];
  __shared__ unsigned short Bg[128 * 40];
  __shared__ unsigned short Bu[128 * 40];
  const int K = DM;
  int bid = blockIdx.x, nwg = gridDim.x;        // 256 blocks
  int wgid = (bid & 7) * (nwg >> 3) + (bid >> 3);
  int m0 = (wgid & 15) * 128;
  int n0 = (wgid >> 4) * 128;                   // over FF (2048)
  int tid = threadIdx.x;
  int lane = tid & 63, wave = tid >> 6;
  int wr = (wave >> 1) * 64, wc = (wave & 1) * 64;
  int l16 = lane & 15, lk8 = (lane >> 4) * 8;
  f32x4 accg[4][4], accu[4][4];
  #pragma unroll
  for (int m = 0; m < 4; ++m)
    #pragma unroll
    for (int n = 0; n < 4; ++n) {
      accg[m][n] = (f32x4){0.f, 0.f, 0.f, 0.f};
      accu[m][n] = (f32x4){0.f, 0.f, 0.f, 0.f};
    }
  const unsigned short* Abase = A + (size_t)m0 * K;
  const unsigned short* Gbase = BtG + (size_t)n0 * K;
  const unsigned short* Ubase = BtU + (size_t)n0 * K;
  int r0 = tid >> 2;
  int c0 = (tid & 3) * 8;
  for (int k0 = 0; k0 < K; k0 += 32) {
    uint4 a0 = *(const uint4*)(Abase + (size_t)r0 * K + k0 + c0);
    uint4 a1 = *(const uint4*)(Abase + (size_t)(r0 + 64) * K + k0 + c0);
    uint4 g0 = *(const uint4*)(Gbase + (size_t)r0 * K + k0 + c0);
    uint4 g1 = *(const uint4*)(Gbase + (size_t)(r0 + 64) * K + k0 + c0);
    uint4 u0 = *(const uint4*)(Ubase + (size_t)r0 * K + k0 + c0);
    uint4 u1 = *(const uint4*)(Ubase + (size_t)(r0 + 64) * K + k0 + c0);
    *(uint4*)&As[r0 * 40 + c0] = a0;
    *(uint4*)&As[(r0 + 64) * 40 + c0] = a1;
    *(uint4*)&Bg[r0 * 40 + c0] = g0;
    *(uint4*)&Bg[(r0 + 64) * 40 + c0] = g1;
    *(uint4*)&Bu[r0 * 40 + c0] = u0;
    *(uint4*)&Bu[(r0 + 64) * 40 + c0] = u1;
    __syncthreads();
    short8 af[4], bg[4], bu[4];
    #pragma unroll
    for (int m = 0; m < 4; ++m) af[m] = *(const short8*)&As[(wr + m*16 + l16) * 40 + lk8];
    #pragma unroll
    for (int n = 0; n < 4; ++n) {
      bg[n] = *(const short8*)&Bg[(wc + n*16 + l16) * 40 + lk8];
      bu[n] = *(const short8*)&Bu[(wc + n*16 + l16) * 40 + lk8];
    }
    #pragma unroll
    for (int m = 0; m < 4; ++m)
      #pragma unroll
      for (int n = 0; n < 4; ++n) {
        accg[m][n] = __builtin_amdgcn_mfma_f32_16x16x32_bf16(af[m], bg[n], accg[m][n], 0, 0, 0);
        accu[m][n] = __builtin_amdgcn_mfma_f32_16x16x32_bf16(af[m], bu[n], accu[m][n], 0, 0, 0);
      }
    __syncthreads();
  }
  #pragma unroll
  for (int m = 0; m < 4; ++m)
    #pragma unroll
    for (int r = 0; r < 4; ++r) {
      size_t row = (size_t)(m0 + wr + m*16 + ((lane >> 4) << 2) + r);
      unsigned short* Cr = Cm + row * FFD + n0 + wc + l16;
      #pragma unroll
      for (int n = 0; n < 4; ++n)
        Cr[n * 16] = f2b(gelu_t(accg[m][n][r]) * accu[m][n][r]);
    }
}

// ---------------- MFMA flash attention, causal, GQA ----------------
__global__ __launch_bounds__(256) void attn_mfma_kernel(
    const unsigned short* __restrict__ qkv, unsigned short* __restrict__ out) {
  __shared__ unsigned short Ks[64 * 64];
  __shared__ unsigned short Vt[64 * 64];
  __shared__ unsigned short Ps[4][16 * 64];
  int h = blockIdx.y;
  int qt = gridDim.x - 1 - blockIdx.x;   // heavy (deep-causal) blocks dispatch first
  int r0 = qt * 64;
  int kvh = h / 3;           // N_REP = 3
  int t = threadIdx.x;
  int lane = t & 63, w = t >> 6;
  int l16 = lane & 15, g = lane >> 4;

  int qr = r0 + w * 16 + l16;
  const unsigned short* qrow = qkv + (size_t)qr * QKVN + h * HD;
  short8 aq0 = *(const short8*)(qrow + 8 * g);
  short8 aq1 = *(const short8*)(qrow + 32 + 8 * g);

  f32x4 o_acc[4];
  float mrun[4], lrun[4];
  #pragma unroll
  for (int i = 0; i < 4; ++i) { o_acc[i] = (f32x4){0.f,0.f,0.f,0.f}; mrun[i] = -1e30f; lrun[i] = 0.f; }

  int nt = qt + 1;
  for (int kt = 0; kt < nt; ++kt) {
    int kb = kt * 64;
    if (kt) __syncthreads();
    {
      const unsigned short* krow = qkv + (size_t)(kb + lane) * QKVN + DM + kvh * HD + 16 * w;
      uint4 k0 = ((const uint4*)krow)[0];
      uint4 k1 = ((const uint4*)krow)[1];
      uint4 v0 = ((const uint4*)(krow + NKV * HD))[0];
      uint4 v1 = ((const uint4*)(krow + NKV * HD))[1];
      int k7 = lane & 7;
      *(uint4*)&Ks[lane * 64 + (((2*w)     ^ k7) << 3)] = k0;
      *(uint4*)&Ks[lane * 64 + (((2*w + 1) ^ k7) << 3)] = k1;
      unsigned short tv[16];
      *(uint4*)&tv[0] = v0; *(uint4*)&tv[8] = v1;
      #pragma unroll
      for (int j = 0; j < 16; ++j) {
        int d = 16 * w + j;
        Vt[d * 64 + ((((lane >> 3) ^ (d & 7)) << 3) + (lane & 7))] = tv[j];
      }
    }
    __syncthreads();

    f32x4 s_acc[4];
    #pragma unroll
    for (int nb = 0; nb < 4; ++nb) s_acc[nb] = (f32x4){0.f,0.f,0.f,0.f};
    #pragma unroll
    for (int nb = 0; nb < 4; ++nb) {
      int key = nb * 16 + l16;
      short8 bk0 = *(const short8*)&Ks[key * 64 + ((g       ^ (key & 7)) << 3)];
      short8 bk1 = *(const short8*)&Ks[key * 64 + (((4 + g) ^ (key & 7)) << 3)];
      s_acc[nb] = __builtin_amdgcn_mfma_f32_16x16x32_bf16(aq0, bk0, s_acc[nb], 0, 0, 0);
      s_acc[nb] = __builtin_amdgcn_mfma_f32_16x16x32_bf16(aq1, bk1, s_acc[nb], 0, 0, 0);
    }

    bool diag = (kt == qt);
    #pragma unroll
    for (int r = 0; r < 4; ++r) {
      int qg = r0 + w * 16 + g * 4 + r;
      float sv[4];
      #pragma unroll
      for (int nb = 0; nb < 4; ++nb) {
        sv[nb] = s_acc[nb][r] * 0.125f;
        if (diag && (kb + nb * 16 + l16 > qg)) sv[nb] = -1e30f;
      }
      float mx = fmaxf(fmaxf(sv[0], sv[1]), fmaxf(sv[2], sv[3]));
      mx = fmaxf(mx, __shfl_xor(mx, 1));
      mx = fmaxf(mx, __shfl_xor(mx, 2));
      mx = fmaxf(mx, __shfl_xor(mx, 4));
      mx = fmaxf(mx, __shfl_xor(mx, 8));
      float mnew = fmaxf(mrun[r], mx);
      float es = __expf(mrun[r] - mnew);
      float rs = 0.f;
      #pragma unroll
      for (int nb = 0; nb < 4; ++nb) { sv[nb] = __expf(sv[nb] - mnew); rs += sv[nb]; }
      rs += __shfl_xor(rs, 1);
      rs += __shfl_xor(rs, 2);
      rs += __shfl_xor(rs, 4);
      rs += __shfl_xor(rs, 8);
      lrun[r] = lrun[r] * es + rs;
      mrun[r] = mnew;
      #pragma unroll
      for (int db = 0; db < 4; ++db) o_acc[db][r] *= es;
      int qloc = g * 4 + r, q7 = qloc & 7;
      #pragma unroll
      for (int nb = 0; nb < 4; ++nb) {
        int key = nb * 16 + l16;
        Ps[w][qloc * 64 + ((((key >> 3) ^ q7) << 3) + (key & 7))] = f2b(sv[nb]);
      }
    }

    #pragma unroll
    for (int kc = 0; kc < 2; ++kc) {
      short8 pa = *(const short8*)&Ps[w][l16 * 64 + (((4 * kc + g) ^ (l16 & 7)) << 3)];
      #pragma unroll
      for (int db = 0; db < 4; ++db) {
        int d = db * 16 + l16;
        short8 bv = *(const short8*)&Vt[d * 64 + (((4 * kc + g) ^ (d & 7)) << 3)];
        o_acc[db] = __builtin_amdgcn_mfma_f32_16x16x32_bf16(pa, bv, o_acc[db], 0, 0, 0);
      }
    }
  }

  #pragma unroll
  for (int r = 0; r < 4; ++r) {
    int qg = r0 + w * 16 + g * 4 + r;
    float inv = 1.0f / lrun[r];
    unsigned short* orow = out + (size_t)qg * DM + h * HD + l16;
    #pragma unroll
    for (int db = 0; db < 4; ++db) orow[db * 16] = f2b(o_acc[db][r] * inv);
  }
}

extern "C" void kernel_launch(void* const* d_in, const int* in_sizes, int n_in,
                              void* d_out, int out_size, void* d_ws, size_t ws_size,
                              hipStream_t stream) {
  const int*   idx   = (const int*)d_in[0];
  const float* embed = (const float*)d_in[1];
  const float* ln1   = (const float*)d_in[2];
  const float* Wq    = (const float*)d_in[3];
  const float* Wk    = (const float*)d_in[4];
  const float* Wv    = (const float*)d_in[5];
  const float* Wo    = (const float*)d_in[6];
  const float* ln2   = (const float*)d_in[7];
  const float* Wg    = (const float*)d_in[8];
  const float* Wu    = (const float*)d_in[9];
  const float* Wd    = (const float*)d_in[10];
  const float* normf = (const float*)d_in[11];
  float* out = (float*)d_out;
  char* ws = (char*)d_ws;
  (void)in_sizes; (void)n_in; (void)out_size; (void)ws_size;

  // ---- workspace layout ----
  unsigned short* embed_bf = (unsigned short*)ws;
  size_t off = (size_t)VOC * DM * 2;
  unsigned short* wts = (unsigned short*)(ws + off);
  const size_t LW = (size_t)QKVN * DM + (size_t)DM * DM
                  + 2ull * FFD * DM + (size_t)DM * FFD;
  off += LW * 2ull * NL;
  float* xf = (float*)(ws + off);            off += (size_t)TSEQ * DM * 4;
  unsigned short* h_bf = (unsigned short*)(ws + off);    off += (size_t)TSEQ * DM * 2;
  unsigned short* qkv_bf = (unsigned short*)(ws + off);  off += (size_t)TSEQ * QKVN * 2;
  unsigned short* attn_bf = (unsigned short*)(ws + off); off += (size_t)TSEQ * DM * 2;
  unsigned short* m_bf = (unsigned short*)(ws + off);    off += (size_t)TSEQ * FFD * 2;
  float2* rope_tab = (float2*)(ws + off);    off += (size_t)TSEQ * 32 * 8;

  // ---- prep: embed cast + rope table + batched weight transpose/cast ----
  cast_bf16_kernel<<<(VOC * DM / 4 + 255) / 256, 256, 0, stream>>>(embed, embed_bf, VOC * DM / 4);
  rope_tab_kernel<<<TSEQ * 32 / 256, 256, 0, stream>>>(rope_tab);

  {
    unsigned short* qkvT = wts;
    unsigned short* woT  = wts + (size_t)QKVN * DM;
    unsigned short* wguT = woT + (size_t)DM * DM;
    unsigned short* wdT  = wguT + 2ull * FFD * DM;
    transpose_cast_kernel<<<dim3(24, 24, NL), dim3(32, 8), 0, stream>>>(Wq, qkvT, 768, 768, 589824, LW);
    transpose_cast_kernel<<<dim3(8, 24, NL),  dim3(32, 8), 0, stream>>>(Wk, qkvT + 768ull * 768, 768, 256, 196608, LW);
    transpose_cast_kernel<<<dim3(8, 24, NL),  dim3(32, 8), 0, stream>>>(Wv, qkvT + 1024ull * 768, 768, 256, 196608, LW);
    transpose_cast_kernel<<<dim3(24, 24, NL), dim3(32, 8), 0, stream>>>(Wo, woT, 768, 768, 589824, LW);
    transpose_cast_kernel<<<dim3(64, 24, NL), dim3(32, 8), 0, stream>>>(Wg, wguT, 768, 2048, 1572864, LW);
    transpose_cast_kernel<<<dim3(64, 24, NL), dim3(32, 8), 0, stream>>>(Wu, wguT + (size_t)FFD * DM, 768, 2048, 1572864, LW);
    transpose_cast_kernel<<<dim3(24, 64, NL), dim3(32, 8), 0, stream>>>(Wd, wdT, 2048, 768, 1572864, LW);
  }

  gather_kernel<<<TSEQ, 192, 0, stream>>>(idx, embed, xf);

  for (int l = 0; l < NL; ++l) {
    unsigned short* base = wts + (size_t)l * LW;
    unsigned short* qkvT = base;
    unsigned short* woT  = base + (size_t)QKVN * DM;
    unsigned short* wguT = woT + (size_t)DM * DM;
    unsigned short* wdT  = wguT + 2ull * FFD * DM;

    rmsnorm_kernel<<<TSEQ, 256, 0, stream>>>(xf, ln1 + (size_t)l * DM, h_bf);
    gemm_bt_kernel<3><<<dim3((QKVN / 128) * 16, 1), 256, 0, stream>>>(h_bf, qkvT, qkv_bf, QKVN, DM, DM, rope_tab);
    attn_mfma_kernel<<<dim3(TSEQ / 64, NH), 256, 0, stream>>>(qkv_bf, attn_bf);
    gemm_bt_kernel<4><<<dim3((DM / 128) * 16, 3), 256, 0, stream>>>(attn_bf, woT, xf, DM, DM, 256, rope_tab);
    rmsnorm_kernel<<<TSEQ, 256, 0, stream>>>(xf, ln2 + (size_t)l * DM, h_bf);
    gemm_gu_kernel<<<(FFD / 128) * 16, 256, 0, stream>>>(h_bf, wguT, wguT + (size_t)FFD * DM, m_bf);
    gemm_bt_kernel<4><<<dim3((DM / 128) * 16, 4), 256, 0, stream>>>(m_bf, wdT, xf, DM, FFD, 512, rope_tab);
  }

  rmsnorm_kernel<<<TSEQ, 256, 0, stream>>>(xf, normf, h_bf);
  // 256x256 deep-pipelined logits GEMM: 8 m-tiles x 125 n-tiles = 1000 blocks
  gemm_l8_kernel<<<(VOC / 256) * (TSEQ / 256), 512, 0, stream>>>(h_bf, embed_bf, out, VOC, DM);
}

// Round 7
// 931.711 us; speedup vs baseline: 1.3375x; 1.1148x over previous
//
#include <hip/hip_runtime.h>

#define TSEQ 2048
#define DM   768
#define NH   12
#define NKV  4
#define HD   64
#define FFD  2048
#define NL   4
#define VOC  32000
#define QKVN 1280   // 768 q + 256 k + 256 v

typedef __attribute__((ext_vector_type(8))) short short8;
typedef __attribute__((ext_vector_type(4))) float f32x4;

__device__ __forceinline__ unsigned short f2b(float f) {
  unsigned int u = __float_as_uint(f);
  u += 0x7fffu + ((u >> 16) & 1u);
  return (unsigned short)(u >> 16);
}
__device__ __forceinline__ float b2f(unsigned short u) {
  return __uint_as_float(((unsigned int)u) << 16);
}
__device__ __forceinline__ unsigned int packbf(float a, float b) {
  return (unsigned int)f2b(a) | ((unsigned int)f2b(b) << 16);
}

// direct global->LDS async copy, 16B/lane; LDS dest wave-uniform (HW adds lane*16)
__device__ __forceinline__ void gl16(const unsigned short* g, unsigned short* l) {
  __builtin_amdgcn_global_load_lds(
      (const __attribute__((address_space(1))) void*)g,
      (__attribute__((address_space(3))) void*)l, 16, 0, 0);
}

// ---------------- cast f32 -> bf16 (vectorized x4) ----------------
__global__ void cast_bf16_kernel(const float* __restrict__ src,
                                 unsigned short* __restrict__ dst, int n4) {
  int i = blockIdx.x * blockDim.x + threadIdx.x;
  if (i >= n4) return;
  float4 v = ((const float4*)src)[i];
  uint2 o; o.x = packbf(v.x, v.y); o.y = packbf(v.z, v.w);
  ((uint2*)dst)[i] = o;
}

// ---------------- RoPE cos/sin table: [pos][d] for d in 0..31 ----------------
__global__ void rope_tab_kernel(float2* __restrict__ tab) {
  int i = blockIdx.x * blockDim.x + threadIdx.x;   // over TSEQ*32
  int pos = i >> 5, d = i & 31;
  float inv = exp2f(-(float)d * (13.287712379549449f / 32.0f));
  float sv, cv; sincosf((float)pos * inv, &sv, &cv);
  tab[i] = make_float2(cv, sv);
}

// ---------------- transpose + cast (batched over layers via blockIdx.z) ----------------
__global__ void transpose_cast_kernel(const float* __restrict__ src,
                                      unsigned short* __restrict__ dst,
                                      int K, int N, size_t sstride, size_t dstride) {
  __shared__ float tile[32][33];
  src += (size_t)blockIdx.z * sstride;
  dst += (size_t)blockIdx.z * dstride;
  int n0 = blockIdx.x * 32, k0 = blockIdx.y * 32;
  int tx = threadIdx.x, ty = threadIdx.y;  // 32 x 8
  #pragma unroll
  for (int i = 0; i < 4; ++i) {
    int r = ty + i * 8;
    tile[r][tx] = src[(size_t)(k0 + r) * N + n0 + tx];
  }
  __syncthreads();
  #pragma unroll
  for (int i = 0; i < 4; ++i) {
    int r = ty + i * 8;
    dst[(size_t)(n0 + r) * K + k0 + tx] = f2b(tile[tx][r]);
  }
}

// ---------------- embedding gather ----------------
__global__ void gather_kernel(const int* __restrict__ idx,
                              const float* __restrict__ embed,
                              float* __restrict__ x) {
  int row = blockIdx.x; int t = threadIdx.x;  // 192 threads, float4 each
  int id = idx[row];
  ((float4*)(x + (size_t)row * DM))[t] = ((const float4*)(embed + (size_t)id * DM))[t];
}

// ---------------- RMSNorm: f32 in -> bf16 out ----------------
__global__ void rmsnorm_kernel(const float* __restrict__ x,
                               const float* __restrict__ w,
                               unsigned short* __restrict__ out) {
  int row = blockIdx.x; int t = threadIdx.x;  // 256 threads, D=768
  const float* xr = x + (size_t)row * DM;
  float v0 = xr[t], v1 = xr[t + 256], v2 = xr[t + 512];
  float s = v0*v0 + v1*v1 + v2*v2;
  #pragma unroll
  for (int off = 1; off < 64; off <<= 1) s += __shfl_xor(s, off);
  __shared__ float red[4];
  if ((t & 63) == 0) red[t >> 6] = s;
  __syncthreads();
  float tot = red[0] + red[1] + red[2] + red[3];
  float rs = rsqrtf(tot * (1.0f / DM) + 1e-6f);
  unsigned short* orow = out + (size_t)row * DM;
  orow[t]       = f2b(w[t]       * v0 * rs);
  orow[t + 256] = f2b(w[t + 256] * v1 * rs);
  orow[t + 512] = f2b(w[t + 512] * v2 * rs);
}

// ---------------- 256x256 deep-pipelined GEMM (logits): C = A @ Bt^T, f32 out ----
__global__ __launch_bounds__(512, 1) void gemm_l8_kernel(
    const unsigned short* __restrict__ A, const unsigned short* __restrict__ Bt,
    float* __restrict__ C, int N, int K) {
  __shared__ unsigned short lds[2][2][256 * 64];   // [dbuf][A,B][row*64+col]
  const int NT = K >> 6;
  int bid = blockIdx.x, nwg = gridDim.x;
  int wgid = (bid & 7) * (nwg >> 3) + (bid >> 3);
  int m0 = (wgid & 7) * 256;        // 8 m-tiles (TSEQ/256)
  int n0 = (wgid >> 3) * 256;
  int tid = threadIdx.x;
  int lane = tid & 63, w = tid >> 6;
  int wm = w >> 2, wn = w & 3;
  int al = lane & 15, ag = lane >> 4;
  int swz = (al & 7) << 3;          // frag-read swizzle (shorts)

  int rA = tid >> 3;                                  // 0..63
  int cK = ((tid & 7) * 8) ^ ((rA & 7) << 3);         // bf16 col within 64
  const unsigned short* Ag = A + (size_t)(m0 + rA) * K + cK;
  const unsigned short* Bg = Bt + (size_t)(n0 + rA) * K + cK;

  f32x4 acc[8][4];
  #pragma unroll
  for (int i = 0; i < 8; ++i)
    #pragma unroll
    for (int n = 0; n < 4; ++n) acc[i][n] = (f32x4){0.f, 0.f, 0.f, 0.f};

  #define STAGE(kt, c) { \
    size_t ko = (size_t)(kt) * 64; \
    unsigned short* dA = &lds[(c)][0][0] + w * 512; \
    unsigned short* dB = &lds[(c)][1][0] + w * 512; \
    gl16(Ag + (size_t)0   * K + ko, dA);            \
    gl16(Ag + (size_t)64  * K + ko, dA + 4096);     \
    gl16(Ag + (size_t)128 * K + ko, dA + 8192);     \
    gl16(Ag + (size_t)192 * K + ko, dA + 12288);    \
    gl16(Bg + (size_t)0   * K + ko, dB);            \
    gl16(Bg + (size_t)64  * K + ko, dB + 4096);     \
    gl16(Bg + (size_t)128 * K + ko, dB + 8192);     \
    gl16(Bg + (size_t)192 * K + ko, dB + 12288);    \
  }

  STAGE(0, 0);
  STAGE(1, 1);
  asm volatile("s_waitcnt vmcnt(8)" ::: "memory");
  __builtin_amdgcn_s_barrier();

  for (int t = 0; t < NT; ++t) {
    int cur = t & 1;
    const unsigned short* La = &lds[cur][0][0];
    const unsigned short* Lb = &lds[cur][1][0];
    short8 a0[8], b0[4], a1[8], b1[4];
    #pragma unroll
    for (int i = 0; i < 8; ++i)
      a0[i] = *(const short8*)&La[(wm*128 + i*16 + al)*64 + ((ag*8) ^ swz)];
    #pragma unroll
    for (int n = 0; n < 4; ++n)
      b0[n] = *(const short8*)&Lb[(wn*64 + n*16 + al)*64 + ((ag*8) ^ swz)];
    #pragma unroll
    for (int i = 0; i < 8; ++i)
      #pragma unroll
      for (int n = 0; n < 4; ++n)
        acc[i][n] = __builtin_amdgcn_mfma_f32_16x16x32_bf16(a0[i], b0[n], acc[i][n], 0, 0, 0);
    #pragma unroll
    for (int i = 0; i < 8; ++i)
      a1[i] = *(const short8*)&La[(wm*128 + i*16 + al)*64 + ((32 + ag*8) ^ swz)];
    #pragma unroll
    for (int n = 0; n < 4; ++n)
      b1[n] = *(const short8*)&Lb[(wn*64 + n*16 + al)*64 + ((32 + ag*8) ^ swz)];
    asm volatile("s_waitcnt lgkmcnt(0)" ::: "memory");
    __builtin_amdgcn_s_barrier();
    if (t + 2 < NT) STAGE(t + 2, cur);
    __builtin_amdgcn_s_setprio(1);
    #pragma unroll
    for (int i = 0; i < 8; ++i)
      #pragma unroll
      for (int n = 0; n < 4; ++n)
        acc[i][n] = __builtin_amdgcn_mfma_f32_16x16x32_bf16(a1[i], b1[n], acc[i][n], 0, 0, 0);
    __builtin_amdgcn_s_setprio(0);
    if (t + 2 < NT) { asm volatile("s_waitcnt vmcnt(8)" ::: "memory"); }
    else            { asm volatile("s_waitcnt vmcnt(0)" ::: "memory"); }
    __builtin_amdgcn_s_barrier();
  }
  #undef STAGE

  #pragma unroll
  for (int i = 0; i < 8; ++i)
    #pragma unroll
    for (int r = 0; r < 4; ++r) {
      float* Cr = C + (size_t)(m0 + wm*128 + i*16 + ag*4 + r) * N + n0 + wn*64 + al;
      #pragma unroll
      for (int n = 0; n < 4; ++n) Cr[n * 16] = acc[i][n][r];
    }
}

// ---------------- 128x128 pipelined 8-wave GEMM, split-K, f32 atomicAdd ----------
// Same schedule as l8: BK=64 dbuf, counted vmcnt(4), both-sides swizzle.
// Wave (wm,wn) of 2Mx4N owns 64x32 out; 4 loads/wave/tile; 64KB LDS.
__global__ __launch_bounds__(512) void gemm_p8_kernel(
    const unsigned short* __restrict__ A, const unsigned short* __restrict__ Bt,
    float* __restrict__ C, int N, int K, int Kc) {
  __shared__ unsigned short lds[2][2][128 * 64];
  const int NT = Kc >> 6;
  int bid = blockIdx.x, nwg = gridDim.x;
  int wgid = (bid & 7) * (nwg >> 3) + (bid >> 3);
  int m0 = (wgid & 15) * 128;
  int n0 = (wgid >> 4) * 128;
  int tid = threadIdx.x;
  int lane = tid & 63, w = tid >> 6;
  int wm = w >> 2, wn = w & 3;
  int al = lane & 15, ag = lane >> 4;
  int swz = (al & 7) << 3;

  size_t koff = (size_t)blockIdx.y * Kc;
  int rp = 8 * w + (lane >> 3);                    // wave stages rows rp, rp+64
  int cK = ((lane & 7) * 8) ^ ((lane >> 3) << 3);
  const unsigned short* Ag = A + (size_t)(m0 + rp) * K + koff + cK;
  const unsigned short* Bg = Bt + (size_t)(n0 + rp) * K + koff + cK;

  f32x4 acc[4][2];
  #pragma unroll
  for (int i = 0; i < 4; ++i)
    #pragma unroll
    for (int n = 0; n < 2; ++n) acc[i][n] = (f32x4){0.f, 0.f, 0.f, 0.f};

  #define STAGE(kt, c) { \
    size_t ko = (size_t)(kt) * 64; \
    unsigned short* dA = &lds[(c)][0][0] + w * 512; \
    unsigned short* dB = &lds[(c)][1][0] + w * 512; \
    gl16(Ag + ko,                 dA);        \
    gl16(Ag + (size_t)64*K + ko,  dA + 4096); \
    gl16(Bg + ko,                 dB);        \
    gl16(Bg + (size_t)64*K + ko,  dB + 4096); \
  }

  STAGE(0, 0);
  STAGE(1, 1);
  asm volatile("s_waitcnt vmcnt(4)" ::: "memory");
  __builtin_amdgcn_s_barrier();

  for (int t = 0; t < NT; ++t) {
    int cur = t & 1;
    const unsigned short* La = &lds[cur][0][0];
    const unsigned short* Lb = &lds[cur][1][0];
    short8 a0[4], b0[2], a1[4], b1[2];
    #pragma unroll
    for (int i = 0; i < 4; ++i)
      a0[i] = *(const short8*)&La[(wm*64 + i*16 + al)*64 + ((ag*8) ^ swz)];
    #pragma unroll
    for (int n = 0; n < 2; ++n)
      b0[n] = *(const short8*)&Lb[(wn*32 + n*16 + al)*64 + ((ag*8) ^ swz)];
    #pragma unroll
    for (int i = 0; i < 4; ++i)
      #pragma unroll
      for (int n = 0; n < 2; ++n)
        acc[i][n] = __builtin_amdgcn_mfma_f32_16x16x32_bf16(a0[i], b0[n], acc[i][n], 0, 0, 0);
    #pragma unroll
    for (int i = 0; i < 4; ++i)
      a1[i] = *(const short8*)&La[(wm*64 + i*16 + al)*64 + ((32 + ag*8) ^ swz)];
    #pragma unroll
    for (int n = 0; n < 2; ++n)
      b1[n] = *(const short8*)&Lb[(wn*32 + n*16 + al)*64 + ((32 + ag*8) ^ swz)];
    asm volatile("s_waitcnt lgkmcnt(0)" ::: "memory");
    __builtin_amdgcn_s_barrier();
    if (t + 2 < NT) STAGE(t + 2, cur);
    __builtin_amdgcn_s_setprio(1);
    #pragma unroll
    for (int i = 0; i < 4; ++i)
      #pragma unroll
      for (int n = 0; n < 2; ++n)
        acc[i][n] = __builtin_amdgcn_mfma_f32_16x16x32_bf16(a1[i], b1[n], acc[i][n], 0, 0, 0);
    __builtin_amdgcn_s_setprio(0);
    if (t + 2 < NT) { asm volatile("s_waitcnt vmcnt(4)" ::: "memory"); }
    else            { asm volatile("s_waitcnt vmcnt(0)" ::: "memory"); }
    __builtin_amdgcn_s_barrier();
  }
  #undef STAGE

  #pragma unroll
  for (int i = 0; i < 4; ++i)
    #pragma unroll
    for (int r = 0; r < 4; ++r) {
      float* Cr = C + (size_t)(m0 + wm*64 + i*16 + ag*4 + r) * N + n0 + wn*32 + al;
      #pragma unroll
      for (int n = 0; n < 2; ++n) atomicAdd(&Cr[n * 16], acc[i][n][r]);
    }
}

// ---------------- gelu ----------------
__device__ __forceinline__ float gelu_t(float x) {
  float x3 = x * x * x;
  return 0.5f * x * (1.0f + tanhf(0.7978845608028654f * (x + 0.044715f * x3)));
}

// ---- pipelined gate/up GEMM: tile 128 rows x [G128|U128], 8 waves, BK=64 ----
// Wave (wm,wn): 64 rows x (32 G-cols + 32 U-cols) -> epilogue gelu(g)*u local.
__global__ __launch_bounds__(512) void gemm_gu8_kernel(
    const unsigned short* __restrict__ A, const unsigned short* __restrict__ BtG,
    const unsigned short* __restrict__ BtU, unsigned short* __restrict__ Cm) {
  __shared__ unsigned short lds[2][3][128 * 64];   // [dbuf][A,G,U]
  const int K = DM;
  const int NT = K >> 6;                           // 12
  int bid = blockIdx.x, nwg = gridDim.x;           // 256
  int wgid = (bid & 7) * (nwg >> 3) + (bid >> 3);
  int m0 = (wgid & 15) * 128;
  int n0 = (wgid >> 4) * 128;                      // over FF
  int tid = threadIdx.x;
  int lane = tid & 63, w = tid >> 6;
  int wm = w >> 2, wn = w & 3;
  int al = lane & 15, ag = lane >> 4;
  int swz = (al & 7) << 3;

  int rp = 8 * w + (lane >> 3);
  int cK = ((lane & 7) * 8) ^ ((lane >> 3) << 3);
  const unsigned short* Ag = A + (size_t)(m0 + rp) * K + cK;
  const unsigned short* Gg = BtG + (size_t)(n0 + rp) * K + cK;
  const unsigned short* Ug = BtU + (size_t)(n0 + rp) * K + cK;

  f32x4 accg[4][2], accu[4][2];
  #pragma unroll
  for (int i = 0; i < 4; ++i)
    #pragma unroll
    for (int n = 0; n < 2; ++n) {
      accg[i][n] = (f32x4){0.f, 0.f, 0.f, 0.f};
      accu[i][n] = (f32x4){0.f, 0.f, 0.f, 0.f};
    }

  #define STAGE(kt, c) { \
    size_t ko = (size_t)(kt) * 64; \
    unsigned short* dA = &lds[(c)][0][0] + w * 512; \
    unsigned short* dG = &lds[(c)][1][0] + w * 512; \
    unsigned short* dU = &lds[(c)][2][0] + w * 512; \
    gl16(Ag + ko,                 dA);        \
    gl16(Ag + (size_t)64*K + ko,  dA + 4096); \
    gl16(Gg + ko,                 dG);        \
    gl16(Gg + (size_t)64*K + ko,  dG + 4096); \
    gl16(Ug + ko,                 dU);        \
    gl16(Ug + (size_t)64*K + ko,  dU + 4096); \
  }

  STAGE(0, 0);
  STAGE(1, 1);
  asm volatile("s_waitcnt vmcnt(6)" ::: "memory");
  __builtin_amdgcn_s_barrier();

  for (int t = 0; t < NT; ++t) {
    int cur = t & 1;
    const unsigned short* La = &lds[cur][0][0];
    const unsigned short* Lg = &lds[cur][1][0];
    const unsigned short* Lu = &lds[cur][2][0];
    short8 a0[4], g0[2], u0[2], a1[4], g1[2], u1[2];
    #pragma unroll
    for (int i = 0; i < 4; ++i)
      a0[i] = *(const short8*)&La[(wm*64 + i*16 + al)*64 + ((ag*8) ^ swz)];
    #pragma unroll
    for (int n = 0; n < 2; ++n) {
      g0[n] = *(const short8*)&Lg[(wn*32 + n*16 + al)*64 + ((ag*8) ^ swz)];
      u0[n] = *(const short8*)&Lu[(wn*32 + n*16 + al)*64 + ((ag*8) ^ swz)];
    }
    #pragma unroll
    for (int i = 0; i < 4; ++i)
      #pragma unroll
      for (int n = 0; n < 2; ++n) {
        accg[i][n] = __builtin_amdgcn_mfma_f32_16x16x32_bf16(a0[i], g0[n], accg[i][n], 0, 0, 0);
        accu[i][n] = __builtin_amdgcn_mfma_f32_16x16x32_bf16(a0[i], u0[n], accu[i][n], 0, 0, 0);
      }
    #pragma unroll
    for (int i = 0; i < 4; ++i)
      a1[i] = *(const short8*)&La[(wm*64 + i*16 + al)*64 + ((32 + ag*8) ^ swz)];
    #pragma unroll
    for (int n = 0; n < 2; ++n) {
      g1[n] = *(const short8*)&Lg[(wn*32 + n*16 + al)*64 + ((32 + ag*8) ^ swz)];
      u1[n] = *(const short8*)&Lu[(wn*32 + n*16 + al)*64 + ((32 + ag*8) ^ swz)];
    }
    asm volatile("s_waitcnt lgkmcnt(0)" ::: "memory");
    __builtin_amdgcn_s_barrier();
    if (t + 2 < NT) STAGE(t + 2, cur);
    __builtin_amdgcn_s_setprio(1);
    #pragma unroll
    for (int i = 0; i < 4; ++i)
      #pragma unroll
      for (int n = 0; n < 2; ++n) {
        accg[i][n] = __builtin_amdgcn_mfma_f32_16x16x32_bf16(a1[i], g1[n], accg[i][n], 0, 0, 0);
        accu[i][n] = __builtin_amdgcn_mfma_f32_16x16x32_bf16(a1[i], u1[n], accu[i][n], 0, 0, 0);
      }
    __builtin_amdgcn_s_setprio(0);
    if (t + 2 < NT) { asm volatile("s_waitcnt vmcnt(6)" ::: "memory"); }
    else            { asm volatile("s_waitcnt vmcnt(0)" ::: "memory"); }
    __builtin_amdgcn_s_barrier();
  }
  #undef STAGE

  #pragma unroll
  for (int i = 0; i < 4; ++i)
    #pragma unroll
    for (int r = 0; r < 4; ++r) {
      unsigned short* Cr = Cm + (size_t)(m0 + wm*64 + i*16 + ag*4 + r) * FFD + n0 + wn*32 + al;
      #pragma unroll
      for (int n = 0; n < 2; ++n)
        Cr[n * 16] = f2b(gelu_t(accg[i][n][r]) * accu[i][n][r]);
    }
}

// ---------------- GEMM: C[M][N] = A[M][K] @ Bt[N][K]^T (128x128, reg-staged) ----
// OUT: 3 = bf16 + fused RoPE (table)
template <int OUT>
__global__ __launch_bounds__(256) void gemm_bt_kernel(
    const unsigned short* __restrict__ A, const unsigned short* __restrict__ Bt,
    void* __restrict__ Cv, int N, int K, int Kc,
    const float2* __restrict__ rope_tab) {
  __shared__ unsigned short As[128 * 40];
  __shared__ unsigned short Bs[128 * 40];
  int bid = blockIdx.x, nwg = gridDim.x;
  int wgid = (bid & 7) * (nwg >> 3) + (bid >> 3);
  int m0 = (wgid & 15) * 128;
  int n0 = (wgid >> 4) * 128;
  int tid = threadIdx.x;
  int lane = tid & 63, wave = tid >> 6;
  int wr = (wave >> 1) * 64, wc = (wave & 1) * 64;
  int l16 = lane & 15, lk8 = (lane >> 4) * 8;
  f32x4 acc[4][4];
  #pragma unroll
  for (int m = 0; m < 4; ++m)
    #pragma unroll
    for (int n = 0; n < 4; ++n) acc[m][n] = (f32x4){0.f, 0.f, 0.f, 0.f};
  size_t koff = (size_t)blockIdx.y * Kc;
  const unsigned short* Abase = A + (size_t)m0 * K + koff;
  const unsigned short* Bbase = Bt + (size_t)n0 * K + koff;
  int r0 = tid >> 2;            // 0..63
  int c0 = (tid & 3) * 8;       // 0,8,16,24
  for (int k0 = 0; k0 < Kc; k0 += 32) {
    uint4 a0 = *(const uint4*)(Abase + (size_t)r0 * K + k0 + c0);
    uint4 a1 = *(const uint4*)(Abase + (size_t)(r0 + 64) * K + k0 + c0);
    uint4 b0 = *(const uint4*)(Bbase + (size_t)r0 * K + k0 + c0);
    uint4 b1 = *(const uint4*)(Bbase + (size_t)(r0 + 64) * K + k0 + c0);
    *(uint4*)&As[r0 * 40 + c0] = a0;
    *(uint4*)&As[(r0 + 64) * 40 + c0] = a1;
    *(uint4*)&Bs[r0 * 40 + c0] = b0;
    *(uint4*)&Bs[(r0 + 64) * 40 + c0] = b1;
    __syncthreads();
    short8 af[4], bfr[4];
    #pragma unroll
    for (int m = 0; m < 4; ++m) af[m]  = *(const short8*)&As[(wr + m*16 + l16) * 40 + lk8];
    #pragma unroll
    for (int n = 0; n < 4; ++n) bfr[n] = *(const short8*)&Bs[(wc + n*16 + l16) * 40 + lk8];
    #pragma unroll
    for (int m = 0; m < 4; ++m)
      #pragma unroll
      for (int n = 0; n < 4; ++n)
        acc[m][n] = __builtin_amdgcn_mfma_f32_16x16x32_bf16(af[m], bfr[n], acc[m][n], 0, 0, 0);
    __syncthreads();
  }
  // C/D layout: col = lane&15, row = (lane>>4)*4 + reg   [learn_hip m89/m91]
  {
    unsigned short* C = (unsigned short*)Cv;
    bool qk = (n0 + wc) < 1024;   // whole 64-col group is one q/k head
    #pragma unroll
    for (int m = 0; m < 4; ++m)
      #pragma unroll
      for (int r = 0; r < 4; ++r) {
        int pos = m0 + wr + m*16 + ((lane >> 4) << 2) + r;
        unsigned short* Cr = C + (size_t)pos * N + n0 + wc + l16;
        if (qk) {
          #pragma unroll
          for (int n = 0; n < 2; ++n) {
            int d = n * 16 + l16;                 // 0..31 within head
            float2 cs = rope_tab[pos * 32 + d];
            float x1 = acc[m][n][r], x2 = acc[m][n + 2][r];
            Cr[n * 16]       = f2b(x1 * cs.x - x2 * cs.y);
            Cr[(n + 2) * 16] = f2b(x2 * cs.x + x1 * cs.y);
          }
        } else {
          #pragma unroll
          for (int n = 0; n < 4; ++n) Cr[n * 16] = f2b(acc[m][n][r]);
        }
      }
  }
}

// ---------------- MFMA flash attention, causal, GQA ----------------
__global__ __launch_bounds__(256) void attn_mfma_kernel(
    const unsigned short* __restrict__ qkv, unsigned short* __restrict__ out) {
  __shared__ unsigned short Ks[64 * 64];
  __shared__ unsigned short Vt[64 * 64];
  __shared__ unsigned short Ps[4][16 * 64];
  int h = blockIdx.y;
  int qt = gridDim.x - 1 - blockIdx.x;   // heavy (deep-causal) blocks dispatch first
  int r0 = qt * 64;
  int kvh = h / 3;           // N_REP = 3
  int t = threadIdx.x;
  int lane = t & 63, w = t >> 6;
  int l16 = lane & 15, g = lane >> 4;

  int qr = r0 + w * 16 + l16;
  const unsigned short* qrow = qkv + (size_t)qr * QKVN + h * HD;
  short8 aq0 = *(const short8*)(qrow + 8 * g);
  short8 aq1 = *(const short8*)(qrow + 32 + 8 * g);

  f32x4 o_acc[4];
  float mrun[4], lrun[4];
  #pragma unroll
  for (int i = 0; i < 4; ++i) { o_acc[i] = (f32x4){0.f,0.f,0.f,0.f}; mrun[i] = -1e30f; lrun[i] = 0.f; }

  int nt = qt + 1;
  for (int kt = 0; kt < nt; ++kt) {
    int kb = kt * 64;
    if (kt) __syncthreads();
    {
      const unsigned short* krow = qkv + (size_t)(kb + lane) * QKVN + DM + kvh * HD + 16 * w;
      uint4 k0 = ((const uint4*)krow)[0];
      uint4 k1 = ((const uint4*)krow)[1];
      uint4 v0 = ((const uint4*)(krow + NKV * HD))[0];
      uint4 v1 = ((const uint4*)(krow + NKV * HD))[1];
      int k7 = lane & 7;
      *(uint4*)&Ks[lane * 64 + (((2*w)     ^ k7) << 3)] = k0;
      *(uint4*)&Ks[lane * 64 + (((2*w + 1) ^ k7) << 3)] = k1;
      unsigned short tv[16];
      *(uint4*)&tv[0] = v0; *(uint4*)&tv[8] = v1;
      #pragma unroll
      for (int j = 0; j < 16; ++j) {
        int d = 16 * w + j;
        Vt[d * 64 + ((((lane >> 3) ^ (d & 7)) << 3) + (lane & 7))] = tv[j];
      }
    }
    __syncthreads();

    f32x4 s_acc[4];
    #pragma unroll
    for (int nb = 0; nb < 4; ++nb) s_acc[nb] = (f32x4){0.f,0.f,0.f,0.f};
    #pragma unroll
    for (int nb = 0; nb < 4; ++nb) {
      int key = nb * 16 + l16;
      short8 bk0 = *(const short8*)&Ks[key * 64 + ((g       ^ (key & 7)) << 3)];
      short8 bk1 = *(const short8*)&Ks[key * 64 + (((4 + g) ^ (key & 7)) << 3)];
      s_acc[nb] = __builtin_amdgcn_mfma_f32_16x16x32_bf16(aq0, bk0, s_acc[nb], 0, 0, 0);
      s_acc[nb] = __builtin_amdgcn_mfma_f32_16x16x32_bf16(aq1, bk1, s_acc[nb], 0, 0, 0);
    }

    bool diag = (kt == qt);
    #pragma unroll
    for (int r = 0; r < 4; ++r) {
      int qg = r0 + w * 16 + g * 4 + r;
      float sv[4];
      #pragma unroll
      for (int nb = 0; nb < 4; ++nb) {
        sv[nb] = s_acc[nb][r] * 0.125f;
        if (diag && (kb + nb * 16 + l16 > qg)) sv[nb] = -1e30f;
      }
      float mx = fmaxf(fmaxf(sv[0], sv[1]), fmaxf(sv[2], sv[3]));
      mx = fmaxf(mx, __shfl_xor(mx, 1));
      mx = fmaxf(mx, __shfl_xor(mx, 2));
      mx = fmaxf(mx, __shfl_xor(mx, 4));
      mx = fmaxf(mx, __shfl_xor(mx, 8));
      float mnew = fmaxf(mrun[r], mx);
      float es = __expf(mrun[r] - mnew);
      float rs = 0.f;
      #pragma unroll
      for (int nb = 0; nb < 4; ++nb) { sv[nb] = __expf(sv[nb] - mnew); rs += sv[nb]; }
      rs += __shfl_xor(rs, 1);
      rs += __shfl_xor(rs, 2);
      rs += __shfl_xor(rs, 4);
      rs += __shfl_xor(rs, 8);
      lrun[r] = lrun[r] * es + rs;
      mrun[r] = mnew;
      #pragma unroll
      for (int db = 0; db < 4; ++db) o_acc[db][r] *= es;
      int qloc = g * 4 + r, q7 = qloc & 7;
      #pragma unroll
      for (int nb = 0; nb < 4; ++nb) {
        int key = nb * 16 + l16;
        Ps[w][qloc * 64 + ((((key >> 3) ^ q7) << 3) + (key & 7))] = f2b(sv[nb]);
      }
    }

    #pragma unroll
    for (int kc = 0; kc < 2; ++kc) {
      short8 pa = *(const short8*)&Ps[w][l16 * 64 + (((4 * kc + g) ^ (l16 & 7)) << 3)];
      #pragma unroll
      for (int db = 0; db < 4; ++db) {
        int d = db * 16 + l16;
        short8 bv = *(const short8*)&Vt[d * 64 + (((4 * kc + g) ^ (d & 7)) << 3)];
        o_acc[db] = __builtin_amdgcn_mfma_f32_16x16x32_bf16(pa, bv, o_acc[db], 0, 0, 0);
      }
    }
  }

  #pragma unroll
  for (int r = 0; r < 4; ++r) {
    int qg = r0 + w * 16 + g * 4 + r;
    float inv = 1.0f / lrun[r];
    unsigned short* orow = out + (size_t)qg * DM + h * HD + l16;
    #pragma unroll
    for (int db = 0; db < 4; ++db) orow[db * 16] = f2b(o_acc[db][r] * inv);
  }
}

extern "C" void kernel_launch(void* const* d_in, const int* in_sizes, int n_in,
                              void* d_out, int out_size, void* d_ws, size_t ws_size,
                              hipStream_t stream) {
  const int*   idx   = (const int*)d_in[0];
  const float* embed = (const float*)d_in[1];
  const float* ln1   = (const float*)d_in[2];
  const float* Wq    = (const float*)d_in[3];
  const float* Wk    = (const float*)d_in[4];
  const float* Wv    = (const float*)d_in[5];
  const float* Wo    = (const float*)d_in[6];
  const float* ln2   = (const float*)d_in[7];
  const float* Wg    = (const float*)d_in[8];
  const float* Wu    = (const float*)d_in[9];
  const float* Wd    = (const float*)d_in[10];
  const float* normf = (const float*)d_in[11];
  float* out = (float*)d_out;
  char* ws = (char*)d_ws;
  (void)in_sizes; (void)n_in; (void)out_size; (void)ws_size;

  // ---- workspace layout ----
  unsigned short* embed_bf = (unsigned short*)ws;
  size_t off = (size_t)VOC * DM * 2;
  unsigned short* wts = (unsigned short*)(ws + off);
  const size_t LW = (size_t)QKVN * DM + (size_t)DM * DM
                  + 2ull * FFD * DM + (size_t)DM * FFD;
  off += LW * 2ull * NL;
  float* xf = (float*)(ws + off);            off += (size_t)TSEQ * DM * 4;
  unsigned short* h_bf = (unsigned short*)(ws + off);    off += (size_t)TSEQ * DM * 2;
  unsigned short* qkv_bf = (unsigned short*)(ws + off);  off += (size_t)TSEQ * QKVN * 2;
  unsigned short* attn_bf = (unsigned short*)(ws + off); off += (size_t)TSEQ * DM * 2;
  unsigned short* m_bf = (unsigned short*)(ws + off);    off += (size_t)TSEQ * FFD * 2;
  float2* rope_tab = (float2*)(ws + off);    off += (size_t)TSEQ * 32 * 8;

  // ---- prep: embed cast + rope table + batched weight transpose/cast ----
  cast_bf16_kernel<<<(VOC * DM / 4 + 255) / 256, 256, 0, stream>>>(embed, embed_bf, VOC * DM / 4);
  rope_tab_kernel<<<TSEQ * 32 / 256, 256, 0, stream>>>(rope_tab);

  {
    unsigned short* qkvT = wts;
    unsigned short* woT  = wts + (size_t)QKVN * DM;
    unsigned short* wguT = woT + (size_t)DM * DM;
    unsigned short* wdT  = wguT + 2ull * FFD * DM;
    transpose_cast_kernel<<<dim3(24, 24, NL), dim3(32, 8), 0, stream>>>(Wq, qkvT, 768, 768, 589824, LW);
    transpose_cast_kernel<<<dim3(8, 24, NL),  dim3(32, 8), 0, stream>>>(Wk, qkvT + 768ull * 768, 768, 256, 196608, LW);
    transpose_cast_kernel<<<dim3(8, 24, NL),  dim3(32, 8), 0, stream>>>(Wv, qkvT + 1024ull * 768, 768, 256, 196608, LW);
    transpose_cast_kernel<<<dim3(24, 24, NL), dim3(32, 8), 0, stream>>>(Wo, woT, 768, 768, 589824, LW);
    transpose_cast_kernel<<<dim3(64, 24, NL), dim3(32, 8), 0, stream>>>(Wg, wguT, 768, 2048, 1572864, LW);
    transpose_cast_kernel<<<dim3(64, 24, NL), dim3(32, 8), 0, stream>>>(Wu, wguT + (size_t)FFD * DM, 768, 2048, 1572864, LW);
    transpose_cast_kernel<<<dim3(24, 64, NL), dim3(32, 8), 0, stream>>>(Wd, wdT, 2048, 768, 1572864, LW);
  }

  gather_kernel<<<TSEQ, 192, 0, stream>>>(idx, embed, xf);

  for (int l = 0; l < NL; ++l) {
    unsigned short* base = wts + (size_t)l * LW;
    unsigned short* qkvT = base;
    unsigned short* woT  = base + (size_t)QKVN * DM;
    unsigned short* wguT = woT + (size_t)DM * DM;
    unsigned short* wdT  = wguT + 2ull * FFD * DM;

    rmsnorm_kernel<<<TSEQ, 256, 0, stream>>>(xf, ln1 + (size_t)l * DM, h_bf);
    gemm_bt_kernel<3><<<dim3((QKVN / 128) * 16, 1), 256, 0, stream>>>(h_bf, qkvT, qkv_bf, QKVN, DM, DM, rope_tab);
    attn_mfma_kernel<<<dim3(TSEQ / 64, NH), 256, 0, stream>>>(qkv_bf, attn_bf);
    gemm_p8_kernel<<<dim3((DM / 128) * 16, 3), 512, 0, stream>>>(attn_bf, woT, xf, DM, DM, 256);
    rmsnorm_kernel<<<TSEQ, 256, 0, stream>>>(xf, ln2 + (size_t)l * DM, h_bf);
    gemm_gu8_kernel<<<(FFD / 128) * 16, 512, 0, stream>>>(h_bf, wguT, wguT + (size_t)FFD * DM, m_bf);
    gemm_p8_kernel<<<dim3((DM / 128) * 16, 4), 512, 0, stream>>>(m_bf, wdT, xf, DM, FFD, 512);
  }

  rmsnorm_kernel<<<TSEQ, 256, 0, stream>>>(xf, normf, h_bf);
  // 256x256 deep-pipelined logits GEMM: 8 m-tiles x 125 n-tiles = 1000 blocks
  gemm_l8_kernel<<<(VOC / 256) * (TSEQ / 256), 512, 0, stream>>>(h_bf, embed_bf, out, VOC, DM);
}

// Round 8
// 882.472 us; speedup vs baseline: 1.4121x; 1.0558x over previous
//
#include <hip/hip_runtime.h>

#define TSEQ 2048
#define DM   768
#define NH   12
#define NKV  4
#define HD   64
#define FFD  2048
#define NL   4
#define VOC  32000
#define QKVN 1280   // 768 q + 256 k + 256 v

typedef __attribute__((ext_vector_type(8))) short short8;
typedef __attribute__((ext_vector_type(4))) float f32x4;

__device__ __forceinline__ unsigned short f2b(float f) {
  unsigned int u = __float_as_uint(f);
  u += 0x7fffu + ((u >> 16) & 1u);
  return (unsigned short)(u >> 16);
}
__device__ __forceinline__ float b2f(unsigned short u) {
  return __uint_as_float(((unsigned int)u) << 16);
}
__device__ __forceinline__ unsigned int packbf(float a, float b) {
  return (unsigned int)f2b(a) | ((unsigned int)f2b(b) << 16);
}

// direct global->LDS async copy, 16B/lane; LDS dest wave-uniform (HW adds lane*16)
__device__ __forceinline__ void gl16(const unsigned short* g, unsigned short* l) {
  __builtin_amdgcn_global_load_lds(
      (const __attribute__((address_space(1))) void*)g,
      (__attribute__((address_space(3))) void*)l, 16, 0, 0);
}

// ---------------- cast f32 -> bf16 (vectorized x4) ----------------
__global__ void cast_bf16_kernel(const float* __restrict__ src,
                                 unsigned short* __restrict__ dst, int n4) {
  int i = blockIdx.x * blockDim.x + threadIdx.x;
  if (i >= n4) return;
  float4 v = ((const float4*)src)[i];
  uint2 o; o.x = packbf(v.x, v.y); o.y = packbf(v.z, v.w);
  ((uint2*)dst)[i] = o;
}

// ---------------- RoPE cos/sin table: [pos][d] for d in 0..31 ----------------
__global__ void rope_tab_kernel(float2* __restrict__ tab) {
  int i = blockIdx.x * blockDim.x + threadIdx.x;   // over TSEQ*32
  int pos = i >> 5, d = i & 31;
  float inv = exp2f(-(float)d * (13.287712379549449f / 32.0f));
  float sv, cv; sincosf((float)pos * inv, &sv, &cv);
  tab[i] = make_float2(cv, sv);
}

// ---------------- transpose + cast (batched over layers via blockIdx.z) ----------------
__global__ void transpose_cast_kernel(const float* __restrict__ src,
                                      unsigned short* __restrict__ dst,
                                      int K, int N, size_t sstride, size_t dstride) {
  __shared__ float tile[32][33];
  src += (size_t)blockIdx.z * sstride;
  dst += (size_t)blockIdx.z * dstride;
  int n0 = blockIdx.x * 32, k0 = blockIdx.y * 32;
  int tx = threadIdx.x, ty = threadIdx.y;  // 32 x 8
  #pragma unroll
  for (int i = 0; i < 4; ++i) {
    int r = ty + i * 8;
    tile[r][tx] = src[(size_t)(k0 + r) * N + n0 + tx];
  }
  __syncthreads();
  #pragma unroll
  for (int i = 0; i < 4; ++i) {
    int r = ty + i * 8;
    dst[(size_t)(n0 + r) * K + k0 + tx] = f2b(tile[tx][r]);
  }
}

// ---------------- embedding gather ----------------
__global__ void gather_kernel(const int* __restrict__ idx,
                              const float* __restrict__ embed,
                              float* __restrict__ x) {
  int row = blockIdx.x; int t = threadIdx.x;  // 192 threads, float4 each
  int id = idx[row];
  ((float4*)(x + (size_t)row * DM))[t] = ((const float4*)(embed + (size_t)id * DM))[t];
}

// ---------------- RMSNorm: f32 in -> bf16 out ----------------
__global__ void rmsnorm_kernel(const float* __restrict__ x,
                               const float* __restrict__ w,
                               unsigned short* __restrict__ out) {
  int row = blockIdx.x; int t = threadIdx.x;  // 256 threads, D=768
  const float* xr = x + (size_t)row * DM;
  float v0 = xr[t], v1 = xr[t + 256], v2 = xr[t + 512];
  float s = v0*v0 + v1*v1 + v2*v2;
  #pragma unroll
  for (int off = 1; off < 64; off <<= 1) s += __shfl_xor(s, off);
  __shared__ float red[4];
  if ((t & 63) == 0) red[t >> 6] = s;
  __syncthreads();
  float tot = red[0] + red[1] + red[2] + red[3];
  float rs = rsqrtf(tot * (1.0f / DM) + 1e-6f);
  unsigned short* orow = out + (size_t)row * DM;
  orow[t]       = f2b(w[t]       * v0 * rs);
  orow[t + 256] = f2b(w[t + 256] * v1 * rs);
  orow[t + 512] = f2b(w[t + 512] * v2 * rs);
}

// ---------------- 256x256 deep-pipelined GEMM (logits): C = A @ Bt^T, f32 out ----
__global__ __launch_bounds__(512, 1) void gemm_l8_kernel(
    const unsigned short* __restrict__ A, const unsigned short* __restrict__ Bt,
    float* __restrict__ C, int N, int K) {
  __shared__ unsigned short lds[2][2][256 * 64];   // [dbuf][A,B][row*64+col]
  const int NT = K >> 6;
  int bid = blockIdx.x, nwg = gridDim.x;
  int wgid = (bid & 7) * (nwg >> 3) + (bid >> 3);
  int m0 = (wgid & 7) * 256;        // 8 m-tiles (TSEQ/256)
  int n0 = (wgid >> 3) * 256;
  int tid = threadIdx.x;
  int lane = tid & 63, w = tid >> 6;
  int wm = w >> 2, wn = w & 3;
  int al = lane & 15, ag = lane >> 4;
  int swz = (al & 7) << 3;          // frag-read swizzle (shorts)

  int rA = tid >> 3;                                  // 0..63
  int cK = ((tid & 7) * 8) ^ ((rA & 7) << 3);         // bf16 col within 64
  const unsigned short* Ag = A + (size_t)(m0 + rA) * K + cK;
  const unsigned short* Bg = Bt + (size_t)(n0 + rA) * K + cK;

  f32x4 acc[8][4];
  #pragma unroll
  for (int i = 0; i < 8; ++i)
    #pragma unroll
    for (int n = 0; n < 4; ++n) acc[i][n] = (f32x4){0.f, 0.f, 0.f, 0.f};

  #define STAGE(kt, c) { \
    size_t ko = (size_t)(kt) * 64; \
    unsigned short* dA = &lds[(c)][0][0] + w * 512; \
    unsigned short* dB = &lds[(c)][1][0] + w * 512; \
    gl16(Ag + (size_t)0   * K + ko, dA);            \
    gl16(Ag + (size_t)64  * K + ko, dA + 4096);     \
    gl16(Ag + (size_t)128 * K + ko, dA + 8192);     \
    gl16(Ag + (size_t)192 * K + ko, dA + 12288);    \
    gl16(Bg + (size_t)0   * K + ko, dB);            \
    gl16(Bg + (size_t)64  * K + ko, dB + 4096);     \
    gl16(Bg + (size_t)128 * K + ko, dB + 8192);     \
    gl16(Bg + (size_t)192 * K + ko, dB + 12288);    \
  }

  STAGE(0, 0);
  STAGE(1, 1);
  asm volatile("s_waitcnt vmcnt(8)" ::: "memory");
  __builtin_amdgcn_s_barrier();

  for (int t = 0; t < NT; ++t) {
    int cur = t & 1;
    const unsigned short* La = &lds[cur][0][0];
    const unsigned short* Lb = &lds[cur][1][0];
    short8 a0[8], b0[4], a1[8], b1[4];
    #pragma unroll
    for (int i = 0; i < 8; ++i)
      a0[i] = *(const short8*)&La[(wm*128 + i*16 + al)*64 + ((ag*8) ^ swz)];
    #pragma unroll
    for (int n = 0; n < 4; ++n)
      b0[n] = *(const short8*)&Lb[(wn*64 + n*16 + al)*64 + ((ag*8) ^ swz)];
    #pragma unroll
    for (int i = 0; i < 8; ++i)
      #pragma unroll
      for (int n = 0; n < 4; ++n)
        acc[i][n] = __builtin_amdgcn_mfma_f32_16x16x32_bf16(a0[i], b0[n], acc[i][n], 0, 0, 0);
    #pragma unroll
    for (int i = 0; i < 8; ++i)
      a1[i] = *(const short8*)&La[(wm*128 + i*16 + al)*64 + ((32 + ag*8) ^ swz)];
    #pragma unroll
    for (int n = 0; n < 4; ++n)
      b1[n] = *(const short8*)&Lb[(wn*64 + n*16 + al)*64 + ((32 + ag*8) ^ swz)];
    asm volatile("s_waitcnt lgkmcnt(0)" ::: "memory");
    __builtin_amdgcn_s_barrier();
    if (t + 2 < NT) STAGE(t + 2, cur);
    __builtin_amdgcn_s_setprio(1);
    #pragma unroll
    for (int i = 0; i < 8; ++i)
      #pragma unroll
      for (int n = 0; n < 4; ++n)
        acc[i][n] = __builtin_amdgcn_mfma_f32_16x16x32_bf16(a1[i], b1[n], acc[i][n], 0, 0, 0);
    __builtin_amdgcn_s_setprio(0);
    if (t + 2 < NT) { asm volatile("s_waitcnt vmcnt(8)" ::: "memory"); }
    else            { asm volatile("s_waitcnt vmcnt(0)" ::: "memory"); }
    __builtin_amdgcn_s_barrier();
  }
  #undef STAGE

  #pragma unroll
  for (int i = 0; i < 8; ++i)
    #pragma unroll
    for (int r = 0; r < 4; ++r) {
      float* Cr = C + (size_t)(m0 + wm*128 + i*16 + ag*4 + r) * N + n0 + wn*64 + al;
      #pragma unroll
      for (int n = 0; n < 4; ++n) Cr[n * 16] = acc[i][n][r];
    }
}

// ---------------- 128x128 pipelined 8-wave GEMM, split-K, f32 atomicAdd ----------
__global__ __launch_bounds__(512) void gemm_p8_kernel(
    const unsigned short* __restrict__ A, const unsigned short* __restrict__ Bt,
    float* __restrict__ C, int N, int K, int Kc) {
  __shared__ unsigned short lds[2][2][128 * 64];
  const int NT = Kc >> 6;
  int bid = blockIdx.x, nwg = gridDim.x;
  int wgid = (bid & 7) * (nwg >> 3) + (bid >> 3);
  int m0 = (wgid & 15) * 128;
  int n0 = (wgid >> 4) * 128;
  int tid = threadIdx.x;
  int lane = tid & 63, w = tid >> 6;
  int wm = w >> 2, wn = w & 3;
  int al = lane & 15, ag = lane >> 4;
  int swz = (al & 7) << 3;

  size_t koff = (size_t)blockIdx.y * Kc;
  int rp = 8 * w + (lane >> 3);
  int cK = ((lane & 7) * 8) ^ ((lane >> 3) << 3);
  const unsigned short* Ag = A + (size_t)(m0 + rp) * K + koff + cK;
  const unsigned short* Bg = Bt + (size_t)(n0 + rp) * K + koff + cK;

  f32x4 acc[4][2];
  #pragma unroll
  for (int i = 0; i < 4; ++i)
    #pragma unroll
    for (int n = 0; n < 2; ++n) acc[i][n] = (f32x4){0.f, 0.f, 0.f, 0.f};

  #define STAGE(kt, c) { \
    size_t ko = (size_t)(kt) * 64; \
    unsigned short* dA = &lds[(c)][0][0] + w * 512; \
    unsigned short* dB = &lds[(c)][1][0] + w * 512; \
    gl16(Ag + ko,                 dA);        \
    gl16(Ag + (size_t)64*K + ko,  dA + 4096); \
    gl16(Bg + ko,                 dB);        \
    gl16(Bg + (size_t)64*K + ko,  dB + 4096); \
  }

  STAGE(0, 0);
  STAGE(1, 1);
  asm volatile("s_waitcnt vmcnt(4)" ::: "memory");
  __builtin_amdgcn_s_barrier();

  for (int t = 0; t < NT; ++t) {
    int cur = t & 1;
    const unsigned short* La = &lds[cur][0][0];
    const unsigned short* Lb = &lds[cur][1][0];
    short8 a0[4], b0[2], a1[4], b1[2];
    #pragma unroll
    for (int i = 0; i < 4; ++i)
      a0[i] = *(const short8*)&La[(wm*64 + i*16 + al)*64 + ((ag*8) ^ swz)];
    #pragma unroll
    for (int n = 0; n < 2; ++n)
      b0[n] = *(const short8*)&Lb[(wn*32 + n*16 + al)*64 + ((ag*8) ^ swz)];
    #pragma unroll
    for (int i = 0; i < 4; ++i)
      #pragma unroll
      for (int n = 0; n < 2; ++n)
        acc[i][n] = __builtin_amdgcn_mfma_f32_16x16x32_bf16(a0[i], b0[n], acc[i][n], 0, 0, 0);
    #pragma unroll
    for (int i = 0; i < 4; ++i)
      a1[i] = *(const short8*)&La[(wm*64 + i*16 + al)*64 + ((32 + ag*8) ^ swz)];
    #pragma unroll
    for (int n = 0; n < 2; ++n)
      b1[n] = *(const short8*)&Lb[(wn*32 + n*16 + al)*64 + ((32 + ag*8) ^ swz)];
    asm volatile("s_waitcnt lgkmcnt(0)" ::: "memory");
    __builtin_amdgcn_s_barrier();
    if (t + 2 < NT) STAGE(t + 2, cur);
    __builtin_amdgcn_s_setprio(1);
    #pragma unroll
    for (int i = 0; i < 4; ++i)
      #pragma unroll
      for (int n = 0; n < 2; ++n)
        acc[i][n] = __builtin_amdgcn_mfma_f32_16x16x32_bf16(a1[i], b1[n], acc[i][n], 0, 0, 0);
    __builtin_amdgcn_s_setprio(0);
    if (t + 2 < NT) { asm volatile("s_waitcnt vmcnt(4)" ::: "memory"); }
    else            { asm volatile("s_waitcnt vmcnt(0)" ::: "memory"); }
    __builtin_amdgcn_s_barrier();
  }
  #undef STAGE

  #pragma unroll
  for (int i = 0; i < 4; ++i)
    #pragma unroll
    for (int r = 0; r < 4; ++r) {
      float* Cr = C + (size_t)(m0 + wm*64 + i*16 + ag*4 + r) * N + n0 + wn*32 + al;
      #pragma unroll
      for (int n = 0; n < 2; ++n) atomicAdd(&Cr[n * 16], acc[i][n][r]);
    }
}

// ---------------- gelu ----------------
__device__ __forceinline__ float gelu_t(float x) {
  float x3 = x * x * x;
  return 0.5f * x * (1.0f + tanhf(0.7978845608028654f * (x + 0.044715f * x3)));
}

// ---- pipelined gate/up GEMM: tile 128 rows x [G128|U128], 8 waves, BK=64 ----
__global__ __launch_bounds__(512) void gemm_gu8_kernel(
    const unsigned short* __restrict__ A, const unsigned short* __restrict__ BtG,
    const unsigned short* __restrict__ BtU, unsigned short* __restrict__ Cm) {
  __shared__ unsigned short lds[2][3][128 * 64];   // [dbuf][A,G,U]
  const int K = DM;
  const int NT = K >> 6;                           // 12
  int bid = blockIdx.x, nwg = gridDim.x;           // 256
  int wgid = (bid & 7) * (nwg >> 3) + (bid >> 3);
  int m0 = (wgid & 15) * 128;
  int n0 = (wgid >> 4) * 128;                      // over FF
  int tid = threadIdx.x;
  int lane = tid & 63, w = tid >> 6;
  int wm = w >> 2, wn = w & 3;
  int al = lane & 15, ag = lane >> 4;
  int swz = (al & 7) << 3;

  int rp = 8 * w + (lane >> 3);
  int cK = ((lane & 7) * 8) ^ ((lane >> 3) << 3);
  const unsigned short* Ag = A + (size_t)(m0 + rp) * K + cK;
  const unsigned short* Gg = BtG + (size_t)(n0 + rp) * K + cK;
  const unsigned short* Ug = BtU + (size_t)(n0 + rp) * K + cK;

  f32x4 accg[4][2], accu[4][2];
  #pragma unroll
  for (int i = 0; i < 4; ++i)
    #pragma unroll
    for (int n = 0; n < 2; ++n) {
      accg[i][n] = (f32x4){0.f, 0.f, 0.f, 0.f};
      accu[i][n] = (f32x4){0.f, 0.f, 0.f, 0.f};
    }

  #define STAGE(kt, c) { \
    size_t ko = (size_t)(kt) * 64; \
    unsigned short* dA = &lds[(c)][0][0] + w * 512; \
    unsigned short* dG = &lds[(c)][1][0] + w * 512; \
    unsigned short* dU = &lds[(c)][2][0] + w * 512; \
    gl16(Ag + ko,                 dA);        \
    gl16(Ag + (size_t)64*K + ko,  dA + 4096); \
    gl16(Gg + ko,                 dG);        \
    gl16(Gg + (size_t)64*K + ko,  dG + 4096); \
    gl16(Ug + ko,                 dU);        \
    gl16(Ug + (size_t)64*K + ko,  dU + 4096); \
  }

  STAGE(0, 0);
  STAGE(1, 1);
  asm volatile("s_waitcnt vmcnt(6)" ::: "memory");
  __builtin_amdgcn_s_barrier();

  for (int t = 0; t < NT; ++t) {
    int cur = t & 1;
    const unsigned short* La = &lds[cur][0][0];
    const unsigned short* Lg = &lds[cur][1][0];
    const unsigned short* Lu = &lds[cur][2][0];
    short8 a0[4], g0[2], u0[2], a1[4], g1[2], u1[2];
    #pragma unroll
    for (int i = 0; i < 4; ++i)
      a0[i] = *(const short8*)&La[(wm*64 + i*16 + al)*64 + ((ag*8) ^ swz)];
    #pragma unroll
    for (int n = 0; n < 2; ++n) {
      g0[n] = *(const short8*)&Lg[(wn*32 + n*16 + al)*64 + ((ag*8) ^ swz)];
      u0[n] = *(const short8*)&Lu[(wn*32 + n*16 + al)*64 + ((ag*8) ^ swz)];
    }
    #pragma unroll
    for (int i = 0; i < 4; ++i)
      #pragma unroll
      for (int n = 0; n < 2; ++n) {
        accg[i][n] = __builtin_amdgcn_mfma_f32_16x16x32_bf16(a0[i], g0[n], accg[i][n], 0, 0, 0);
        accu[i][n] = __builtin_amdgcn_mfma_f32_16x16x32_bf16(a0[i], u0[n], accu[i][n], 0, 0, 0);
      }
    #pragma unroll
    for (int i = 0; i < 4; ++i)
      a1[i] = *(const short8*)&La[(wm*64 + i*16 + al)*64 + ((32 + ag*8) ^ swz)];
    #pragma unroll
    for (int n = 0; n < 2; ++n) {
      g1[n] = *(const short8*)&Lg[(wn*32 + n*16 + al)*64 + ((32 + ag*8) ^ swz)];
      u1[n] = *(const short8*)&Lu[(wn*32 + n*16 + al)*64 + ((32 + ag*8) ^ swz)];
    }
    asm volatile("s_waitcnt lgkmcnt(0)" ::: "memory");
    __builtin_amdgcn_s_barrier();
    if (t + 2 < NT) STAGE(t + 2, cur);
    __builtin_amdgcn_s_setprio(1);
    #pragma unroll
    for (int i = 0; i < 4; ++i)
      #pragma unroll
      for (int n = 0; n < 2; ++n) {
        accg[i][n] = __builtin_amdgcn_mfma_f32_16x16x32_bf16(a1[i], g1[n], accg[i][n], 0, 0, 0);
        accu[i][n] = __builtin_amdgcn_mfma_f32_16x16x32_bf16(a1[i], u1[n], accu[i][n], 0, 0, 0);
      }
    __builtin_amdgcn_s_setprio(0);
    if (t + 2 < NT) { asm volatile("s_waitcnt vmcnt(6)" ::: "memory"); }
    else            { asm volatile("s_waitcnt vmcnt(0)" ::: "memory"); }
    __builtin_amdgcn_s_barrier();
  }
  #undef STAGE

  #pragma unroll
  for (int i = 0; i < 4; ++i)
    #pragma unroll
    for (int r = 0; r < 4; ++r) {
      unsigned short* Cr = Cm + (size_t)(m0 + wm*64 + i*16 + ag*4 + r) * FFD + n0 + wn*32 + al;
      #pragma unroll
      for (int n = 0; n < 2; ++n)
        Cr[n * 16] = f2b(gelu_t(accg[i][n][r]) * accu[i][n][r]);
    }
}

// ------- QKV GEMM (128x128, reg-staged): q/k -> RoPE'd bf16; V -> vT transposed ----
__global__ __launch_bounds__(256) void gemm_qkv_kernel(
    const unsigned short* __restrict__ A, const unsigned short* __restrict__ Bt,
    unsigned short* __restrict__ C, unsigned short* __restrict__ vT,
    const float2* __restrict__ rope_tab) {
  const int N = QKVN, K = DM;
  __shared__ unsigned short As[128 * 40];
  __shared__ unsigned short Bs[128 * 40];
  int bid = blockIdx.x, nwg = gridDim.x;
  int wgid = (bid & 7) * (nwg >> 3) + (bid >> 3);
  int m0 = (wgid & 15) * 128;
  int n0 = (wgid >> 4) * 128;
  int tid = threadIdx.x;
  int lane = tid & 63, wave = tid >> 6;
  int wr = (wave >> 1) * 64, wc = (wave & 1) * 64;
  int l16 = lane & 15, lk8 = (lane >> 4) * 8;
  f32x4 acc[4][4];
  #pragma unroll
  for (int m = 0; m < 4; ++m)
    #pragma unroll
    for (int n = 0; n < 4; ++n) acc[m][n] = (f32x4){0.f, 0.f, 0.f, 0.f};
  const unsigned short* Abase = A + (size_t)m0 * K;
  const unsigned short* Bbase = Bt + (size_t)n0 * K;
  int r0 = tid >> 2;            // 0..63
  int c0 = (tid & 3) * 8;       // 0,8,16,24
  for (int k0 = 0; k0 < K; k0 += 32) {
    uint4 a0 = *(const uint4*)(Abase + (size_t)r0 * K + k0 + c0);
    uint4 a1 = *(const uint4*)(Abase + (size_t)(r0 + 64) * K + k0 + c0);
    uint4 b0 = *(const uint4*)(Bbase + (size_t)r0 * K + k0 + c0);
    uint4 b1 = *(const uint4*)(Bbase + (size_t)(r0 + 64) * K + k0 + c0);
    *(uint4*)&As[r0 * 40 + c0] = a0;
    *(uint4*)&As[(r0 + 64) * 40 + c0] = a1;
    *(uint4*)&Bs[r0 * 40 + c0] = b0;
    *(uint4*)&Bs[(r0 + 64) * 40 + c0] = b1;
    __syncthreads();
    short8 af[4], bfr[4];
    #pragma unroll
    for (int m = 0; m < 4; ++m) af[m]  = *(const short8*)&As[(wr + m*16 + l16) * 40 + lk8];
    #pragma unroll
    for (int n = 0; n < 4; ++n) bfr[n] = *(const short8*)&Bs[(wc + n*16 + l16) * 40 + lk8];
    #pragma unroll
    for (int m = 0; m < 4; ++m)
      #pragma unroll
      for (int n = 0; n < 4; ++n)
        acc[m][n] = __builtin_amdgcn_mfma_f32_16x16x32_bf16(af[m], bfr[n], acc[m][n], 0, 0, 0);
    __syncthreads();
  }
  bool qk = (n0 + wc) < 1024;   // whole 64-col group = one q/k head (RoPE) else V head
  #pragma unroll
  for (int m = 0; m < 4; ++m)
    #pragma unroll
    for (int r = 0; r < 4; ++r) {
      int pos = m0 + wr + m*16 + ((lane >> 4) << 2) + r;
      if (qk) {
        unsigned short* Cr = C + (size_t)pos * N + n0 + wc + l16;
        #pragma unroll
        for (int n = 0; n < 2; ++n) {
          int d = n * 16 + l16;                 // 0..31 within head
          float2 cs = rope_tab[pos * 32 + d];
          float x1 = acc[m][n][r], x2 = acc[m][n + 2][r];
          Cr[n * 16]       = f2b(x1 * cs.x - x2 * cs.y);
          Cr[(n + 2) * 16] = f2b(x2 * cs.x + x1 * cs.y);
        }
      } else {
        // V columns: write transposed vT[(kvh*64+d)][pos]
        #pragma unroll
        for (int n = 0; n < 4; ++n) {
          int hb = n0 + wc + n*16 + l16 - 1024;   // 0..255
          vT[(size_t)hb * TSEQ + pos] = f2b(acc[m][n][r]);
        }
      }
    }
}

// ---------------- MFMA flash attention, causal, GQA ----------------
// K from qkv (row-major), V from vT (pre-transposed [256][TSEQ]).
__global__ __launch_bounds__(256) void attn_mfma_kernel(
    const unsigned short* __restrict__ qkv, const unsigned short* __restrict__ vT,
    unsigned short* __restrict__ out) {
  __shared__ unsigned short Ks[64 * 64];
  __shared__ unsigned short Vt[64 * 64];
  __shared__ unsigned short Ps[4][16 * 64];
  int h = blockIdx.y;
  int qt = gridDim.x - 1 - blockIdx.x;   // heavy (deep-causal) blocks dispatch first
  int r0 = qt * 64;
  int kvh = h / 3;           // N_REP = 3
  int t = threadIdx.x;
  int lane = t & 63, w = t >> 6;
  int l16 = lane & 15, g = lane >> 4;

  int qr = r0 + w * 16 + l16;
  const unsigned short* qrow = qkv + (size_t)qr * QKVN + h * HD;
  short8 aq0 = *(const short8*)(qrow + 8 * g);
  short8 aq1 = *(const short8*)(qrow + 32 + 8 * g);

  // V staging source: thread t covers Vt row d = t>>2, key chunk pair (t&3)*2
  int vd = t >> 2;
  const unsigned short* vbase = vT + (size_t)(kvh * 64 + vd) * TSEQ + (t & 3) * 16;
  int vc0 = (t & 3) * 2;
  unsigned short* vdst0 = &Vt[vd * 64 + (((vc0)     ^ (vd & 7)) << 3)];
  unsigned short* vdst1 = &Vt[vd * 64 + (((vc0 + 1) ^ (vd & 7)) << 3)];

  f32x4 o_acc[4];
  float mrun[4], lsum[4];
  #pragma unroll
  for (int i = 0; i < 4; ++i) { o_acc[i] = (f32x4){0.f,0.f,0.f,0.f}; mrun[i] = -1e30f; lsum[i] = 0.f; }

  int nt = qt + 1;
  for (int kt = 0; kt < nt; ++kt) {
    int kb = kt * 64;
    if (kt) __syncthreads();
    {
      // K: wave w stages dim chunk [16w,16w+16) for all 64 keys (key = lane)
      const unsigned short* krow = qkv + (size_t)(kb + lane) * QKVN + DM + kvh * HD + 16 * w;
      uint4 k0 = ((const uint4*)krow)[0];
      uint4 k1 = ((const uint4*)krow)[1];
      int k7 = lane & 7;
      *(uint4*)&Ks[lane * 64 + (((2*w)     ^ k7) << 3)] = k0;
      *(uint4*)&Ks[lane * 64 + (((2*w + 1) ^ k7) << 3)] = k1;
      // V: vectorized from vT (row-major in d, contiguous keys)
      uint4 v0 = ((const uint4*)(vbase + kb))[0];
      uint4 v1 = ((const uint4*)(vbase + kb))[1];
      *(uint4*)vdst0 = v0;
      *(uint4*)vdst1 = v1;
    }
    __syncthreads();

    f32x4 s_acc[4];
    #pragma unroll
    for (int nb = 0; nb < 4; ++nb) s_acc[nb] = (f32x4){0.f,0.f,0.f,0.f};
    #pragma unroll
    for (int nb = 0; nb < 4; ++nb) {
      int key = nb * 16 + l16;
      short8 bk0 = *(const short8*)&Ks[key * 64 + ((g       ^ (key & 7)) << 3)];
      short8 bk1 = *(const short8*)&Ks[key * 64 + (((4 + g) ^ (key & 7)) << 3)];
      s_acc[nb] = __builtin_amdgcn_mfma_f32_16x16x32_bf16(aq0, bk0, s_acc[nb], 0, 0, 0);
      s_acc[nb] = __builtin_amdgcn_mfma_f32_16x16x32_bf16(aq1, bk1, s_acc[nb], 0, 0, 0);
    }

    bool diag = (kt == qt);
    #pragma unroll
    for (int r = 0; r < 4; ++r) {
      int qg = r0 + w * 16 + g * 4 + r;
      float sv[4];
      #pragma unroll
      for (int nb = 0; nb < 4; ++nb) {
        sv[nb] = s_acc[nb][r] * 0.125f;
        if (diag && (kb + nb * 16 + l16 > qg)) sv[nb] = -1e30f;
      }
      float mx = fmaxf(fmaxf(sv[0], sv[1]), fmaxf(sv[2], sv[3]));
      mx = fmaxf(mx, __shfl_xor(mx, 1));
      mx = fmaxf(mx, __shfl_xor(mx, 2));
      mx = fmaxf(mx, __shfl_xor(mx, 4));
      mx = fmaxf(mx, __shfl_xor(mx, 8));
      // defer-max (T13, THR=8): only rescale when the max moved materially
      if (mx > mrun[r] + 8.0f) {
        float es = __expf(mrun[r] - mx);
        lsum[r] *= es;
        #pragma unroll
        for (int db = 0; db < 4; ++db) o_acc[db][r] *= es;
        mrun[r] = mx;
      }
      float rsum = 0.f;
      #pragma unroll
      for (int nb = 0; nb < 4; ++nb) { sv[nb] = __expf(sv[nb] - mrun[r]); rsum += sv[nb]; }
      lsum[r] += rsum;   // per-lane partial; reduced once at the end
      int qloc = g * 4 + r, q7 = qloc & 7;
      #pragma unroll
      for (int nb = 0; nb < 4; ++nb) {
        int key = nb * 16 + l16;
        Ps[w][qloc * 64 + ((((key >> 3) ^ q7) << 3) + (key & 7))] = f2b(sv[nb]);
      }
    }

    #pragma unroll
    for (int kc = 0; kc < 2; ++kc) {
      short8 pa = *(const short8*)&Ps[w][l16 * 64 + (((4 * kc + g) ^ (l16 & 7)) << 3)];
      #pragma unroll
      for (int db = 0; db < 4; ++db) {
        int d = db * 16 + l16;
        short8 bv = *(const short8*)&Vt[d * 64 + (((4 * kc + g) ^ (d & 7)) << 3)];
        o_acc[db] = __builtin_amdgcn_mfma_f32_16x16x32_bf16(pa, bv, o_acc[db], 0, 0, 0);
      }
    }
  }

  #pragma unroll
  for (int r = 0; r < 4; ++r) {
    int qg = r0 + w * 16 + g * 4 + r;
    float s = lsum[r];
    s += __shfl_xor(s, 1);
    s += __shfl_xor(s, 2);
    s += __shfl_xor(s, 4);
    s += __shfl_xor(s, 8);
    float inv = 1.0f / s;
    unsigned short* orow = out + (size_t)qg * DM + h * HD + l16;
    #pragma unroll
    for (int db = 0; db < 4; ++db) orow[db * 16] = f2b(o_acc[db][r] * inv);
  }
}

extern "C" void kernel_launch(void* const* d_in, const int* in_sizes, int n_in,
                              void* d_out, int out_size, void* d_ws, size_t ws_size,
                              hipStream_t stream) {
  const int*   idx   = (const int*)d_in[0];
  const float* embed = (const float*)d_in[1];
  const float* ln1   = (const float*)d_in[2];
  const float* Wq    = (const float*)d_in[3];
  const float* Wk    = (const float*)d_in[4];
  const float* Wv    = (const float*)d_in[5];
  const float* Wo    = (const float*)d_in[6];
  const float* ln2   = (const float*)d_in[7];
  const float* Wg    = (const float*)d_in[8];
  const float* Wu    = (const float*)d_in[9];
  const float* Wd    = (const float*)d_in[10];
  const float* normf = (const float*)d_in[11];
  float* out = (float*)d_out;
  char* ws = (char*)d_ws;
  (void)in_sizes; (void)n_in; (void)out_size; (void)ws_size;

  // ---- workspace layout ----
  unsigned short* embed_bf = (unsigned short*)ws;
  size_t off = (size_t)VOC * DM * 2;
  unsigned short* wts = (unsigned short*)(ws + off);
  const size_t LW = (size_t)QKVN * DM + (size_t)DM * DM
                  + 2ull * FFD * DM + (size_t)DM * FFD;
  off += LW * 2ull * NL;
  float* xf = (float*)(ws + off);            off += (size_t)TSEQ * DM * 4;
  unsigned short* h_bf = (unsigned short*)(ws + off);    off += (size_t)TSEQ * DM * 2;
  unsigned short* qkv_bf = (unsigned short*)(ws + off);  off += (size_t)TSEQ * QKVN * 2;
  unsigned short* attn_bf = (unsigned short*)(ws + off); off += (size_t)TSEQ * DM * 2;
  unsigned short* m_bf = (unsigned short*)(ws + off);    off += (size_t)TSEQ * FFD * 2;
  float2* rope_tab = (float2*)(ws + off);    off += (size_t)TSEQ * 32 * 8;
  unsigned short* vT = (unsigned short*)(ws + off);      off += (size_t)NKV * HD * TSEQ * 2;

  // ---- prep: embed cast + rope table + batched weight transpose/cast ----
  cast_bf16_kernel<<<(VOC * DM / 4 + 255) / 256, 256, 0, stream>>>(embed, embed_bf, VOC * DM / 4);
  rope_tab_kernel<<<TSEQ * 32 / 256, 256, 0, stream>>>(rope_tab);

  {
    unsigned short* qkvT = wts;
    unsigned short* woT  = wts + (size_t)QKVN * DM;
    unsigned short* wguT = woT + (size_t)DM * DM;
    unsigned short* wdT  = wguT + 2ull * FFD * DM;
    transpose_cast_kernel<<<dim3(24, 24, NL), dim3(32, 8), 0, stream>>>(Wq, qkvT, 768, 768, 589824, LW);
    transpose_cast_kernel<<<dim3(8, 24, NL),  dim3(32, 8), 0, stream>>>(Wk, qkvT + 768ull * 768, 768, 256, 196608, LW);
    transpose_cast_kernel<<<dim3(8, 24, NL),  dim3(32, 8), 0, stream>>>(Wv, qkvT + 1024ull * 768, 768, 256, 196608, LW);
    transpose_cast_kernel<<<dim3(24, 24, NL), dim3(32, 8), 0, stream>>>(Wo, woT, 768, 768, 589824, LW);
    transpose_cast_kernel<<<dim3(64, 24, NL), dim3(32, 8), 0, stream>>>(Wg, wguT, 768, 2048, 1572864, LW);
    transpose_cast_kernel<<<dim3(64, 24, NL), dim3(32, 8), 0, stream>>>(Wu, wguT + (size_t)FFD * DM, 768, 2048, 1572864, LW);
    transpose_cast_kernel<<<dim3(24, 64, NL), dim3(32, 8), 0, stream>>>(Wd, wdT, 2048, 768, 1572864, LW);
  }

  gather_kernel<<<TSEQ, 192, 0, stream>>>(idx, embed, xf);

  for (int l = 0; l < NL; ++l) {
    unsigned short* base = wts + (size_t)l * LW;
    unsigned short* qkvT = base;
    unsigned short* woT  = base + (size_t)QKVN * DM;
    unsigned short* wguT = woT + (size_t)DM * DM;
    unsigned short* wdT  = wguT + 2ull * FFD * DM;

    rmsnorm_kernel<<<TSEQ, 256, 0, stream>>>(xf, ln1 + (size_t)l * DM, h_bf);
    gemm_qkv_kernel<<<(QKVN / 128) * 16, 256, 0, stream>>>(h_bf, qkvT, qkv_bf, vT, rope_tab);
    attn_mfma_kernel<<<dim3(TSEQ / 64, NH), 256, 0, stream>>>(qkv_bf, vT, attn_bf);
    gemm_p8_kernel<<<dim3((DM / 128) * 16, 3), 512, 0, stream>>>(attn_bf, woT, xf, DM, DM, 256);
    rmsnorm_kernel<<<TSEQ, 256, 0, stream>>>(xf, ln2 + (size_t)l * DM, h_bf);
    gemm_gu8_kernel<<<(FFD / 128) * 16, 512, 0, stream>>>(h_bf, wguT, wguT + (size_t)FFD * DM, m_bf);
    gemm_p8_kernel<<<dim3((DM / 128) * 16, 4), 512, 0, stream>>>(m_bf, wdT, xf, DM, FFD, 512);
  }

  rmsnorm_kernel<<<TSEQ, 256, 0, stream>>>(xf, normf, h_bf);
  gemm_l8_kernel<<<(VOC / 256) * (TSEQ / 256), 512, 0, stream>>>(h_bf, embed_bf, out, VOC, DM);
}

// Round 9
// 852.512 us; speedup vs baseline: 1.4617x; 1.0351x over previous
//
#include <hip/hip_runtime.h>

#define TSEQ 2048
#define DM   768
#define NH   12
#define NKV  4
#define HD   64
#define FFD  2048
#define NL   4
#define VOC  32000
#define QKVN 1280   // 768 q + 256 k + 256 v

typedef __attribute__((ext_vector_type(8))) short short8;
typedef __attribute__((ext_vector_type(4))) float f32x4;

__device__ __forceinline__ unsigned short f2b(float f) {
  unsigned int u = __float_as_uint(f);
  u += 0x7fffu + ((u >> 16) & 1u);
  return (unsigned short)(u >> 16);
}
__device__ __forceinline__ float b2f(unsigned short u) {
  return __uint_as_float(((unsigned int)u) << 16);
}
__device__ __forceinline__ unsigned int packbf(float a, float b) {
  return (unsigned int)f2b(a) | ((unsigned int)f2b(b) << 16);
}

// direct global->LDS async copy, 16B/lane; LDS dest wave-uniform (HW adds lane*16)
__device__ __forceinline__ void gl16(const unsigned short* g, unsigned short* l) {
  __builtin_amdgcn_global_load_lds(
      (const __attribute__((address_space(1))) void*)g,
      (__attribute__((address_space(3))) void*)l, 16, 0, 0);
}

// ---------------- cast f32 -> bf16 (vectorized x4) ----------------
__global__ void cast_bf16_kernel(const float* __restrict__ src,
                                 unsigned short* __restrict__ dst, int n4) {
  int i = blockIdx.x * blockDim.x + threadIdx.x;
  if (i >= n4) return;
  float4 v = ((const float4*)src)[i];
  uint2 o; o.x = packbf(v.x, v.y); o.y = packbf(v.z, v.w);
  ((uint2*)dst)[i] = o;
}

// ---------------- RoPE cos/sin table: [pos][d] for d in 0..31 ----------------
__global__ void rope_tab_kernel(float2* __restrict__ tab) {
  int i = blockIdx.x * blockDim.x + threadIdx.x;   // over TSEQ*32
  int pos = i >> 5, d = i & 31;
  float inv = exp2f(-(float)d * (13.287712379549449f / 32.0f));
  float sv, cv; sincosf((float)pos * inv, &sv, &cv);
  tab[i] = make_float2(cv, sv);
}

// ---------------- transpose + cast (batched over layers via blockIdx.z) ----------------
__global__ void transpose_cast_kernel(const float* __restrict__ src,
                                      unsigned short* __restrict__ dst,
                                      int K, int N, size_t sstride, size_t dstride) {
  __shared__ float tile[32][33];
  src += (size_t)blockIdx.z * sstride;
  dst += (size_t)blockIdx.z * dstride;
  int n0 = blockIdx.x * 32, k0 = blockIdx.y * 32;
  int tx = threadIdx.x, ty = threadIdx.y;  // 32 x 8
  #pragma unroll
  for (int i = 0; i < 4; ++i) {
    int r = ty + i * 8;
    tile[r][tx] = src[(size_t)(k0 + r) * N + n0 + tx];
  }
  __syncthreads();
  #pragma unroll
  for (int i = 0; i < 4; ++i) {
    int r = ty + i * 8;
    dst[(size_t)(n0 + r) * K + k0 + tx] = f2b(tile[tx][r]);
  }
}

// ---------------- embedding gather ----------------
__global__ void gather_kernel(const int* __restrict__ idx,
                              const float* __restrict__ embed,
                              float* __restrict__ x) {
  int row = blockIdx.x; int t = threadIdx.x;  // 192 threads, float4 each
  int id = idx[row];
  ((float4*)(x + (size_t)row * DM))[t] = ((const float4*)(embed + (size_t)id * DM))[t];
}

// ---------------- RMSNorm: f32 in -> bf16 out ----------------
__global__ void rmsnorm_kernel(const float* __restrict__ x,
                               const float* __restrict__ w,
                               unsigned short* __restrict__ out) {
  int row = blockIdx.x; int t = threadIdx.x;  // 256 threads, D=768
  const float* xr = x + (size_t)row * DM;
  float v0 = xr[t], v1 = xr[t + 256], v2 = xr[t + 512];
  float s = v0*v0 + v1*v1 + v2*v2;
  #pragma unroll
  for (int off = 1; off < 64; off <<= 1) s += __shfl_xor(s, off);
  __shared__ float red[4];
  if ((t & 63) == 0) red[t >> 6] = s;
  __syncthreads();
  float tot = red[0] + red[1] + red[2] + red[3];
  float rs = rsqrtf(tot * (1.0f / DM) + 1e-6f);
  unsigned short* orow = out + (size_t)row * DM;
  orow[t]       = f2b(w[t]       * v0 * rs);
  orow[t + 256] = f2b(w[t + 256] * v1 * rs);
  orow[t + 512] = f2b(w[t + 512] * v2 * rs);
}

// ---------------- 256x256 deep-pipelined GEMM (logits): C = A @ Bt^T, f32 out ----
__global__ __launch_bounds__(512, 1) void gemm_l8_kernel(
    const unsigned short* __restrict__ A, const unsigned short* __restrict__ Bt,
    float* __restrict__ C, int N, int K) {
  __shared__ unsigned short lds[2][2][256 * 64];   // [dbuf][A,B][row*64+col]
  const int NT = K >> 6;
  int bid = blockIdx.x, nwg = gridDim.x;
  int wgid = (bid & 7) * (nwg >> 3) + (bid >> 3);
  int m0 = (wgid & 7) * 256;        // 8 m-tiles (TSEQ/256)
  int n0 = (wgid >> 3) * 256;
  int tid = threadIdx.x;
  int lane = tid & 63, w = tid >> 6;
  int wm = w >> 2, wn = w & 3;
  int al = lane & 15, ag = lane >> 4;
  int swz = (al & 7) << 3;          // frag-read swizzle (shorts)

  int rA = tid >> 3;                                  // 0..63
  int cK = ((tid & 7) * 8) ^ ((rA & 7) << 3);         // bf16 col within 64
  const unsigned short* Ag = A + (size_t)(m0 + rA) * K + cK;
  const unsigned short* Bg = Bt + (size_t)(n0 + rA) * K + cK;

  f32x4 acc[8][4];
  #pragma unroll
  for (int i = 0; i < 8; ++i)
    #pragma unroll
    for (int n = 0; n < 4; ++n) acc[i][n] = (f32x4){0.f, 0.f, 0.f, 0.f};

  #define STAGE(kt, c) { \
    size_t ko = (size_t)(kt) * 64; \
    unsigned short* dA = &lds[(c)][0][0] + w * 512; \
    unsigned short* dB = &lds[(c)][1][0] + w * 512; \
    gl16(Ag + (size_t)0   * K + ko, dA);            \
    gl16(Ag + (size_t)64  * K + ko, dA + 4096);     \
    gl16(Ag + (size_t)128 * K + ko, dA + 8192);     \
    gl16(Ag + (size_t)192 * K + ko, dA + 12288);    \
    gl16(Bg + (size_t)0   * K + ko, dB);            \
    gl16(Bg + (size_t)64  * K + ko, dB + 4096);     \
    gl16(Bg + (size_t)128 * K + ko, dB + 8192);     \
    gl16(Bg + (size_t)192 * K + ko, dB + 12288);    \
  }

  STAGE(0, 0);
  STAGE(1, 1);
  asm volatile("s_waitcnt vmcnt(8)" ::: "memory");
  __builtin_amdgcn_s_barrier();

  for (int t = 0; t < NT; ++t) {
    int cur = t & 1;
    const unsigned short* La = &lds[cur][0][0];
    const unsigned short* Lb = &lds[cur][1][0];
    short8 a0[8], b0[4], a1[8], b1[4];
    #pragma unroll
    for (int i = 0; i < 8; ++i)
      a0[i] = *(const short8*)&La[(wm*128 + i*16 + al)*64 + ((ag*8) ^ swz)];
    #pragma unroll
    for (int n = 0; n < 4; ++n)
      b0[n] = *(const short8*)&Lb[(wn*64 + n*16 + al)*64 + ((ag*8) ^ swz)];
    #pragma unroll
    for (int i = 0; i < 8; ++i)
      #pragma unroll
      for (int n = 0; n < 4; ++n)
        acc[i][n] = __builtin_amdgcn_mfma_f32_16x16x32_bf16(a0[i], b0[n], acc[i][n], 0, 0, 0);
    #pragma unroll
    for (int i = 0; i < 8; ++i)
      a1[i] = *(const short8*)&La[(wm*128 + i*16 + al)*64 + ((32 + ag*8) ^ swz)];
    #pragma unroll
    for (int n = 0; n < 4; ++n)
      b1[n] = *(const short8*)&Lb[(wn*64 + n*16 + al)*64 + ((32 + ag*8) ^ swz)];
    asm volatile("s_waitcnt lgkmcnt(0)" ::: "memory");
    __builtin_amdgcn_s_barrier();
    if (t + 2 < NT) STAGE(t + 2, cur);
    __builtin_amdgcn_s_setprio(1);
    #pragma unroll
    for (int i = 0; i < 8; ++i)
      #pragma unroll
      for (int n = 0; n < 4; ++n)
        acc[i][n] = __builtin_amdgcn_mfma_f32_16x16x32_bf16(a1[i], b1[n], acc[i][n], 0, 0, 0);
    __builtin_amdgcn_s_setprio(0);
    if (t + 2 < NT) { asm volatile("s_waitcnt vmcnt(8)" ::: "memory"); }
    else            { asm volatile("s_waitcnt vmcnt(0)" ::: "memory"); }
    __builtin_amdgcn_s_barrier();
  }
  #undef STAGE

  #pragma unroll
  for (int i = 0; i < 8; ++i)
    #pragma unroll
    for (int r = 0; r < 4; ++r) {
      float* Cr = C + (size_t)(m0 + wm*128 + i*16 + ag*4 + r) * N + n0 + wn*64 + al;
      #pragma unroll
      for (int n = 0; n < 4; ++n) Cr[n * 16] = acc[i][n][r];
    }
}

// ---------------- 128x128 pipelined 8-wave GEMM, split-K, f32 atomicAdd ----------
__global__ __launch_bounds__(512) void gemm_p8_kernel(
    const unsigned short* __restrict__ A, const unsigned short* __restrict__ Bt,
    float* __restrict__ C, int N, int K, int Kc) {
  __shared__ unsigned short lds[2][2][128 * 64];
  const int NT = Kc >> 6;
  int bid = blockIdx.x, nwg = gridDim.x;
  int wgid = (bid & 7) * (nwg >> 3) + (bid >> 3);
  int m0 = (wgid & 15) * 128;
  int n0 = (wgid >> 4) * 128;
  int tid = threadIdx.x;
  int lane = tid & 63, w = tid >> 6;
  int wm = w >> 2, wn = w & 3;
  int al = lane & 15, ag = lane >> 4;
  int swz = (al & 7) << 3;

  size_t koff = (size_t)blockIdx.y * Kc;
  int rp = 8 * w + (lane >> 3);
  int cK = ((lane & 7) * 8) ^ ((lane >> 3) << 3);
  const unsigned short* Ag = A + (size_t)(m0 + rp) * K + koff + cK;
  const unsigned short* Bg = Bt + (size_t)(n0 + rp) * K + koff + cK;

  f32x4 acc[4][2];
  #pragma unroll
  for (int i = 0; i < 4; ++i)
    #pragma unroll
    for (int n = 0; n < 2; ++n) acc[i][n] = (f32x4){0.f, 0.f, 0.f, 0.f};

  #define STAGE(kt, c) { \
    size_t ko = (size_t)(kt) * 64; \
    unsigned short* dA = &lds[(c)][0][0] + w * 512; \
    unsigned short* dB = &lds[(c)][1][0] + w * 512; \
    gl16(Ag + ko,                 dA);        \
    gl16(Ag + (size_t)64*K + ko,  dA + 4096); \
    gl16(Bg + ko,                 dB);        \
    gl16(Bg + (size_t)64*K + ko,  dB + 4096); \
  }

  STAGE(0, 0);
  STAGE(1, 1);
  asm volatile("s_waitcnt vmcnt(4)" ::: "memory");
  __builtin_amdgcn_s_barrier();

  for (int t = 0; t < NT; ++t) {
    int cur = t & 1;
    const unsigned short* La = &lds[cur][0][0];
    const unsigned short* Lb = &lds[cur][1][0];
    short8 a0[4], b0[2], a1[4], b1[2];
    #pragma unroll
    for (int i = 0; i < 4; ++i)
      a0[i] = *(const short8*)&La[(wm*64 + i*16 + al)*64 + ((ag*8) ^ swz)];
    #pragma unroll
    for (int n = 0; n < 2; ++n)
      b0[n] = *(const short8*)&Lb[(wn*32 + n*16 + al)*64 + ((ag*8) ^ swz)];
    #pragma unroll
    for (int i = 0; i < 4; ++i)
      #pragma unroll
      for (int n = 0; n < 2; ++n)
        acc[i][n] = __builtin_amdgcn_mfma_f32_16x16x32_bf16(a0[i], b0[n], acc[i][n], 0, 0, 0);
    #pragma unroll
    for (int i = 0; i < 4; ++i)
      a1[i] = *(const short8*)&La[(wm*64 + i*16 + al)*64 + ((32 + ag*8) ^ swz)];
    #pragma unroll
    for (int n = 0; n < 2; ++n)
      b1[n] = *(const short8*)&Lb[(wn*32 + n*16 + al)*64 + ((32 + ag*8) ^ swz)];
    asm volatile("s_waitcnt lgkmcnt(0)" ::: "memory");
    __builtin_amdgcn_s_barrier();
    if (t + 2 < NT) STAGE(t + 2, cur);
    __builtin_amdgcn_s_setprio(1);
    #pragma unroll
    for (int i = 0; i < 4; ++i)
      #pragma unroll
      for (int n = 0; n < 2; ++n)
        acc[i][n] = __builtin_amdgcn_mfma_f32_16x16x32_bf16(a1[i], b1[n], acc[i][n], 0, 0, 0);
    __builtin_amdgcn_s_setprio(0);
    if (t + 2 < NT) { asm volatile("s_waitcnt vmcnt(4)" ::: "memory"); }
    else            { asm volatile("s_waitcnt vmcnt(0)" ::: "memory"); }
    __builtin_amdgcn_s_barrier();
  }
  #undef STAGE

  #pragma unroll
  for (int i = 0; i < 4; ++i)
    #pragma unroll
    for (int r = 0; r < 4; ++r) {
      float* Cr = C + (size_t)(m0 + wm*64 + i*16 + ag*4 + r) * N + n0 + wn*32 + al;
      #pragma unroll
      for (int n = 0; n < 2; ++n) atomicAdd(&Cr[n * 16], acc[i][n][r]);
    }
}

// ---------------- gelu ----------------
__device__ __forceinline__ float gelu_t(float x) {
  float x3 = x * x * x;
  return 0.5f * x * (1.0f + tanhf(0.7978845608028654f * (x + 0.044715f * x3)));
}

// ---- pipelined gate/up GEMM: tile 128 rows x [G128|U128], 8 waves, BK=64 ----
__global__ __launch_bounds__(512) void gemm_gu8_kernel(
    const unsigned short* __restrict__ A, const unsigned short* __restrict__ BtG,
    const unsigned short* __restrict__ BtU, unsigned short* __restrict__ Cm) {
  __shared__ unsigned short lds[2][3][128 * 64];   // [dbuf][A,G,U]
  const int K = DM;
  const int NT = K >> 6;                           // 12
  int bid = blockIdx.x, nwg = gridDim.x;           // 256
  int wgid = (bid & 7) * (nwg >> 3) + (bid >> 3);
  int m0 = (wgid & 15) * 128;
  int n0 = (wgid >> 4) * 128;                      // over FF
  int tid = threadIdx.x;
  int lane = tid & 63, w = tid >> 6;
  int wm = w >> 2, wn = w & 3;
  int al = lane & 15, ag = lane >> 4;
  int swz = (al & 7) << 3;

  int rp = 8 * w + (lane >> 3);
  int cK = ((lane & 7) * 8) ^ ((lane >> 3) << 3);
  const unsigned short* Ag = A + (size_t)(m0 + rp) * K + cK;
  const unsigned short* Gg = BtG + (size_t)(n0 + rp) * K + cK;
  const unsigned short* Ug = BtU + (size_t)(n0 + rp) * K + cK;

  f32x4 accg[4][2], accu[4][2];
  #pragma unroll
  for (int i = 0; i < 4; ++i)
    #pragma unroll
    for (int n = 0; n < 2; ++n) {
      accg[i][n] = (f32x4){0.f, 0.f, 0.f, 0.f};
      accu[i][n] = (f32x4){0.f, 0.f, 0.f, 0.f};
    }

  #define STAGE(kt, c) { \
    size_t ko = (size_t)(kt) * 64; \
    unsigned short* dA = &lds[(c)][0][0] + w * 512; \
    unsigned short* dG = &lds[(c)][1][0] + w * 512; \
    unsigned short* dU = &lds[(c)][2][0] + w * 512; \
    gl16(Ag + ko,                 dA);        \
    gl16(Ag + (size_t)64*K + ko,  dA + 4096); \
    gl16(Gg + ko,                 dG);        \
    gl16(Gg + (size_t)64*K + ko,  dG + 4096); \
    gl16(Ug + ko,                 dU);        \
    gl16(Ug + (size_t)64*K + ko,  dU + 4096); \
  }

  STAGE(0, 0);
  STAGE(1, 1);
  asm volatile("s_waitcnt vmcnt(6)" ::: "memory");
  __builtin_amdgcn_s_barrier();

  for (int t = 0; t < NT; ++t) {
    int cur = t & 1;
    const unsigned short* La = &lds[cur][0][0];
    const unsigned short* Lg = &lds[cur][1][0];
    const unsigned short* Lu = &lds[cur][2][0];
    short8 a0[4], g0[2], u0[2], a1[4], g1[2], u1[2];
    #pragma unroll
    for (int i = 0; i < 4; ++i)
      a0[i] = *(const short8*)&La[(wm*64 + i*16 + al)*64 + ((ag*8) ^ swz)];
    #pragma unroll
    for (int n = 0; n < 2; ++n) {
      g0[n] = *(const short8*)&Lg[(wn*32 + n*16 + al)*64 + ((ag*8) ^ swz)];
      u0[n] = *(const short8*)&Lu[(wn*32 + n*16 + al)*64 + ((ag*8) ^ swz)];
    }
    #pragma unroll
    for (int i = 0; i < 4; ++i)
      #pragma unroll
      for (int n = 0; n < 2; ++n) {
        accg[i][n] = __builtin_amdgcn_mfma_f32_16x16x32_bf16(a0[i], g0[n], accg[i][n], 0, 0, 0);
        accu[i][n] = __builtin_amdgcn_mfma_f32_16x16x32_bf16(a0[i], u0[n], accu[i][n], 0, 0, 0);
      }
    #pragma unroll
    for (int i = 0; i < 4; ++i)
      a1[i] = *(const short8*)&La[(wm*64 + i*16 + al)*64 + ((32 + ag*8) ^ swz)];
    #pragma unroll
    for (int n = 0; n < 2; ++n) {
      g1[n] = *(const short8*)&Lg[(wn*32 + n*16 + al)*64 + ((32 + ag*8) ^ swz)];
      u1[n] = *(const short8*)&Lu[(wn*32 + n*16 + al)*64 + ((32 + ag*8) ^ swz)];
    }
    asm volatile("s_waitcnt lgkmcnt(0)" ::: "memory");
    __builtin_amdgcn_s_barrier();
    if (t + 2 < NT) STAGE(t + 2, cur);
    __builtin_amdgcn_s_setprio(1);
    #pragma unroll
    for (int i = 0; i < 4; ++i)
      #pragma unroll
      for (int n = 0; n < 2; ++n) {
        accg[i][n] = __builtin_amdgcn_mfma_f32_16x16x32_bf16(a1[i], g1[n], accg[i][n], 0, 0, 0);
        accu[i][n] = __builtin_amdgcn_mfma_f32_16x16x32_bf16(a1[i], u1[n], accu[i][n], 0, 0, 0);
      }
    __builtin_amdgcn_s_setprio(0);
    if (t + 2 < NT) { asm volatile("s_waitcnt vmcnt(6)" ::: "memory"); }
    else            { asm volatile("s_waitcnt vmcnt(0)" ::: "memory"); }
    __builtin_amdgcn_s_barrier();
  }
  #undef STAGE

  #pragma unroll
  for (int i = 0; i < 4; ++i)
    #pragma unroll
    for (int r = 0; r < 4; ++r) {
      unsigned short* Cr = Cm + (size_t)(m0 + wm*64 + i*16 + ag*4 + r) * FFD + n0 + wn*32 + al;
      #pragma unroll
      for (int n = 0; n < 2; ++n)
        Cr[n * 16] = f2b(gelu_t(accg[i][n][r]) * accu[i][n][r]);
    }
}

// ------- QKV GEMM (128x128, reg-staged): q/k -> RoPE'd bf16; V -> vT transposed ----
__global__ __launch_bounds__(256) void gemm_qkv_kernel(
    const unsigned short* __restrict__ A, const unsigned short* __restrict__ Bt,
    unsigned short* __restrict__ C, unsigned short* __restrict__ vT,
    const float2* __restrict__ rope_tab) {
  const int N = QKVN, K = DM;
  __shared__ unsigned short As[128 * 40];
  __shared__ unsigned short Bs[128 * 40];
  int bid = blockIdx.x, nwg = gridDim.x;
  int wgid = (bid & 7) * (nwg >> 3) + (bid >> 3);
  int m0 = (wgid & 15) * 128;
  int n0 = (wgid >> 4) * 128;
  int tid = threadIdx.x;
  int lane = tid & 63, wave = tid >> 6;
  int wr = (wave >> 1) * 64, wc = (wave & 1) * 64;
  int l16 = lane & 15, lk8 = (lane >> 4) * 8;
  f32x4 acc[4][4];
  #pragma unroll
  for (int m = 0; m < 4; ++m)
    #pragma unroll
    for (int n = 0; n < 4; ++n) acc[m][n] = (f32x4){0.f, 0.f, 0.f, 0.f};
  const unsigned short* Abase = A + (size_t)m0 * K;
  const unsigned short* Bbase = Bt + (size_t)n0 * K;
  int r0 = tid >> 2;            // 0..63
  int c0 = (tid & 3) * 8;       // 0,8,16,24
  for (int k0 = 0; k0 < K; k0 += 32) {
    uint4 a0 = *(const uint4*)(Abase + (size_t)r0 * K + k0 + c0);
    uint4 a1 = *(const uint4*)(Abase + (size_t)(r0 + 64) * K + k0 + c0);
    uint4 b0 = *(const uint4*)(Bbase + (size_t)r0 * K + k0 + c0);
    uint4 b1 = *(const uint4*)(Bbase + (size_t)(r0 + 64) * K + k0 + c0);
    *(uint4*)&As[r0 * 40 + c0] = a0;
    *(uint4*)&As[(r0 + 64) * 40 + c0] = a1;
    *(uint4*)&Bs[r0 * 40 + c0] = b0;
    *(uint4*)&Bs[(r0 + 64) * 40 + c0] = b1;
    __syncthreads();
    short8 af[4], bfr[4];
    #pragma unroll
    for (int m = 0; m < 4; ++m) af[m]  = *(const short8*)&As[(wr + m*16 + l16) * 40 + lk8];
    #pragma unroll
    for (int n = 0; n < 4; ++n) bfr[n] = *(const short8*)&Bs[(wc + n*16 + l16) * 40 + lk8];
    #pragma unroll
    for (int m = 0; m < 4; ++m)
      #pragma unroll
      for (int n = 0; n < 4; ++n)
        acc[m][n] = __builtin_amdgcn_mfma_f32_16x16x32_bf16(af[m], bfr[n], acc[m][n], 0, 0, 0);
    __syncthreads();
  }
  bool qk = (n0 + wc) < 1024;   // whole 64-col group = one q/k head (RoPE) else V head
  #pragma unroll
  for (int m = 0; m < 4; ++m)
    #pragma unroll
    for (int r = 0; r < 4; ++r) {
      int pos = m0 + wr + m*16 + ((lane >> 4) << 2) + r;
      if (qk) {
        unsigned short* Cr = C + (size_t)pos * N + n0 + wc + l16;
        #pragma unroll
        for (int n = 0; n < 2; ++n) {
          int d = n * 16 + l16;                 // 0..31 within head
          float2 cs = rope_tab[pos * 32 + d];
          float x1 = acc[m][n][r], x2 = acc[m][n + 2][r];
          Cr[n * 16]       = f2b(x1 * cs.x - x2 * cs.y);
          Cr[(n + 2) * 16] = f2b(x2 * cs.x + x1 * cs.y);
        }
      } else {
        // V columns: write transposed vT[(kvh*64+d)][pos]
        #pragma unroll
        for (int n = 0; n < 4; ++n) {
          int hb = n0 + wc + n*16 + l16 - 1024;   // 0..255
          vT[(size_t)hb * TSEQ + pos] = f2b(acc[m][n][r]);
        }
      }
    }
}

// ---------------- MFMA flash attention, causal, GQA ----------------
// K from qkv (row-major), V from vT (pre-transposed [256][TSEQ]).
// Double-buffered LDS K/V via global_load_lds (pre-swizzled source, linear dest);
// counted vmcnt(4) keeps next tile's 4 loads in flight across barriers (T3+T4).
__global__ __launch_bounds__(256) void attn_mfma_kernel(
    const unsigned short* __restrict__ qkv, const unsigned short* __restrict__ vT,
    unsigned short* __restrict__ out) {
  __shared__ unsigned short Ks[2][64 * 64];
  __shared__ unsigned short Vt[2][64 * 64];
  __shared__ unsigned short Ps[4][16 * 64];
  int h = blockIdx.y;
  int qt = gridDim.x - 1 - blockIdx.x;   // heavy (deep-causal) blocks dispatch first
  int r0 = qt * 64;
  int kvh = h / 3;           // N_REP = 3
  int t = threadIdx.x;
  int lane = t & 63, w = t >> 6;
  int l16 = lane & 15, g = lane >> 4;

  int qr = r0 + w * 16 + l16;
  const unsigned short* qrow = qkv + (size_t)qr * QKVN + h * HD;
  short8 aq0 = *(const short8*)(qrow + 8 * g);
  short8 aq1 = *(const short8*)(qrow + 32 + 8 * g);

  // staging sources: lane l covers row base+(l>>3), source chunk (l&7)^(l>>3)
  // so the LINEAR LDS image satisfies stored[row][c] = global[row][c ^ (row&7)]
  // (row&7 == l>>3 since all row bases are multiples of 8) — matches frag reads.
  int sw = (lane & 7) ^ (lane >> 3);
  int rloc = w * 16 + (lane >> 3);          // K key / V d row for issue 0 (+8 for issue 1)
  const unsigned short* kgb = qkv + (size_t)rloc * QKVN + DM + kvh * HD + 8 * sw;
  const unsigned short* vgb = vT + (size_t)(kvh * 64 + rloc) * TSEQ + 8 * sw;

  #define ASTAGE(kb, c) { \
    unsigned short* kd = &Ks[(c)][0] + w * 1024; \
    unsigned short* vd = &Vt[(c)][0] + w * 1024; \
    gl16(kgb + (size_t)(kb) * QKVN,       kd);       \
    gl16(kgb + (size_t)((kb) + 8) * QKVN, kd + 512); \
    gl16(vgb + (kb),                      vd);       \
    gl16(vgb + (size_t)8 * TSEQ + (kb),   vd + 512); \
  }

  f32x4 o_acc[4];
  float mrun[4], lsum[4];
  #pragma unroll
  for (int i = 0; i < 4; ++i) { o_acc[i] = (f32x4){0.f,0.f,0.f,0.f}; mrun[i] = -1e30f; lsum[i] = 0.f; }

  int nt = qt + 1;
  ASTAGE(0, 0);
  for (int kt = 0; kt < nt; ++kt) {
    int cur = kt & 1;
    int kb = kt * 64;
    if (kt + 1 < nt) {
      ASTAGE((kt + 1) * 64, cur ^ 1);                     // prefetch next tile
      asm volatile("s_waitcnt vmcnt(4)" ::: "memory");    // current tile's 4 done
    } else {
      asm volatile("s_waitcnt vmcnt(0)" ::: "memory");
    }
    __builtin_amdgcn_s_barrier();

    const unsigned short* Kc = &Ks[cur][0];
    const unsigned short* Vc = &Vt[cur][0];

    f32x4 s_acc[4];
    #pragma unroll
    for (int nb = 0; nb < 4; ++nb) s_acc[nb] = (f32x4){0.f,0.f,0.f,0.f};
    #pragma unroll
    for (int nb = 0; nb < 4; ++nb) {
      int key = nb * 16 + l16;
      short8 bk0 = *(const short8*)&Kc[key * 64 + ((g       ^ (key & 7)) << 3)];
      short8 bk1 = *(const short8*)&Kc[key * 64 + (((4 + g) ^ (key & 7)) << 3)];
      s_acc[nb] = __builtin_amdgcn_mfma_f32_16x16x32_bf16(aq0, bk0, s_acc[nb], 0, 0, 0);
      s_acc[nb] = __builtin_amdgcn_mfma_f32_16x16x32_bf16(aq1, bk1, s_acc[nb], 0, 0, 0);
    }

    bool diag = (kt == qt);
    #pragma unroll
    for (int r = 0; r < 4; ++r) {
      int qg = r0 + w * 16 + g * 4 + r;
      float sv[4];
      #pragma unroll
      for (int nb = 0; nb < 4; ++nb) {
        sv[nb] = s_acc[nb][r] * 0.125f;
        if (diag && (kb + nb * 16 + l16 > qg)) sv[nb] = -1e30f;
      }
      float mx = fmaxf(fmaxf(sv[0], sv[1]), fmaxf(sv[2], sv[3]));
      mx = fmaxf(mx, __shfl_xor(mx, 1));
      mx = fmaxf(mx, __shfl_xor(mx, 2));
      mx = fmaxf(mx, __shfl_xor(mx, 4));
      mx = fmaxf(mx, __shfl_xor(mx, 8));
      // defer-max (T13, THR=8): only rescale when the max moved materially
      if (mx > mrun[r] + 8.0f) {
        float es = __expf(mrun[r] - mx);
        lsum[r] *= es;
        #pragma unroll
        for (int db = 0; db < 4; ++db) o_acc[db][r] *= es;
        mrun[r] = mx;
      }
      float rsum = 0.f;
      #pragma unroll
      for (int nb = 0; nb < 4; ++nb) { sv[nb] = __expf(sv[nb] - mrun[r]); rsum += sv[nb]; }
      lsum[r] += rsum;   // per-lane partial; reduced once at the end
      int qloc = g * 4 + r, q7 = qloc & 7;
      #pragma unroll
      for (int nb = 0; nb < 4; ++nb) {
        int key = nb * 16 + l16;
        Ps[w][qloc * 64 + ((((key >> 3) ^ q7) << 3) + (key & 7))] = f2b(sv[nb]);
      }
    }

    #pragma unroll
    for (int kc = 0; kc < 2; ++kc) {
      short8 pa = *(const short8*)&Ps[w][l16 * 64 + (((4 * kc + g) ^ (l16 & 7)) << 3)];
      #pragma unroll
      for (int db = 0; db < 4; ++db) {
        int d = db * 16 + l16;
        short8 bv = *(const short8*)&Vc[d * 64 + (((4 * kc + g) ^ (d & 7)) << 3)];
        o_acc[db] = __builtin_amdgcn_mfma_f32_16x16x32_bf16(pa, bv, o_acc[db], 0, 0, 0);
      }
    }
    __builtin_amdgcn_s_barrier();   // all reads of buf[cur] done before its overwrite
  }
  #undef ASTAGE

  #pragma unroll
  for (int r = 0; r < 4; ++r) {
    int qg = r0 + w * 16 + g * 4 + r;
    float s = lsum[r];
    s += __shfl_xor(s, 1);
    s += __shfl_xor(s, 2);
    s += __shfl_xor(s, 4);
    s += __shfl_xor(s, 8);
    float inv = 1.0f / s;
    unsigned short* orow = out + (size_t)qg * DM + h * HD + l16;
    #pragma unroll
    for (int db = 0; db < 4; ++db) orow[db * 16] = f2b(o_acc[db][r] * inv);
  }
}

extern "C" void kernel_launch(void* const* d_in, const int* in_sizes, int n_in,
                              void* d_out, int out_size, void* d_ws, size_t ws_size,
                              hipStream_t stream) {
  const int*   idx   = (const int*)d_in[0];
  const float* embed = (const float*)d_in[1];
  const float* ln1   = (const float*)d_in[2];
  const float* Wq    = (const float*)d_in[3];
  const float* Wk    = (const float*)d_in[4];
  const float* Wv    = (const float*)d_in[5];
  const float* Wo    = (const float*)d_in[6];
  const float* ln2   = (const float*)d_in[7];
  const float* Wg    = (const float*)d_in[8];
  const float* Wu    = (const float*)d_in[9];
  const float* Wd    = (const float*)d_in[10];
  const float* normf = (const float*)d_in[11];
  float* out = (float*)d_out;
  char* ws = (char*)d_ws;
  (void)in_sizes; (void)n_in; (void)out_size; (void)ws_size;

  // ---- workspace layout ----
  unsigned short* embed_bf = (unsigned short*)ws;
  size_t off = (size_t)VOC * DM * 2;
  unsigned short* wts = (unsigned short*)(ws + off);
  const size_t LW = (size_t)QKVN * DM + (size_t)DM * DM
                  + 2ull * FFD * DM + (size_t)DM * FFD;
  off += LW * 2ull * NL;
  float* xf = (float*)(ws + off);            off += (size_t)TSEQ * DM * 4;
  unsigned short* h_bf = (unsigned short*)(ws + off);    off += (size_t)TSEQ * DM * 2;
  unsigned short* qkv_bf = (unsigned short*)(ws + off);  off += (size_t)TSEQ * QKVN * 2;
  unsigned short* attn_bf = (unsigned short*)(ws + off); off += (size_t)TSEQ * DM * 2;
  unsigned short* m_bf = (unsigned short*)(ws + off);    off += (size_t)TSEQ * FFD * 2;
  float2* rope_tab = (float2*)(ws + off);    off += (size_t)TSEQ * 32 * 8;
  unsigned short* vT = (unsigned short*)(ws + off);      off += (size_t)NKV * HD * TSEQ * 2;

  // ---- prep: embed cast + rope table + batched weight transpose/cast ----
  cast_bf16_kernel<<<(VOC * DM / 4 + 255) / 256, 256, 0, stream>>>(embed, embed_bf, VOC * DM / 4);
  rope_tab_kernel<<<TSEQ * 32 / 256, 256, 0, stream>>>(rope_tab);

  {
    unsigned short* qkvT = wts;
    unsigned short* woT  = wts + (size_t)QKVN * DM;
    unsigned short* wguT = woT + (size_t)DM * DM;
    unsigned short* wdT  = wguT + 2ull * FFD * DM;
    transpose_cast_kernel<<<dim3(24, 24, NL), dim3(32, 8), 0, stream>>>(Wq, qkvT, 768, 768, 589824, LW);
    transpose_cast_kernel<<<dim3(8, 24, NL),  dim3(32, 8), 0, stream>>>(Wk, qkvT + 768ull * 768, 768, 256, 196608, LW);
    transpose_cast_kernel<<<dim3(8, 24, NL),  dim3(32, 8), 0, stream>>>(Wv, qkvT + 1024ull * 768, 768, 256, 196608, LW);
    transpose_cast_kernel<<<dim3(24, 24, NL), dim3(32, 8), 0, stream>>>(Wo, woT, 768, 768, 589824, LW);
    transpose_cast_kernel<<<dim3(64, 24, NL), dim3(32, 8), 0, stream>>>(Wg, wguT, 768, 2048, 1572864, LW);
    transpose_cast_kernel<<<dim3(64, 24, NL), dim3(32, 8), 0, stream>>>(Wu, wguT + (size_t)FFD * DM, 768, 2048, 1572864, LW);
    transpose_cast_kernel<<<dim3(24, 64, NL), dim3(32, 8), 0, stream>>>(Wd, wdT, 2048, 768, 1572864, LW);
  }

  gather_kernel<<<TSEQ, 192, 0, stream>>>(idx, embed, xf);

  for (int l = 0; l < NL; ++l) {
    unsigned short* base = wts + (size_t)l * LW;
    unsigned short* qkvT = base;
    unsigned short* woT  = base + (size_t)QKVN * DM;
    unsigned short* wguT = woT + (size_t)DM * DM;
    unsigned short* wdT  = wguT + 2ull * FFD * DM;

    rmsnorm_kernel<<<TSEQ, 256, 0, stream>>>(xf, ln1 + (size_t)l * DM, h_bf);
    gemm_qkv_kernel<<<(QKVN / 128) * 16, 256, 0, stream>>>(h_bf, qkvT, qkv_bf, vT, rope_tab);
    attn_mfma_kernel<<<dim3(TSEQ / 64, NH), 256, 0, stream>>>(qkv_bf, vT, attn_bf);
    gemm_p8_kernel<<<dim3((DM / 128) * 16, 3), 512, 0, stream>>>(attn_bf, woT, xf, DM, DM, 256);
    rmsnorm_kernel<<<TSEQ, 256, 0, stream>>>(xf, ln2 + (size_t)l * DM, h_bf);
    gemm_gu8_kernel<<<(FFD / 128) * 16, 512, 0, stream>>>(h_bf, wguT, wguT + (size_t)FFD * DM, m_bf);
    gemm_p8_kernel<<<dim3((DM / 128) * 16, 4), 512, 0, stream>>>(m_bf, wdT, xf, DM, FFD, 512);
  }

  rmsnorm_kernel<<<TSEQ, 256, 0, stream>>>(xf, normf, h_bf);
  gemm_l8_kernel<<<(VOC / 256) * (TSEQ / 256), 512, 0, stream>>>(h_bf, embed_bf, out, VOC, DM);
}

// Round 10
// 769.757 us; speedup vs baseline: 1.6189x; 1.1075x over previous
//
#include <hip/hip_runtime.h>

#define TSEQ 2048
#define DM   768
#define NH   12
#define NKV  4
#define HD   64
#define FFD  2048
#define NL   4
#define VOC  32000
#define QKVN 1280   // 768 q + 256 k + 256 v

typedef __attribute__((ext_vector_type(8))) short short8;
typedef __attribute__((ext_vector_type(4))) float f32x4;

__device__ __forceinline__ unsigned short f2b(float f) {
  unsigned int u = __float_as_uint(f);
  u += 0x7fffu + ((u >> 16) & 1u);
  return (unsigned short)(u >> 16);
}
__device__ __forceinline__ float b2f(unsigned short u) {
  return __uint_as_float(((unsigned int)u) << 16);
}
__device__ __forceinline__ unsigned int packbf(float a, float b) {
  return (unsigned int)f2b(a) | ((unsigned int)f2b(b) << 16);
}

// direct global->LDS async copy, 16B/lane; LDS dest wave-uniform (HW adds lane*16)
__device__ __forceinline__ void gl16(const unsigned short* g, unsigned short* l) {
  __builtin_amdgcn_global_load_lds(
      (const __attribute__((address_space(1))) void*)g,
      (__attribute__((address_space(3))) void*)l, 16, 0, 0);
}

// ---------------- cast f32 -> bf16 (vectorized x4) ----------------
__global__ void cast_bf16_kernel(const float* __restrict__ src,
                                 unsigned short* __restrict__ dst, int n4) {
  int i = blockIdx.x * blockDim.x + threadIdx.x;
  if (i >= n4) return;
  float4 v = ((const float4*)src)[i];
  uint2 o; o.x = packbf(v.x, v.y); o.y = packbf(v.z, v.w);
  ((uint2*)dst)[i] = o;
}

// ---------------- RoPE cos/sin table: [pos][d] for d in 0..31 ----------------
__global__ void rope_tab_kernel(float2* __restrict__ tab) {
  int i = blockIdx.x * blockDim.x + threadIdx.x;   // over TSEQ*32
  int pos = i >> 5, d = i & 31;
  float inv = exp2f(-(float)d * (13.287712379549449f / 32.0f));
  float sv, cv; sincosf((float)pos * inv, &sv, &cv);
  tab[i] = make_float2(cv, sv);
}

// ---------------- transpose + cast (batched over layers via blockIdx.z) ----------------
__global__ void transpose_cast_kernel(const float* __restrict__ src,
                                      unsigned short* __restrict__ dst,
                                      int K, int N, size_t sstride, size_t dstride) {
  __shared__ float tile[32][33];
  src += (size_t)blockIdx.z * sstride;
  dst += (size_t)blockIdx.z * dstride;
  int n0 = blockIdx.x * 32, k0 = blockIdx.y * 32;
  int tx = threadIdx.x, ty = threadIdx.y;  // 32 x 8
  #pragma unroll
  for (int i = 0; i < 4; ++i) {
    int r = ty + i * 8;
    tile[r][tx] = src[(size_t)(k0 + r) * N + n0 + tx];
  }
  __syncthreads();
  #pragma unroll
  for (int i = 0; i < 4; ++i) {
    int r = ty + i * 8;
    dst[(size_t)(n0 + r) * K + k0 + tx] = f2b(tile[tx][r]);
  }
}

// ---------------- embedding gather ----------------
__global__ void gather_kernel(const int* __restrict__ idx,
                              const float* __restrict__ embed,
                              float* __restrict__ x) {
  int row = blockIdx.x; int t = threadIdx.x;  // 192 threads, float4 each
  int id = idx[row];
  ((float4*)(x + (size_t)row * DM))[t] = ((const float4*)(embed + (size_t)id * DM))[t];
}

// ---------------- RMSNorm: f32 in -> bf16 out ----------------
__global__ void rmsnorm_kernel(const float* __restrict__ x,
                               const float* __restrict__ w,
                               unsigned short* __restrict__ out) {
  int row = blockIdx.x; int t = threadIdx.x;  // 256 threads, D=768
  const float* xr = x + (size_t)row * DM;
  float v0 = xr[t], v1 = xr[t + 256], v2 = xr[t + 512];
  float s = v0*v0 + v1*v1 + v2*v2;
  #pragma unroll
  for (int off = 1; off < 64; off <<= 1) s += __shfl_xor(s, off);
  __shared__ float red[4];
  if ((t & 63) == 0) red[t >> 6] = s;
  __syncthreads();
  float tot = red[0] + red[1] + red[2] + red[3];
  float rs = rsqrtf(tot * (1.0f / DM) + 1e-6f);
  unsigned short* orow = out + (size_t)row * DM;
  orow[t]       = f2b(w[t]       * v0 * rs);
  orow[t + 256] = f2b(w[t + 256] * v1 * rs);
  orow[t + 512] = f2b(w[t + 512] * v2 * rs);
}

// ---------------- 256x256 deep-pipelined GEMM (logits): C = A @ Bt^T, f32 out ----
__global__ __launch_bounds__(512, 1) void gemm_l8_kernel(
    const unsigned short* __restrict__ A, const unsigned short* __restrict__ Bt,
    float* __restrict__ C, int N, int K) {
  __shared__ unsigned short lds[2][2][256 * 64];   // [dbuf][A,B][row*64+col]
  const int NT = K >> 6;
  int bid = blockIdx.x, nwg = gridDim.x;
  int wgid = (bid & 7) * (nwg >> 3) + (bid >> 3);
  int m0 = (wgid & 7) * 256;        // 8 m-tiles (TSEQ/256)
  int n0 = (wgid >> 3) * 256;
  int tid = threadIdx.x;
  int lane = tid & 63, w = tid >> 6;
  int wm = w >> 2, wn = w & 3;
  int al = lane & 15, ag = lane >> 4;
  int swz = (al & 7) << 3;          // frag-read swizzle (shorts)

  int rA = tid >> 3;                                  // 0..63
  int cK = ((tid & 7) * 8) ^ ((rA & 7) << 3);         // bf16 col within 64
  const unsigned short* Ag = A + (size_t)(m0 + rA) * K + cK;
  const unsigned short* Bg = Bt + (size_t)(n0 + rA) * K + cK;

  f32x4 acc[8][4];
  #pragma unroll
  for (int i = 0; i < 8; ++i)
    #pragma unroll
    for (int n = 0; n < 4; ++n) acc[i][n] = (f32x4){0.f, 0.f, 0.f, 0.f};

  #define STAGE(kt, c) { \
    size_t ko = (size_t)(kt) * 64; \
    unsigned short* dA = &lds[(c)][0][0] + w * 512; \
    unsigned short* dB = &lds[(c)][1][0] + w * 512; \
    gl16(Ag + (size_t)0   * K + ko, dA);            \
    gl16(Ag + (size_t)64  * K + ko, dA + 4096);     \
    gl16(Ag + (size_t)128 * K + ko, dA + 8192);     \
    gl16(Ag + (size_t)192 * K + ko, dA + 12288);    \
    gl16(Bg + (size_t)0   * K + ko, dB);            \
    gl16(Bg + (size_t)64  * K + ko, dB + 4096);     \
    gl16(Bg + (size_t)128 * K + ko, dB + 8192);     \
    gl16(Bg + (size_t)192 * K + ko, dB + 12288);    \
  }

  STAGE(0, 0);
  STAGE(1, 1);
  asm volatile("s_waitcnt vmcnt(8)" ::: "memory");
  __builtin_amdgcn_s_barrier();

  for (int t = 0; t < NT; ++t) {
    int cur = t & 1;
    const unsigned short* La = &lds[cur][0][0];
    const unsigned short* Lb = &lds[cur][1][0];
    short8 a0[8], b0[4], a1[8], b1[4];
    #pragma unroll
    for (int i = 0; i < 8; ++i)
      a0[i] = *(const short8*)&La[(wm*128 + i*16 + al)*64 + ((ag*8) ^ swz)];
    #pragma unroll
    for (int n = 0; n < 4; ++n)
      b0[n] = *(const short8*)&Lb[(wn*64 + n*16 + al)*64 + ((ag*8) ^ swz)];
    #pragma unroll
    for (int i = 0; i < 8; ++i)
      #pragma unroll
      for (int n = 0; n < 4; ++n)
        acc[i][n] = __builtin_amdgcn_mfma_f32_16x16x32_bf16(a0[i], b0[n], acc[i][n], 0, 0, 0);
    #pragma unroll
    for (int i = 0; i < 8; ++i)
      a1[i] = *(const short8*)&La[(wm*128 + i*16 + al)*64 + ((32 + ag*8) ^ swz)];
    #pragma unroll
    for (int n = 0; n < 4; ++n)
      b1[n] = *(const short8*)&Lb[(wn*64 + n*16 + al)*64 + ((32 + ag*8) ^ swz)];
    asm volatile("s_waitcnt lgkmcnt(0)" ::: "memory");
    __builtin_amdgcn_s_barrier();
    if (t + 2 < NT) STAGE(t + 2, cur);
    __builtin_amdgcn_s_setprio(1);
    #pragma unroll
    for (int i = 0; i < 8; ++i)
      #pragma unroll
      for (int n = 0; n < 4; ++n)
        acc[i][n] = __builtin_amdgcn_mfma_f32_16x16x32_bf16(a1[i], b1[n], acc[i][n], 0, 0, 0);
    __builtin_amdgcn_s_setprio(0);
    if (t + 2 < NT) { asm volatile("s_waitcnt vmcnt(8)" ::: "memory"); }
    else            { asm volatile("s_waitcnt vmcnt(0)" ::: "memory"); }
    __builtin_amdgcn_s_barrier();
  }
  #undef STAGE

  #pragma unroll
  for (int i = 0; i < 8; ++i)
    #pragma unroll
    for (int r = 0; r < 4; ++r) {
      float* Cr = C + (size_t)(m0 + wm*128 + i*16 + ag*4 + r) * N + n0 + wn*64 + al;
      #pragma unroll
      for (int n = 0; n < 4; ++n) Cr[n * 16] = acc[i][n][r];
    }
}

// ---------------- 128x128 pipelined 8-wave GEMM, split-K, f32 atomicAdd ----------
__global__ __launch_bounds__(512) void gemm_p8_kernel(
    const unsigned short* __restrict__ A, const unsigned short* __restrict__ Bt,
    float* __restrict__ C, int N, int K, int Kc) {
  __shared__ unsigned short lds[2][2][128 * 64];
  const int NT = Kc >> 6;
  int bid = blockIdx.x, nwg = gridDim.x;
  int wgid = (bid & 7) * (nwg >> 3) + (bid >> 3);
  int m0 = (wgid & 15) * 128;
  int n0 = (wgid >> 4) * 128;
  int tid = threadIdx.x;
  int lane = tid & 63, w = tid >> 6;
  int wm = w >> 2, wn = w & 3;
  int al = lane & 15, ag = lane >> 4;
  int swz = (al & 7) << 3;

  size_t koff = (size_t)blockIdx.y * Kc;
  int rp = 8 * w + (lane >> 3);
  int cK = ((lane & 7) * 8) ^ ((lane >> 3) << 3);
  const unsigned short* Ag = A + (size_t)(m0 + rp) * K + koff + cK;
  const unsigned short* Bg = Bt + (size_t)(n0 + rp) * K + koff + cK;

  f32x4 acc[4][2];
  #pragma unroll
  for (int i = 0; i < 4; ++i)
    #pragma unroll
    for (int n = 0; n < 2; ++n) acc[i][n] = (f32x4){0.f, 0.f, 0.f, 0.f};

  #define STAGE(kt, c) { \
    size_t ko = (size_t)(kt) * 64; \
    unsigned short* dA = &lds[(c)][0][0] + w * 512; \
    unsigned short* dB = &lds[(c)][1][0] + w * 512; \
    gl16(Ag + ko,                 dA);        \
    gl16(Ag + (size_t)64*K + ko,  dA + 4096); \
    gl16(Bg + ko,                 dB);        \
    gl16(Bg + (size_t)64*K + ko,  dB + 4096); \
  }

  STAGE(0, 0);
  STAGE(1, 1);
  asm volatile("s_waitcnt vmcnt(4)" ::: "memory");
  __builtin_amdgcn_s_barrier();

  for (int t = 0; t < NT; ++t) {
    int cur = t & 1;
    const unsigned short* La = &lds[cur][0][0];
    const unsigned short* Lb = &lds[cur][1][0];
    short8 a0[4], b0[2], a1[4], b1[2];
    #pragma unroll
    for (int i = 0; i < 4; ++i)
      a0[i] = *(const short8*)&La[(wm*64 + i*16 + al)*64 + ((ag*8) ^ swz)];
    #pragma unroll
    for (int n = 0; n < 2; ++n)
      b0[n] = *(const short8*)&Lb[(wn*32 + n*16 + al)*64 + ((ag*8) ^ swz)];
    #pragma unroll
    for (int i = 0; i < 4; ++i)
      #pragma unroll
      for (int n = 0; n < 2; ++n)
        acc[i][n] = __builtin_amdgcn_mfma_f32_16x16x32_bf16(a0[i], b0[n], acc[i][n], 0, 0, 0);
    #pragma unroll
    for (int i = 0; i < 4; ++i)
      a1[i] = *(const short8*)&La[(wm*64 + i*16 + al)*64 + ((32 + ag*8) ^ swz)];
    #pragma unroll
    for (int n = 0; n < 2; ++n)
      b1[n] = *(const short8*)&Lb[(wn*32 + n*16 + al)*64 + ((32 + ag*8) ^ swz)];
    asm volatile("s_waitcnt lgkmcnt(0)" ::: "memory");
    __builtin_amdgcn_s_barrier();
    if (t + 2 < NT) STAGE(t + 2, cur);
    __builtin_amdgcn_s_setprio(1);
    #pragma unroll
    for (int i = 0; i < 4; ++i)
      #pragma unroll
      for (int n = 0; n < 2; ++n)
        acc[i][n] = __builtin_amdgcn_mfma_f32_16x16x32_bf16(a1[i], b1[n], acc[i][n], 0, 0, 0);
    __builtin_amdgcn_s_setprio(0);
    if (t + 2 < NT) { asm volatile("s_waitcnt vmcnt(4)" ::: "memory"); }
    else            { asm volatile("s_waitcnt vmcnt(0)" ::: "memory"); }
    __builtin_amdgcn_s_barrier();
  }
  #undef STAGE

  #pragma unroll
  for (int i = 0; i < 4; ++i)
    #pragma unroll
    for (int r = 0; r < 4; ++r) {
      float* Cr = C + (size_t)(m0 + wm*64 + i*16 + ag*4 + r) * N + n0 + wn*32 + al;
      #pragma unroll
      for (int n = 0; n < 2; ++n) atomicAdd(&Cr[n * 16], acc[i][n][r]);
    }
}

// ---------------- gelu ----------------
__device__ __forceinline__ float gelu_t(float x) {
  float x3 = x * x * x;
  return 0.5f * x * (1.0f + tanhf(0.7978845608028654f * (x + 0.044715f * x3)));
}

// ---- pipelined gate/up GEMM: tile 128 rows x [G128|U128], 8 waves, BK=64 ----
__global__ __launch_bounds__(512) void gemm_gu8_kernel(
    const unsigned short* __restrict__ A, const unsigned short* __restrict__ BtG,
    const unsigned short* __restrict__ BtU, unsigned short* __restrict__ Cm) {
  __shared__ unsigned short lds[2][3][128 * 64];   // [dbuf][A,G,U]
  const int K = DM;
  const int NT = K >> 6;                           // 12
  int bid = blockIdx.x, nwg = gridDim.x;           // 256
  int wgid = (bid & 7) * (nwg >> 3) + (bid >> 3);
  int m0 = (wgid & 15) * 128;
  int n0 = (wgid >> 4) * 128;                      // over FF
  int tid = threadIdx.x;
  int lane = tid & 63, w = tid >> 6;
  int wm = w >> 2, wn = w & 3;
  int al = lane & 15, ag = lane >> 4;
  int swz = (al & 7) << 3;

  int rp = 8 * w + (lane >> 3);
  int cK = ((lane & 7) * 8) ^ ((lane >> 3) << 3);
  const unsigned short* Ag = A + (size_t)(m0 + rp) * K + cK;
  const unsigned short* Gg = BtG + (size_t)(n0 + rp) * K + cK;
  const unsigned short* Ug = BtU + (size_t)(n0 + rp) * K + cK;

  f32x4 accg[4][2], accu[4][2];
  #pragma unroll
  for (int i = 0; i < 4; ++i)
    #pragma unroll
    for (int n = 0; n < 2; ++n) {
      accg[i][n] = (f32x4){0.f, 0.f, 0.f, 0.f};
      accu[i][n] = (f32x4){0.f, 0.f, 0.f, 0.f};
    }

  #define STAGE(kt, c) { \
    size_t ko = (size_t)(kt) * 64; \
    unsigned short* dA = &lds[(c)][0][0] + w * 512; \
    unsigned short* dG = &lds[(c)][1][0] + w * 512; \
    unsigned short* dU = &lds[(c)][2][0] + w * 512; \
    gl16(Ag + ko,                 dA);        \
    gl16(Ag + (size_t)64*K + ko,  dA + 4096); \
    gl16(Gg + ko,                 dG);        \
    gl16(Gg + (size_t)64*K + ko,  dG + 4096); \
    gl16(Ug + ko,                 dU);        \
    gl16(Ug + (size_t)64*K + ko,  dU + 4096); \
  }

  STAGE(0, 0);
  STAGE(1, 1);
  asm volatile("s_waitcnt vmcnt(6)" ::: "memory");
  __builtin_amdgcn_s_barrier();

  for (int t = 0; t < NT; ++t) {
    int cur = t & 1;
    const unsigned short* La = &lds[cur][0][0];
    const unsigned short* Lg = &lds[cur][1][0];
    const unsigned short* Lu = &lds[cur][2][0];
    short8 a0[4], g0[2], u0[2], a1[4], g1[2], u1[2];
    #pragma unroll
    for (int i = 0; i < 4; ++i)
      a0[i] = *(const short8*)&La[(wm*64 + i*16 + al)*64 + ((ag*8) ^ swz)];
    #pragma unroll
    for (int n = 0; n < 2; ++n) {
      g0[n] = *(const short8*)&Lg[(wn*32 + n*16 + al)*64 + ((ag*8) ^ swz)];
      u0[n] = *(const short8*)&Lu[(wn*32 + n*16 + al)*64 + ((ag*8) ^ swz)];
    }
    #pragma unroll
    for (int i = 0; i < 4; ++i)
      #pragma unroll
      for (int n = 0; n < 2; ++n) {
        accg[i][n] = __builtin_amdgcn_mfma_f32_16x16x32_bf16(a0[i], g0[n], accg[i][n], 0, 0, 0);
        accu[i][n] = __builtin_amdgcn_mfma_f32_16x16x32_bf16(a0[i], u0[n], accu[i][n], 0, 0, 0);
      }
    #pragma unroll
    for (int i = 0; i < 4; ++i)
      a1[i] = *(const short8*)&La[(wm*64 + i*16 + al)*64 + ((32 + ag*8) ^ swz)];
    #pragma unroll
    for (int n = 0; n < 2; ++n) {
      g1[n] = *(const short8*)&Lg[(wn*32 + n*16 + al)*64 + ((32 + ag*8) ^ swz)];
      u1[n] = *(const short8*)&Lu[(wn*32 + n*16 + al)*64 + ((32 + ag*8) ^ swz)];
    }
    asm volatile("s_waitcnt lgkmcnt(0)" ::: "memory");
    __builtin_amdgcn_s_barrier();
    if (t + 2 < NT) STAGE(t + 2, cur);
    __builtin_amdgcn_s_setprio(1);
    #pragma unroll
    for (int i = 0; i < 4; ++i)
      #pragma unroll
      for (int n = 0; n < 2; ++n) {
        accg[i][n] = __builtin_amdgcn_mfma_f32_16x16x32_bf16(a1[i], g1[n], accg[i][n], 0, 0, 0);
        accu[i][n] = __builtin_amdgcn_mfma_f32_16x16x32_bf16(a1[i], u1[n], accu[i][n], 0, 0, 0);
      }
    __builtin_amdgcn_s_setprio(0);
    if (t + 2 < NT) { asm volatile("s_waitcnt vmcnt(6)" ::: "memory"); }
    else            { asm volatile("s_waitcnt vmcnt(0)" ::: "memory"); }
    __builtin_amdgcn_s_barrier();
  }
  #undef STAGE

  #pragma unroll
  for (int i = 0; i < 4; ++i)
    #pragma unroll
    for (int r = 0; r < 4; ++r) {
      unsigned short* Cr = Cm + (size_t)(m0 + wm*64 + i*16 + ag*4 + r) * FFD + n0 + wn*32 + al;
      #pragma unroll
      for (int n = 0; n < 2; ++n)
        Cr[n * 16] = f2b(gelu_t(accg[i][n][r]) * accu[i][n][r]);
    }
}

// ------- QKV GEMM (128x128, reg-staged): q/k -> RoPE'd bf16; V -> vT transposed ----
__global__ __launch_bounds__(256) void gemm_qkv_kernel(
    const unsigned short* __restrict__ A, const unsigned short* __restrict__ Bt,
    unsigned short* __restrict__ C, unsigned short* __restrict__ vT,
    const float2* __restrict__ rope_tab) {
  const int N = QKVN, K = DM;
  __shared__ unsigned short As[128 * 40];
  __shared__ unsigned short Bs[128 * 40];
  int bid = blockIdx.x, nwg = gridDim.x;
  int wgid = (bid & 7) * (nwg >> 3) + (bid >> 3);
  int m0 = (wgid & 15) * 128;
  int n0 = (wgid >> 4) * 128;
  int tid = threadIdx.x;
  int lane = tid & 63, wave = tid >> 6;
  int wr = (wave >> 1) * 64, wc = (wave & 1) * 64;
  int l16 = lane & 15, lk8 = (lane >> 4) * 8;
  f32x4 acc[4][4];
  #pragma unroll
  for (int m = 0; m < 4; ++m)
    #pragma unroll
    for (int n = 0; n < 4; ++n) acc[m][n] = (f32x4){0.f, 0.f, 0.f, 0.f};
  const unsigned short* Abase = A + (size_t)m0 * K;
  const unsigned short* Bbase = Bt + (size_t)n0 * K;
  int r0 = tid >> 2;            // 0..63
  int c0 = (tid & 3) * 8;       // 0,8,16,24
  for (int k0 = 0; k0 < K; k0 += 32) {
    uint4 a0 = *(const uint4*)(Abase + (size_t)r0 * K + k0 + c0);
    uint4 a1 = *(const uint4*)(Abase + (size_t)(r0 + 64) * K + k0 + c0);
    uint4 b0 = *(const uint4*)(Bbase + (size_t)r0 * K + k0 + c0);
    uint4 b1 = *(const uint4*)(Bbase + (size_t)(r0 + 64) * K + k0 + c0);
    *(uint4*)&As[r0 * 40 + c0] = a0;
    *(uint4*)&As[(r0 + 64) * 40 + c0] = a1;
    *(uint4*)&Bs[r0 * 40 + c0] = b0;
    *(uint4*)&Bs[(r0 + 64) * 40 + c0] = b1;
    __syncthreads();
    short8 af[4], bfr[4];
    #pragma unroll
    for (int m = 0; m < 4; ++m) af[m]  = *(const short8*)&As[(wr + m*16 + l16) * 40 + lk8];
    #pragma unroll
    for (int n = 0; n < 4; ++n) bfr[n] = *(const short8*)&Bs[(wc + n*16 + l16) * 40 + lk8];
    #pragma unroll
    for (int m = 0; m < 4; ++m)
      #pragma unroll
      for (int n = 0; n < 4; ++n)
        acc[m][n] = __builtin_amdgcn_mfma_f32_16x16x32_bf16(af[m], bfr[n], acc[m][n], 0, 0, 0);
    __syncthreads();
  }
  bool qk = (n0 + wc) < 1024;   // whole 64-col group = one q/k head (RoPE) else V head
  #pragma unroll
  for (int m = 0; m < 4; ++m)
    #pragma unroll
    for (int r = 0; r < 4; ++r) {
      int pos = m0 + wr + m*16 + ((lane >> 4) << 2) + r;
      if (qk) {
        unsigned short* Cr = C + (size_t)pos * N + n0 + wc + l16;
        #pragma unroll
        for (int n = 0; n < 2; ++n) {
          int d = n * 16 + l16;                 // 0..31 within head
          float2 cs = rope_tab[pos * 32 + d];
          float x1 = acc[m][n][r], x2 = acc[m][n + 2][r];
          Cr[n * 16]       = f2b(x1 * cs.x - x2 * cs.y);
          Cr[(n + 2) * 16] = f2b(x2 * cs.x + x1 * cs.y);
        }
      } else {
        // V columns: write transposed vT[(kvh*64+d)][pos]
        #pragma unroll
        for (int n = 0; n < 4; ++n) {
          int hb = n0 + wc + n*16 + l16 - 1024;   // 0..255
          vT[(size_t)hb * TSEQ + pos] = f2b(acc[m][n][r]);
        }
      }
    }
}

// ---------------- MFMA flash attention chunk, causal, GQA, KV-split -----------
// Grid (80, NH): slot s -> (qt, chunk ci); chunk covers kv tiles [ci*8, min(ci*8+8, qt+1)).
// qt<=7: single chunk, writes final bf16. Else writes f32 partial (O, m, l).
__global__ __launch_bounds__(256) void attn_chunk_kernel(
    const unsigned short* __restrict__ qkv, const unsigned short* __restrict__ vT,
    unsigned short* __restrict__ out, float* __restrict__ pO, float* __restrict__ pML) {
  __shared__ unsigned short Ks[2][64 * 64];
  __shared__ unsigned short Vt[2][64 * 64];
  __shared__ unsigned short Ps[4][16 * 64];
  int s = blockIdx.x, h = blockIdx.y;
  int qt, ci;
  if (s < 8)       { qt = s;                ci = 0; }
  else if (s < 24) { qt = 8 + ((s-8) >> 1); ci = (s-8) & 1; }
  else if (s < 48) { qt = 16 + (s-24) / 3;  ci = (s-24) % 3; }
  else             { qt = 24 + ((s-48) >> 2); ci = (s-48) & 3; }
  int nt = qt + 1;
  int t0 = ci * 8;
  int t1 = t0 + 8; if (t1 > nt) t1 = nt;
  int cnt = (nt + 7) >> 3;
  int r0 = qt * 64;
  int kvh = h / 3;           // N_REP = 3
  int t = threadIdx.x;
  int lane = t & 63, w = t >> 6;
  int l16 = lane & 15, g = lane >> 4;

  int qr = r0 + w * 16 + l16;
  const unsigned short* qrow = qkv + (size_t)qr * QKVN + h * HD;
  short8 aq0 = *(const short8*)(qrow + 8 * g);
  short8 aq1 = *(const short8*)(qrow + 32 + 8 * g);

  // staging: lane l covers row base+(l>>3), source chunk (l&7)^(l>>3) so the
  // LINEAR LDS image satisfies stored[row][c] = global[row][c ^ (row&7)].
  int sw = (lane & 7) ^ (lane >> 3);
  int rloc = w * 16 + (lane >> 3);
  const unsigned short* kgb = qkv + (size_t)rloc * QKVN + DM + kvh * HD + 8 * sw;
  const unsigned short* vgb = vT + (size_t)(kvh * 64 + rloc) * TSEQ + 8 * sw;

  #define ASTAGE(kb, c) { \
    unsigned short* kd = &Ks[(c)][0] + w * 1024; \
    unsigned short* vd = &Vt[(c)][0] + w * 1024; \
    gl16(kgb + (size_t)(kb) * QKVN,       kd);       \
    gl16(kgb + (size_t)((kb) + 8) * QKVN, kd + 512); \
    gl16(vgb + (kb),                      vd);       \
    gl16(vgb + (size_t)8 * TSEQ + (kb),   vd + 512); \
  }

  f32x4 o_acc[4];
  float mrun[4], lsum[4];
  #pragma unroll
  for (int i = 0; i < 4; ++i) { o_acc[i] = (f32x4){0.f,0.f,0.f,0.f}; mrun[i] = -1e30f; lsum[i] = 0.f; }

  ASTAGE(t0 * 64, 0);
  for (int kt = t0; kt < t1; ++kt) {
    int cur = (kt - t0) & 1;
    int kb = kt * 64;
    if (kt + 1 < t1) {
      ASTAGE((kt + 1) * 64, cur ^ 1);                     // prefetch next tile
      asm volatile("s_waitcnt vmcnt(4)" ::: "memory");    // current tile's 4 done
    } else {
      asm volatile("s_waitcnt vmcnt(0)" ::: "memory");
    }
    __builtin_amdgcn_s_barrier();

    const unsigned short* Kc = &Ks[cur][0];
    const unsigned short* Vc = &Vt[cur][0];

    f32x4 s_acc[4];
    #pragma unroll
    for (int nb = 0; nb < 4; ++nb) s_acc[nb] = (f32x4){0.f,0.f,0.f,0.f};
    #pragma unroll
    for (int nb = 0; nb < 4; ++nb) {
      int key = nb * 16 + l16;
      short8 bk0 = *(const short8*)&Kc[key * 64 + ((g       ^ (key & 7)) << 3)];
      short8 bk1 = *(const short8*)&Kc[key * 64 + (((4 + g) ^ (key & 7)) << 3)];
      s_acc[nb] = __builtin_amdgcn_mfma_f32_16x16x32_bf16(aq0, bk0, s_acc[nb], 0, 0, 0);
      s_acc[nb] = __builtin_amdgcn_mfma_f32_16x16x32_bf16(aq1, bk1, s_acc[nb], 0, 0, 0);
    }

    bool diag = (kt == qt);
    #pragma unroll
    for (int r = 0; r < 4; ++r) {
      int qg = r0 + w * 16 + g * 4 + r;
      float sv[4];
      #pragma unroll
      for (int nb = 0; nb < 4; ++nb) {
        sv[nb] = s_acc[nb][r] * 0.125f;
        if (diag && (kb + nb * 16 + l16 > qg)) sv[nb] = -1e30f;
      }
      float mx = fmaxf(fmaxf(sv[0], sv[1]), fmaxf(sv[2], sv[3]));
      mx = fmaxf(mx, __shfl_xor(mx, 1));
      mx = fmaxf(mx, __shfl_xor(mx, 2));
      mx = fmaxf(mx, __shfl_xor(mx, 4));
      mx = fmaxf(mx, __shfl_xor(mx, 8));
      // defer-max (T13, THR=8)
      if (mx > mrun[r] + 8.0f) {
        float es = __expf(mrun[r] - mx);
        lsum[r] *= es;
        #pragma unroll
        for (int db = 0; db < 4; ++db) o_acc[db][r] *= es;
        mrun[r] = mx;
      }
      float rsum = 0.f;
      #pragma unroll
      for (int nb = 0; nb < 4; ++nb) { sv[nb] = __expf(sv[nb] - mrun[r]); rsum += sv[nb]; }
      lsum[r] += rsum;
      int qloc = g * 4 + r, q7 = qloc & 7;
      #pragma unroll
      for (int nb = 0; nb < 4; ++nb) {
        int key = nb * 16 + l16;
        Ps[w][qloc * 64 + ((((key >> 3) ^ q7) << 3) + (key & 7))] = f2b(sv[nb]);
      }
    }

    #pragma unroll
    for (int kc = 0; kc < 2; ++kc) {
      short8 pa = *(const short8*)&Ps[w][l16 * 64 + (((4 * kc + g) ^ (l16 & 7)) << 3)];
      #pragma unroll
      for (int db = 0; db < 4; ++db) {
        int d = db * 16 + l16;
        short8 bv = *(const short8*)&Vc[d * 64 + (((4 * kc + g) ^ (d & 7)) << 3)];
        o_acc[db] = __builtin_amdgcn_mfma_f32_16x16x32_bf16(pa, bv, o_acc[db], 0, 0, 0);
      }
    }
    __builtin_amdgcn_s_barrier();
  }
  #undef ASTAGE

  if (cnt == 1) {
    #pragma unroll
    for (int r = 0; r < 4; ++r) {
      int qg = r0 + w * 16 + g * 4 + r;
      float sr = lsum[r];
      sr += __shfl_xor(sr, 1);
      sr += __shfl_xor(sr, 2);
      sr += __shfl_xor(sr, 4);
      sr += __shfl_xor(sr, 8);
      float inv = 1.0f / sr;
      unsigned short* orow = out + (size_t)qg * DM + h * HD + l16;
      #pragma unroll
      for (int db = 0; db < 4; ++db) orow[db * 16] = f2b(o_acc[db][r] * inv);
    }
  } else {
    size_t slotg = (size_t)h * 80 + s;
    float* po = pO + slotg * 4096;
    float* pm = pML + slotg * 128;
    #pragma unroll
    for (int r = 0; r < 4; ++r) {
      int row = w * 16 + g * 4 + r;
      float sr = lsum[r];
      sr += __shfl_xor(sr, 1);
      sr += __shfl_xor(sr, 2);
      sr += __shfl_xor(sr, 4);
      sr += __shfl_xor(sr, 8);
      #pragma unroll
      for (int db = 0; db < 4; ++db) po[row * 64 + db * 16 + l16] = o_acc[db][r];
      if (l16 == 0) { pm[row * 2] = mrun[r]; pm[row * 2 + 1] = sr; }
    }
  }
}

// ---------------- combine partials for qt >= 8 ----------------
__global__ __launch_bounds__(256) void attn_combine_kernel(
    const float* __restrict__ pO, const float* __restrict__ pML,
    unsigned short* __restrict__ out) {
  int h = blockIdx.y;
  int qt = 8 + blockIdx.x;            // 8..31
  int base, cnt;
  if (qt < 16)      { base = 8 + (qt - 8) * 2;  cnt = 2; }
  else if (qt < 24) { base = 24 + (qt - 16) * 3; cnt = 3; }
  else              { base = 48 + (qt - 24) * 4; cnt = 4; }
  int t = threadIdx.x;
  int row = t >> 2, d0 = (t & 3) * 16;
  float m[4], l[4];
  float M = -1e30f;
  for (int c = 0; c < cnt; ++c) {
    const float* pm = pML + ((size_t)h * 80 + base + c) * 128 + row * 2;
    m[c] = pm[0]; l[c] = pm[1];
    M = fmaxf(M, m[c]);
  }
  float o[16];
  #pragma unroll
  for (int j = 0; j < 16; ++j) o[j] = 0.f;
  float wl = 0.f;
  for (int c = 0; c < cnt; ++c) {
    float wc = __expf(m[c] - M);
    wl += wc * l[c];
    const float4* po = (const float4*)(pO + ((size_t)h * 80 + base + c) * 4096 + row * 64 + d0);
    #pragma unroll
    for (int q = 0; q < 4; ++q) {
      float4 v = po[q];
      o[q*4+0] += wc * v.x; o[q*4+1] += wc * v.y;
      o[q*4+2] += wc * v.z; o[q*4+3] += wc * v.w;
    }
  }
  float inv = 1.0f / wl;
  unsigned short* orow = out + (size_t)(qt * 64 + row) * DM + h * HD + d0;
  uint4 s0, s1;
  s0.x = packbf(o[0]*inv,  o[1]*inv);  s0.y = packbf(o[2]*inv,  o[3]*inv);
  s0.z = packbf(o[4]*inv,  o[5]*inv);  s0.w = packbf(o[6]*inv,  o[7]*inv);
  s1.x = packbf(o[8]*inv,  o[9]*inv);  s1.y = packbf(o[10]*inv, o[11]*inv);
  s1.z = packbf(o[12]*inv, o[13]*inv); s1.w = packbf(o[14]*inv, o[15]*inv);
  ((uint4*)orow)[0] = s0; ((uint4*)orow)[1] = s1;
}

extern "C" void kernel_launch(void* const* d_in, const int* in_sizes, int n_in,
                              void* d_out, int out_size, void* d_ws, size_t ws_size,
                              hipStream_t stream) {
  const int*   idx   = (const int*)d_in[0];
  const float* embed = (const float*)d_in[1];
  const float* ln1   = (const float*)d_in[2];
  const float* Wq    = (const float*)d_in[3];
  const float* Wk    = (const float*)d_in[4];
  const float* Wv    = (const float*)d_in[5];
  const float* Wo    = (const float*)d_in[6];
  const float* ln2   = (const float*)d_in[7];
  const float* Wg    = (const float*)d_in[8];
  const float* Wu    = (const float*)d_in[9];
  const float* Wd    = (const float*)d_in[10];
  const float* normf = (const float*)d_in[11];
  float* out = (float*)d_out;
  char* ws = (char*)d_ws;
  (void)in_sizes; (void)n_in; (void)out_size; (void)ws_size;

  // ---- workspace layout ----
  unsigned short* embed_bf = (unsigned short*)ws;
  size_t off = (size_t)VOC * DM * 2;
  unsigned short* wts = (unsigned short*)(ws + off);
  const size_t LW = (size_t)QKVN * DM + (size_t)DM * DM
                  + 2ull * FFD * DM + (size_t)DM * FFD;
  off += LW * 2ull * NL;
  float* xf = (float*)(ws + off);            off += (size_t)TSEQ * DM * 4;
  unsigned short* h_bf = (unsigned short*)(ws + off);    off += (size_t)TSEQ * DM * 2;
  unsigned short* qkv_bf = (unsigned short*)(ws + off);  off += (size_t)TSEQ * QKVN * 2;
  unsigned short* attn_bf = (unsigned short*)(ws + off); off += (size_t)TSEQ * DM * 2;
  // pO (attn partials) overlays m_bf: disjoint lifetimes (attn->combine vs gu8->wd)
  float* pO = (float*)(ws + off);
  unsigned short* m_bf = (unsigned short*)(ws + off);
  off += (size_t)NH * 80 * 4096 * 4;                     // 15.7 MB (>= m_bf's 8.4 MB)
  float* pML = (float*)(ws + off);           off += (size_t)NH * 80 * 128 * 4;
  float2* rope_tab = (float2*)(ws + off);    off += (size_t)TSEQ * 32 * 8;
  unsigned short* vT = (unsigned short*)(ws + off);      off += (size_t)NKV * HD * TSEQ * 2;

  // ---- prep: embed cast + rope table + batched weight transpose/cast ----
  cast_bf16_kernel<<<(VOC * DM / 4 + 255) / 256, 256, 0, stream>>>(embed, embed_bf, VOC * DM / 4);
  rope_tab_kernel<<<TSEQ * 32 / 256, 256, 0, stream>>>(rope_tab);

  {
    unsigned short* qkvT = wts;
    unsigned short* woT  = wts + (size_t)QKVN * DM;
    unsigned short* wguT = woT + (size_t)DM * DM;
    unsigned short* wdT  = wguT + 2ull * FFD * DM;
    transpose_cast_kernel<<<dim3(24, 24, NL), dim3(32, 8), 0, stream>>>(Wq, qkvT, 768, 768, 589824, LW);
    transpose_cast_kernel<<<dim3(8, 24, NL),  dim3(32, 8), 0, stream>>>(Wk, qkvT + 768ull * 768, 768, 256, 196608, LW);
    transpose_cast_kernel<<<dim3(8, 24, NL),  dim3(32, 8), 0, stream>>>(Wv, qkvT + 1024ull * 768, 768, 256, 196608, LW);
    transpose_cast_kernel<<<dim3(24, 24, NL), dim3(32, 8), 0, stream>>>(Wo, woT, 768, 768, 589824, LW);
    transpose_cast_kernel<<<dim3(64, 24, NL), dim3(32, 8), 0, stream>>>(Wg, wguT, 768, 2048, 1572864, LW);
    transpose_cast_kernel<<<dim3(64, 24, NL), dim3(32, 8), 0, stream>>>(Wu, wguT + (size_t)FFD * DM, 768, 2048, 1572864, LW);
    transpose_cast_kernel<<<dim3(24, 64, NL), dim3(32, 8), 0, stream>>>(Wd, wdT, 2048, 768, 1572864, LW);
  }

  gather_kernel<<<TSEQ, 192, 0, stream>>>(idx, embed, xf);

  for (int l = 0; l < NL; ++l) {
    unsigned short* base = wts + (size_t)l * LW;
    unsigned short* qkvT = base;
    unsigned short* woT  = base + (size_t)QKVN * DM;
    unsigned short* wguT = woT + (size_t)DM * DM;
    unsigned short* wdT  = wguT + 2ull * FFD * DM;

    rmsnorm_kernel<<<TSEQ, 256, 0, stream>>>(xf, ln1 + (size_t)l * DM, h_bf);
    gemm_qkv_kernel<<<(QKVN / 128) * 16, 256, 0, stream>>>(h_bf, qkvT, qkv_bf, vT, rope_tab);
    attn_chunk_kernel<<<dim3(80, NH), 256, 0, stream>>>(qkv_bf, vT, attn_bf, pO, pML);
    attn_combine_kernel<<<dim3(24, NH), 256, 0, stream>>>(pO, pML, attn_bf);
    gemm_p8_kernel<<<dim3((DM / 128) * 16, 3), 512, 0, stream>>>(attn_bf, woT, xf, DM, DM, 256);
    rmsnorm_kernel<<<TSEQ, 256, 0, stream>>>(xf, ln2 + (size_t)l * DM, h_bf);
    gemm_gu8_kernel<<<(FFD / 128) * 16, 512, 0, stream>>>(h_bf, wguT, wguT + (size_t)FFD * DM, m_bf);
    gemm_p8_kernel<<<dim3((DM / 128) * 16, 4), 512, 0, stream>>>(m_bf, wdT, xf, DM, FFD, 512);
  }

  rmsnorm_kernel<<<TSEQ, 256, 0, stream>>>(xf, normf, h_bf);
  gemm_l8_kernel<<<(VOC / 256) * (TSEQ / 256), 512, 0, stream>>>(h_bf, embed_bf, out, VOC, DM);
}

// Round 11
// 760.566 us; speedup vs baseline: 1.6385x; 1.0121x over previous
//
#include <hip/hip_runtime.h>

#define TSEQ 2048
#define DM   768
#define NH   12
#define NKV  4
#define HD   64
#define FFD  2048
#define NL   4
#define VOC  32000
#define QKVN 1280   // 768 q + 256 k + 256 v

typedef __attribute__((ext_vector_type(8))) short short8;
typedef __attribute__((ext_vector_type(4))) float f32x4;

__device__ __forceinline__ unsigned short f2b(float f) {
  unsigned int u = __float_as_uint(f);
  u += 0x7fffu + ((u >> 16) & 1u);
  return (unsigned short)(u >> 16);
}
__device__ __forceinline__ float b2f(unsigned short u) {
  return __uint_as_float(((unsigned int)u) << 16);
}
__device__ __forceinline__ unsigned int packbf(float a, float b) {
  return (unsigned int)f2b(a) | ((unsigned int)f2b(b) << 16);
}

// direct global->LDS async copy, 16B/lane; LDS dest wave-uniform (HW adds lane*16)
__device__ __forceinline__ void gl16(const unsigned short* g, unsigned short* l) {
  __builtin_amdgcn_global_load_lds(
      (const __attribute__((address_space(1))) void*)g,
      (__attribute__((address_space(3))) void*)l, 16, 0, 0);
}

// ---------------- cast f32 -> bf16 (vectorized x4) ----------------
__global__ void cast_bf16_kernel(const float* __restrict__ src,
                                 unsigned short* __restrict__ dst, int n4) {
  int i = blockIdx.x * blockDim.x + threadIdx.x;
  if (i >= n4) return;
  float4 v = ((const float4*)src)[i];
  uint2 o; o.x = packbf(v.x, v.y); o.y = packbf(v.z, v.w);
  ((uint2*)dst)[i] = o;
}

// ---------------- RoPE cos/sin table: [pos][d] for d in 0..31 ----------------
__global__ void rope_tab_kernel(float2* __restrict__ tab) {
  int i = blockIdx.x * blockDim.x + threadIdx.x;   // over TSEQ*32
  int pos = i >> 5, d = i & 31;
  float inv = exp2f(-(float)d * (13.287712379549449f / 32.0f));
  float sv, cv; sincosf((float)pos * inv, &sv, &cv);
  tab[i] = make_float2(cv, sv);
}

// ------- mega transpose+cast: ALL weight matrices, all layers, one launch -------
// blockIdx.x in [0,6144) decodes matrix + tile; blockIdx.z = layer.
__global__ void transpose_all_kernel(const float* __restrict__ Wq, const float* __restrict__ Wk,
                                     const float* __restrict__ Wv, const float* __restrict__ Wo,
                                     const float* __restrict__ Wg, const float* __restrict__ Wu,
                                     const float* __restrict__ Wd, unsigned short* __restrict__ wts,
                                     size_t LW) {
  __shared__ float tile[32][33];
  int r = blockIdx.x, l = blockIdx.z;
  const float* src; size_t sstr, doff; int K, N, nx;
  if (r < 576)       { src = Wq; sstr = 589824;  doff = 0;                          K = 768;  N = 768;  nx = 24; }
  else if (r < 768)  { src = Wk; sstr = 196608;  doff = 768ull * 768;               K = 768;  N = 256;  nx = 8;  r -= 576; }
  else if (r < 960)  { src = Wv; sstr = 196608;  doff = 1024ull * 768;              K = 768;  N = 256;  nx = 8;  r -= 768; }
  else if (r < 1536) { src = Wo; sstr = 589824;  doff = (size_t)QKVN * DM;          K = 768;  N = 768;  nx = 24; r -= 960; }
  else if (r < 3072) { src = Wg; sstr = 1572864; doff = (size_t)QKVN * DM + (size_t)DM * DM;
                       K = 768;  N = 2048; nx = 64; r -= 1536; }
  else if (r < 4608) { src = Wu; sstr = 1572864; doff = (size_t)QKVN * DM + (size_t)DM * DM + (size_t)FFD * DM;
                       K = 768;  N = 2048; nx = 64; r -= 3072; }
  else               { src = Wd; sstr = 1572864; doff = (size_t)QKVN * DM + (size_t)DM * DM + 2ull * FFD * DM;
                       K = 2048; N = 768;  nx = 24; r -= 4608; }
  int bx = r % nx, by = r / nx;
  src += (size_t)l * sstr;
  unsigned short* dst = wts + (size_t)l * LW + doff;
  int n0 = bx * 32, k0 = by * 32;
  int tx = threadIdx.x, ty = threadIdx.y;  // 32 x 8
  #pragma unroll
  for (int i = 0; i < 4; ++i) {
    int rr = ty + i * 8;
    tile[rr][tx] = src[(size_t)(k0 + rr) * N + n0 + tx];
  }
  __syncthreads();
  #pragma unroll
  for (int i = 0; i < 4; ++i) {
    int rr = ty + i * 8;
    dst[(size_t)(n0 + rr) * K + k0 + tx] = f2b(tile[tx][rr]);
  }
}

// ---------------- embedding gather ----------------
__global__ void gather_kernel(const int* __restrict__ idx,
                              const float* __restrict__ embed,
                              float* __restrict__ x) {
  int row = blockIdx.x; int t = threadIdx.x;  // 192 threads, float4 each
  int id = idx[row];
  ((float4*)(x + (size_t)row * DM))[t] = ((const float4*)(embed + (size_t)id * DM))[t];
}

// ---------------- RMSNorm: f32 in -> bf16 out ----------------
__global__ void rmsnorm_kernel(const float* __restrict__ x,
                               const float* __restrict__ w,
                               unsigned short* __restrict__ out) {
  int row = blockIdx.x; int t = threadIdx.x;  // 256 threads, D=768
  const float* xr = x + (size_t)row * DM;
  float v0 = xr[t], v1 = xr[t + 256], v2 = xr[t + 512];
  float s = v0*v0 + v1*v1 + v2*v2;
  #pragma unroll
  for (int off = 1; off < 64; off <<= 1) s += __shfl_xor(s, off);
  __shared__ float red[4];
  if ((t & 63) == 0) red[t >> 6] = s;
  __syncthreads();
  float tot = red[0] + red[1] + red[2] + red[3];
  float rs = rsqrtf(tot * (1.0f / DM) + 1e-6f);
  unsigned short* orow = out + (size_t)row * DM;
  orow[t]       = f2b(w[t]       * v0 * rs);
  orow[t + 256] = f2b(w[t + 256] * v1 * rs);
  orow[t + 512] = f2b(w[t + 512] * v2 * rs);
}

// ---------------- 256x256 deep-pipelined GEMM (logits): C = A @ Bt^T, f32 out ----
// Counted-lgkmcnt read/MFMA interleave: 4 read-groups (8/4/8/4), each MFMA
// cluster waits only for the group it needs; later groups' latency hides
// under the MFMA. Buffer-reuse skeleton (lgkm0+bar+STAGE+vmcnt) unchanged.
__global__ __launch_bounds__(512, 1) void gemm_l8_kernel(
    const unsigned short* __restrict__ A, const unsigned short* __restrict__ Bt,
    float* __restrict__ C, int N, int K) {
  __shared__ unsigned short lds[2][2][256 * 64];   // [dbuf][A,B][row*64+col]
  const int NT = K >> 6;
  int bid = blockIdx.x, nwg = gridDim.x;
  int wgid = (bid & 7) * (nwg >> 3) + (bid >> 3);
  int m0 = (wgid & 7) * 256;        // 8 m-tiles (TSEQ/256)
  int n0 = (wgid >> 3) * 256;
  int tid = threadIdx.x;
  int lane = tid & 63, w = tid >> 6;
  int wm = w >> 2, wn = w & 3;
  int al = lane & 15, ag = lane >> 4;
  int swz = (al & 7) << 3;          // frag-read swizzle (shorts)

  int rA = tid >> 3;                                  // 0..63
  int cK = ((tid & 7) * 8) ^ ((rA & 7) << 3);         // bf16 col within 64
  const unsigned short* Ag = A + (size_t)(m0 + rA) * K + cK;
  const unsigned short* Bg = Bt + (size_t)(n0 + rA) * K + cK;

  f32x4 acc[8][4];
  #pragma unroll
  for (int i = 0; i < 8; ++i)
    #pragma unroll
    for (int n = 0; n < 4; ++n) acc[i][n] = (f32x4){0.f, 0.f, 0.f, 0.f};

  #define STAGE(kt, c) { \
    size_t ko = (size_t)(kt) * 64; \
    unsigned short* dA = &lds[(c)][0][0] + w * 512; \
    unsigned short* dB = &lds[(c)][1][0] + w * 512; \
    gl16(Ag + (size_t)0   * K + ko, dA);            \
    gl16(Ag + (size_t)64  * K + ko, dA + 4096);     \
    gl16(Ag + (size_t)128 * K + ko, dA + 8192);     \
    gl16(Ag + (size_t)192 * K + ko, dA + 12288);    \
    gl16(Bg + (size_t)0   * K + ko, dB);            \
    gl16(Bg + (size_t)64  * K + ko, dB + 4096);     \
    gl16(Bg + (size_t)128 * K + ko, dB + 8192);     \
    gl16(Bg + (size_t)192 * K + ko, dB + 12288);    \
  }

  STAGE(0, 0);
  STAGE(1, 1);
  asm volatile("s_waitcnt vmcnt(8)" ::: "memory");
  __builtin_amdgcn_s_barrier();

  for (int t = 0; t < NT; ++t) {
    int cur = t & 1;
    const unsigned short* La = &lds[cur][0][0];
    const unsigned short* Lb = &lds[cur][1][0];
    short8 a0[8], b0[4], a1[8], b1[4];
    // group 1 (8): a0[0..3] + b0
    #pragma unroll
    for (int i = 0; i < 4; ++i)
      a0[i] = *(const short8*)&La[(wm*128 + i*16 + al)*64 + ((ag*8) ^ swz)];
    #pragma unroll
    for (int n = 0; n < 4; ++n)
      b0[n] = *(const short8*)&Lb[(wn*64 + n*16 + al)*64 + ((ag*8) ^ swz)];
    // group 2 (4): a0[4..7]
    #pragma unroll
    for (int i = 4; i < 8; ++i)
      a0[i] = *(const short8*)&La[(wm*128 + i*16 + al)*64 + ((ag*8) ^ swz)];
    asm volatile("s_waitcnt lgkmcnt(4)" ::: "memory");   // group 1 complete
    __builtin_amdgcn_sched_barrier(0);
    #pragma unroll
    for (int i = 0; i < 4; ++i)
      #pragma unroll
      for (int n = 0; n < 4; ++n)
        acc[i][n] = __builtin_amdgcn_mfma_f32_16x16x32_bf16(a0[i], b0[n], acc[i][n], 0, 0, 0);
    // group 3 (8): b1 + a1[0..3]
    #pragma unroll
    for (int n = 0; n < 4; ++n)
      b1[n] = *(const short8*)&Lb[(wn*64 + n*16 + al)*64 + ((32 + ag*8) ^ swz)];
    #pragma unroll
    for (int i = 0; i < 4; ++i)
      a1[i] = *(const short8*)&La[(wm*128 + i*16 + al)*64 + ((32 + ag*8) ^ swz)];
    asm volatile("s_waitcnt lgkmcnt(8)" ::: "memory");   // group 2 complete
    __builtin_amdgcn_sched_barrier(0);
    #pragma unroll
    for (int i = 4; i < 8; ++i)
      #pragma unroll
      for (int n = 0; n < 4; ++n)
        acc[i][n] = __builtin_amdgcn_mfma_f32_16x16x32_bf16(a0[i], b0[n], acc[i][n], 0, 0, 0);
    // group 4 (4): a1[4..7]
    #pragma unroll
    for (int i = 4; i < 8; ++i)
      a1[i] = *(const short8*)&La[(wm*128 + i*16 + al)*64 + ((32 + ag*8) ^ swz)];
    asm volatile("s_waitcnt lgkmcnt(4)" ::: "memory");   // group 3 complete
    __builtin_amdgcn_sched_barrier(0);
    #pragma unroll
    for (int i = 0; i < 4; ++i)
      #pragma unroll
      for (int n = 0; n < 4; ++n)
        acc[i][n] = __builtin_amdgcn_mfma_f32_16x16x32_bf16(a1[i], b1[n], acc[i][n], 0, 0, 0);
    asm volatile("s_waitcnt lgkmcnt(0)" ::: "memory");   // all reads of buf[cur] done
    __builtin_amdgcn_sched_barrier(0);
    __builtin_amdgcn_s_barrier();                        // before overwriting it
    if (t + 2 < NT) STAGE(t + 2, cur);
    __builtin_amdgcn_s_setprio(1);
    #pragma unroll
    for (int i = 4; i < 8; ++i)
      #pragma unroll
      for (int n = 0; n < 4; ++n)
        acc[i][n] = __builtin_amdgcn_mfma_f32_16x16x32_bf16(a1[i], b1[n], acc[i][n], 0, 0, 0);
    __builtin_amdgcn_s_setprio(0);
    if (t + 2 < NT) { asm volatile("s_waitcnt vmcnt(8)" ::: "memory"); }
    else            { asm volatile("s_waitcnt vmcnt(0)" ::: "memory"); }
    __builtin_amdgcn_s_barrier();
  }
  #undef STAGE

  #pragma unroll
  for (int i = 0; i < 8; ++i)
    #pragma unroll
    for (int r = 0; r < 4; ++r) {
      float* Cr = C + (size_t)(m0 + wm*128 + i*16 + ag*4 + r) * N + n0 + wn*64 + al;
      #pragma unroll
      for (int n = 0; n < 4; ++n) Cr[n * 16] = acc[i][n][r];
    }
}

// ---------------- 128x128 pipelined 8-wave GEMM, split-K, f32 atomicAdd ----------
__global__ __launch_bounds__(512) void gemm_p8_kernel(
    const unsigned short* __restrict__ A, const unsigned short* __restrict__ Bt,
    float* __restrict__ C, int N, int K, int Kc) {
  __shared__ unsigned short lds[2][2][128 * 64];
  const int NT = Kc >> 6;
  int bid = blockIdx.x, nwg = gridDim.x;
  int wgid = (bid & 7) * (nwg >> 3) + (bid >> 3);
  int m0 = (wgid & 15) * 128;
  int n0 = (wgid >> 4) * 128;
  int tid = threadIdx.x;
  int lane = tid & 63, w = tid >> 6;
  int wm = w >> 2, wn = w & 3;
  int al = lane & 15, ag = lane >> 4;
  int swz = (al & 7) << 3;

  size_t koff = (size_t)blockIdx.y * Kc;
  int rp = 8 * w + (lane >> 3);
  int cK = ((lane & 7) * 8) ^ ((lane >> 3) << 3);
  const unsigned short* Ag = A + (size_t)(m0 + rp) * K + koff + cK;
  const unsigned short* Bg = Bt + (size_t)(n0 + rp) * K + koff + cK;

  f32x4 acc[4][2];
  #pragma unroll
  for (int i = 0; i < 4; ++i)
    #pragma unroll
    for (int n = 0; n < 2; ++n) acc[i][n] = (f32x4){0.f, 0.f, 0.f, 0.f};

  #define STAGE(kt, c) { \
    size_t ko = (size_t)(kt) * 64; \
    unsigned short* dA = &lds[(c)][0][0] + w * 512; \
    unsigned short* dB = &lds[(c)][1][0] + w * 512; \
    gl16(Ag + ko,                 dA);        \
    gl16(Ag + (size_t)64*K + ko,  dA + 4096); \
    gl16(Bg + ko,                 dB);        \
    gl16(Bg + (size_t)64*K + ko,  dB + 4096); \
  }

  STAGE(0, 0);
  STAGE(1, 1);
  asm volatile("s_waitcnt vmcnt(4)" ::: "memory");
  __builtin_amdgcn_s_barrier();

  for (int t = 0; t < NT; ++t) {
    int cur = t & 1;
    const unsigned short* La = &lds[cur][0][0];
    const unsigned short* Lb = &lds[cur][1][0];
    short8 a0[4], b0[2], a1[4], b1[2];
    #pragma unroll
    for (int i = 0; i < 4; ++i)
      a0[i] = *(const short8*)&La[(wm*64 + i*16 + al)*64 + ((ag*8) ^ swz)];
    #pragma unroll
    for (int n = 0; n < 2; ++n)
      b0[n] = *(const short8*)&Lb[(wn*32 + n*16 + al)*64 + ((ag*8) ^ swz)];
    #pragma unroll
    for (int i = 0; i < 4; ++i)
      a1[i] = *(const short8*)&La[(wm*64 + i*16 + al)*64 + ((32 + ag*8) ^ swz)];
    #pragma unroll
    for (int n = 0; n < 2; ++n)
      b1[n] = *(const short8*)&Lb[(wn*32 + n*16 + al)*64 + ((32 + ag*8) ^ swz)];
    asm volatile("s_waitcnt lgkmcnt(6)" ::: "memory");   // k0 frags complete
    __builtin_amdgcn_sched_barrier(0);
    #pragma unroll
    for (int i = 0; i < 4; ++i)
      #pragma unroll
      for (int n = 0; n < 2; ++n)
        acc[i][n] = __builtin_amdgcn_mfma_f32_16x16x32_bf16(a0[i], b0[n], acc[i][n], 0, 0, 0);
    asm volatile("s_waitcnt lgkmcnt(0)" ::: "memory");
    __builtin_amdgcn_sched_barrier(0);
    __builtin_amdgcn_s_barrier();
    if (t + 2 < NT) STAGE(t + 2, cur);
    __builtin_amdgcn_s_setprio(1);
    #pragma unroll
    for (int i = 0; i < 4; ++i)
      #pragma unroll
      for (int n = 0; n < 2; ++n)
        acc[i][n] = __builtin_amdgcn_mfma_f32_16x16x32_bf16(a1[i], b1[n], acc[i][n], 0, 0, 0);
    __builtin_amdgcn_s_setprio(0);
    if (t + 2 < NT) { asm volatile("s_waitcnt vmcnt(4)" ::: "memory"); }
    else            { asm volatile("s_waitcnt vmcnt(0)" ::: "memory"); }
    __builtin_amdgcn_s_barrier();
  }
  #undef STAGE

  #pragma unroll
  for (int i = 0; i < 4; ++i)
    #pragma unroll
    for (int r = 0; r < 4; ++r) {
      float* Cr = C + (size_t)(m0 + wm*64 + i*16 + ag*4 + r) * N + n0 + wn*32 + al;
      #pragma unroll
      for (int n = 0; n < 2; ++n) atomicAdd(&Cr[n * 16], acc[i][n][r]);
    }
}

// ---------------- gelu ----------------
__device__ __forceinline__ float gelu_t(float x) {
  float x3 = x * x * x;
  return 0.5f * x * (1.0f + tanhf(0.7978845608028654f * (x + 0.044715f * x3)));
}

// ---- pipelined gate/up GEMM: tile 128 rows x [G128|U128], 8 waves, BK=64 ----
__global__ __launch_bounds__(512) void gemm_gu8_kernel(
    const unsigned short* __restrict__ A, const unsigned short* __restrict__ BtG,
    const unsigned short* __restrict__ BtU, unsigned short* __restrict__ Cm) {
  __shared__ unsigned short lds[2][3][128 * 64];   // [dbuf][A,G,U]
  const int K = DM;
  const int NT = K >> 6;                           // 12
  int bid = blockIdx.x, nwg = gridDim.x;           // 256
  int wgid = (bid & 7) * (nwg >> 3) + (bid >> 3);
  int m0 = (wgid & 15) * 128;
  int n0 = (wgid >> 4) * 128;                      // over FF
  int tid = threadIdx.x;
  int lane = tid & 63, w = tid >> 6;
  int wm = w >> 2, wn = w & 3;
  int al = lane & 15, ag = lane >> 4;
  int swz = (al & 7) << 3;

  int rp = 8 * w + (lane >> 3);
  int cK = ((lane & 7) * 8) ^ ((lane >> 3) << 3);
  const unsigned short* Ag = A + (size_t)(m0 + rp) * K + cK;
  const unsigned short* Gg = BtG + (size_t)(n0 + rp) * K + cK;
  const unsigned short* Ug = BtU + (size_t)(n0 + rp) * K + cK;

  f32x4 accg[4][2], accu[4][2];
  #pragma unroll
  for (int i = 0; i < 4; ++i)
    #pragma unroll
    for (int n = 0; n < 2; ++n) {
      accg[i][n] = (f32x4){0.f, 0.f, 0.f, 0.f};
      accu[i][n] = (f32x4){0.f, 0.f, 0.f, 0.f};
    }

  #define STAGE(kt, c) { \
    size_t ko = (size_t)(kt) * 64; \
    unsigned short* dA = &lds[(c)][0][0] + w * 512; \
    unsigned short* dG = &lds[(c)][1][0] + w * 512; \
    unsigned short* dU = &lds[(c)][2][0] + w * 512; \
    gl16(Ag + ko,                 dA);        \
    gl16(Ag + (size_t)64*K + ko,  dA + 4096); \
    gl16(Gg + ko,                 dG);        \
    gl16(Gg + (size_t)64*K + ko,  dG + 4096); \
    gl16(Ug + ko,                 dU);        \
    gl16(Ug + (size_t)64*K + ko,  dU + 4096); \
  }

  STAGE(0, 0);
  STAGE(1, 1);
  asm volatile("s_waitcnt vmcnt(6)" ::: "memory");
  __builtin_amdgcn_s_barrier();

  for (int t = 0; t < NT; ++t) {
    int cur = t & 1;
    const unsigned short* La = &lds[cur][0][0];
    const unsigned short* Lg = &lds[cur][1][0];
    const unsigned short* Lu = &lds[cur][2][0];
    short8 a0[4], g0[2], u0[2], a1[4], g1[2], u1[2];
    #pragma unroll
    for (int i = 0; i < 4; ++i)
      a0[i] = *(const short8*)&La[(wm*64 + i*16 + al)*64 + ((ag*8) ^ swz)];
    #pragma unroll
    for (int n = 0; n < 2; ++n) {
      g0[n] = *(const short8*)&Lg[(wn*32 + n*16 + al)*64 + ((ag*8) ^ swz)];
      u0[n] = *(const short8*)&Lu[(wn*32 + n*16 + al)*64 + ((ag*8) ^ swz)];
    }
    #pragma unroll
    for (int i = 0; i < 4; ++i)
      a1[i] = *(const short8*)&La[(wm*64 + i*16 + al)*64 + ((32 + ag*8) ^ swz)];
    #pragma unroll
    for (int n = 0; n < 2; ++n) {
      g1[n] = *(const short8*)&Lg[(wn*32 + n*16 + al)*64 + ((32 + ag*8) ^ swz)];
      u1[n] = *(const short8*)&Lu[(wn*32 + n*16 + al)*64 + ((32 + ag*8) ^ swz)];
    }
    asm volatile("s_waitcnt lgkmcnt(8)" ::: "memory");   // k0 frags complete
    __builtin_amdgcn_sched_barrier(0);
    #pragma unroll
    for (int i = 0; i < 4; ++i)
      #pragma unroll
      for (int n = 0; n < 2; ++n) {
        accg[i][n] = __builtin_amdgcn_mfma_f32_16x16x32_bf16(a0[i], g0[n], accg[i][n], 0, 0, 0);
        accu[i][n] = __builtin_amdgcn_mfma_f32_16x16x32_bf16(a0[i], u0[n], accu[i][n], 0, 0, 0);
      }
    asm volatile("s_waitcnt lgkmcnt(0)" ::: "memory");
    __builtin_amdgcn_sched_barrier(0);
    __builtin_amdgcn_s_barrier();
    if (t + 2 < NT) STAGE(t + 2, cur);
    __builtin_amdgcn_s_setprio(1);
    #pragma unroll
    for (int i = 0; i < 4; ++i)
      #pragma unroll
      for (int n = 0; n < 2; ++n) {
        accg[i][n] = __builtin_amdgcn_mfma_f32_16x16x32_bf16(a1[i], g1[n], accg[i][n], 0, 0, 0);
        accu[i][n] = __builtin_amdgcn_mfma_f32_16x16x32_bf16(a1[i], u1[n], accu[i][n], 0, 0, 0);
      }
    __builtin_amdgcn_s_setprio(0);
    if (t + 2 < NT) { asm volatile("s_waitcnt vmcnt(6)" ::: "memory"); }
    else            { asm volatile("s_waitcnt vmcnt(0)" ::: "memory"); }
    __builtin_amdgcn_s_barrier();
  }
  #undef STAGE

  #pragma unroll
  for (int i = 0; i < 4; ++i)
    #pragma unroll
    for (int r = 0; r < 4; ++r) {
      unsigned short* Cr = Cm + (size_t)(m0 + wm*64 + i*16 + ag*4 + r) * FFD + n0 + wn*32 + al;
      #pragma unroll
      for (int n = 0; n < 2; ++n)
        Cr[n * 16] = f2b(gelu_t(accg[i][n][r]) * accu[i][n][r]);
    }
}

// ------- QKV GEMM (128x128, reg-staged): q/k -> RoPE'd bf16; V -> vT transposed ----
__global__ __launch_bounds__(256) void gemm_qkv_kernel(
    const unsigned short* __restrict__ A, const unsigned short* __restrict__ Bt,
    unsigned short* __restrict__ C, unsigned short* __restrict__ vT,
    const float2* __restrict__ rope_tab) {
  const int N = QKVN, K = DM;
  __shared__ unsigned short As[128 * 40];
  __shared__ unsigned short Bs[128 * 40];
  int bid = blockIdx.x, nwg = gridDim.x;
  int wgid = (bid & 7) * (nwg >> 3) + (bid >> 3);
  int m0 = (wgid & 15) * 128;
  int n0 = (wgid >> 4) * 128;
  int tid = threadIdx.x;
  int lane = tid & 63, wave = tid >> 6;
  int wr = (wave >> 1) * 64, wc = (wave & 1) * 64;
  int l16 = lane & 15, lk8 = (lane >> 4) * 8;
  f32x4 acc[4][4];
  #pragma unroll
  for (int m = 0; m < 4; ++m)
    #pragma unroll
    for (int n = 0; n < 4; ++n) acc[m][n] = (f32x4){0.f, 0.f, 0.f, 0.f};
  const unsigned short* Abase = A + (size_t)m0 * K;
  const unsigned short* Bbase = Bt + (size_t)n0 * K;
  int r0 = tid >> 2;            // 0..63
  int c0 = (tid & 3) * 8;       // 0,8,16,24
  for (int k0 = 0; k0 < K; k0 += 32) {
    uint4 a0 = *(const uint4*)(Abase + (size_t)r0 * K + k0 + c0);
    uint4 a1 = *(const uint4*)(Abase + (size_t)(r0 + 64) * K + k0 + c0);
    uint4 b0 = *(const uint4*)(Bbase + (size_t)r0 * K + k0 + c0);
    uint4 b1 = *(const uint4*)(Bbase + (size_t)(r0 + 64) * K + k0 + c0);
    *(uint4*)&As[r0 * 40 + c0] = a0;
    *(uint4*)&As[(r0 + 64) * 40 + c0] = a1;
    *(uint4*)&Bs[r0 * 40 + c0] = b0;
    *(uint4*)&Bs[(r0 + 64) * 40 + c0] = b1;
    __syncthreads();
    short8 af[4], bfr[4];
    #pragma unroll
    for (int m = 0; m < 4; ++m) af[m]  = *(const short8*)&As[(wr + m*16 + l16) * 40 + lk8];
    #pragma unroll
    for (int n = 0; n < 4; ++n) bfr[n] = *(const short8*)&Bs[(wc + n*16 + l16) * 40 + lk8];
    #pragma unroll
    for (int m = 0; m < 4; ++m)
      #pragma unroll
      for (int n = 0; n < 4; ++n)
        acc[m][n] = __builtin_amdgcn_mfma_f32_16x16x32_bf16(af[m], bfr[n], acc[m][n], 0, 0, 0);
    __syncthreads();
  }
  bool qk = (n0 + wc) < 1024;   // whole 64-col group = one q/k head (RoPE) else V head
  #pragma unroll
  for (int m = 0; m < 4; ++m)
    #pragma unroll
    for (int r = 0; r < 4; ++r) {
      int pos = m0 + wr + m*16 + ((lane >> 4) << 2) + r;
      if (qk) {
        unsigned short* Cr = C + (size_t)pos * N + n0 + wc + l16;
        #pragma unroll
        for (int n = 0; n < 2; ++n) {
          int d = n * 16 + l16;                 // 0..31 within head
          float2 cs = rope_tab[pos * 32 + d];
          float x1 = acc[m][n][r], x2 = acc[m][n + 2][r];
          Cr[n * 16]       = f2b(x1 * cs.x - x2 * cs.y);
          Cr[(n + 2) * 16] = f2b(x2 * cs.x + x1 * cs.y);
        }
      } else {
        // V columns: write transposed vT[(kvh*64+d)][pos]
        #pragma unroll
        for (int n = 0; n < 4; ++n) {
          int hb = n0 + wc + n*16 + l16 - 1024;   // 0..255
          vT[(size_t)hb * TSEQ + pos] = f2b(acc[m][n][r]);
        }
      }
    }
}

// ---------------- MFMA flash attention chunk, causal, GQA, KV-split -----------
__global__ __launch_bounds__(256) void attn_chunk_kernel(
    const unsigned short* __restrict__ qkv, const unsigned short* __restrict__ vT,
    unsigned short* __restrict__ out, float* __restrict__ pO, float* __restrict__ pML) {
  __shared__ unsigned short Ks[2][64 * 64];
  __shared__ unsigned short Vt[2][64 * 64];
  __shared__ unsigned short Ps[4][16 * 64];
  int s = blockIdx.x, h = blockIdx.y;
  int qt, ci;
  if (s < 8)       { qt = s;                ci = 0; }
  else if (s < 24) { qt = 8 + ((s-8) >> 1); ci = (s-8) & 1; }
  else if (s < 48) { qt = 16 + (s-24) / 3;  ci = (s-24) % 3; }
  else             { qt = 24 + ((s-48) >> 2); ci = (s-48) & 3; }
  int nt = qt + 1;
  int t0 = ci * 8;
  int t1 = t0 + 8; if (t1 > nt) t1 = nt;
  int cnt = (nt + 7) >> 3;
  int r0 = qt * 64;
  int kvh = h / 3;           // N_REP = 3
  int t = threadIdx.x;
  int lane = t & 63, w = t >> 6;
  int l16 = lane & 15, g = lane >> 4;

  int qr = r0 + w * 16 + l16;
  const unsigned short* qrow = qkv + (size_t)qr * QKVN + h * HD;
  short8 aq0 = *(const short8*)(qrow + 8 * g);
  short8 aq1 = *(const short8*)(qrow + 32 + 8 * g);

  int sw = (lane & 7) ^ (lane >> 3);
  int rloc = w * 16 + (lane >> 3);
  const unsigned short* kgb = qkv + (size_t)rloc * QKVN + DM + kvh * HD + 8 * sw;
  const unsigned short* vgb = vT + (size_t)(kvh * 64 + rloc) * TSEQ + 8 * sw;

  #define ASTAGE(kb, c) { \
    unsigned short* kd = &Ks[(c)][0] + w * 1024; \
    unsigned short* vd = &Vt[(c)][0] + w * 1024; \
    gl16(kgb + (size_t)(kb) * QKVN,       kd);       \
    gl16(kgb + (size_t)((kb) + 8) * QKVN, kd + 512); \
    gl16(vgb + (kb),                      vd);       \
    gl16(vgb + (size_t)8 * TSEQ + (kb),   vd + 512); \
  }

  f32x4 o_acc[4];
  float mrun[4], lsum[4];
  #pragma unroll
  for (int i = 0; i < 4; ++i) { o_acc[i] = (f32x4){0.f,0.f,0.f,0.f}; mrun[i] = -1e30f; lsum[i] = 0.f; }

  ASTAGE(t0 * 64, 0);
  for (int kt = t0; kt < t1; ++kt) {
    int cur = (kt - t0) & 1;
    int kb = kt * 64;
    if (kt + 1 < t1) {
      ASTAGE((kt + 1) * 64, cur ^ 1);                     // prefetch next tile
      asm volatile("s_waitcnt vmcnt(4)" ::: "memory");    // current tile's 4 done
    } else {
      asm volatile("s_waitcnt vmcnt(0)" ::: "memory");
    }
    __builtin_amdgcn_s_barrier();

    const unsigned short* Kc = &Ks[cur][0];
    const unsigned short* Vc = &Vt[cur][0];

    f32x4 s_acc[4];
    #pragma unroll
    for (int nb = 0; nb < 4; ++nb) s_acc[nb] = (f32x4){0.f,0.f,0.f,0.f};
    #pragma unroll
    for (int nb = 0; nb < 4; ++nb) {
      int key = nb * 16 + l16;
      short8 bk0 = *(const short8*)&Kc[key * 64 + ((g       ^ (key & 7)) << 3)];
      short8 bk1 = *(const short8*)&Kc[key * 64 + (((4 + g) ^ (key & 7)) << 3)];
      s_acc[nb] = __builtin_amdgcn_mfma_f32_16x16x32_bf16(aq0, bk0, s_acc[nb], 0, 0, 0);
      s_acc[nb] = __builtin_amdgcn_mfma_f32_16x16x32_bf16(aq1, bk1, s_acc[nb], 0, 0, 0);
    }

    bool diag = (kt == qt);
    #pragma unroll
    for (int r = 0; r < 4; ++r) {
      int qg = r0 + w * 16 + g * 4 + r;
      float sv[4];
      #pragma unroll
      for (int nb = 0; nb < 4; ++nb) {
        sv[nb] = s_acc[nb][r] * 0.125f;
        if (diag && (kb + nb * 16 + l16 > qg)) sv[nb] = -1e30f;
      }
      float mx = fmaxf(fmaxf(sv[0], sv[1]), fmaxf(sv[2], sv[3]));
      mx = fmaxf(mx, __shfl_xor(mx, 1));
      mx = fmaxf(mx, __shfl_xor(mx, 2));
      mx = fmaxf(mx, __shfl_xor(mx, 4));
      mx = fmaxf(mx, __shfl_xor(mx, 8));
      if (mx > mrun[r] + 8.0f) {
        float es = __expf(mrun[r] - mx);
        lsum[r] *= es;
        #pragma unroll
        for (int db = 0; db < 4; ++db) o_acc[db][r] *= es;
        mrun[r] = mx;
      }
      float rsum = 0.f;
      #pragma unroll
      for (int nb = 0; nb < 4; ++nb) { sv[nb] = __expf(sv[nb] - mrun[r]); rsum += sv[nb]; }
      lsum[r] += rsum;
      int qloc = g * 4 + r, q7 = qloc & 7;
      #pragma unroll
      for (int nb = 0; nb < 4; ++nb) {
        int key = nb * 16 + l16;
        Ps[w][qloc * 64 + ((((key >> 3) ^ q7) << 3) + (key & 7))] = f2b(sv[nb]);
      }
    }

    #pragma unroll
    for (int kc = 0; kc < 2; ++kc) {
      short8 pa = *(const short8*)&Ps[w][l16 * 64 + (((4 * kc + g) ^ (l16 & 7)) << 3)];
      #pragma unroll
      for (int db = 0; db < 4; ++db) {
        int d = db * 16 + l16;
        short8 bv = *(const short8*)&Vc[d * 64 + (((4 * kc + g) ^ (d & 7)) << 3)];
        o_acc[db] = __builtin_amdgcn_mfma_f32_16x16x32_bf16(pa, bv, o_acc[db], 0, 0, 0);
      }
    }
    __builtin_amdgcn_s_barrier();
  }
  #undef ASTAGE

  if (cnt == 1) {
    #pragma unroll
    for (int r = 0; r < 4; ++r) {
      int qg = r0 + w * 16 + g * 4 + r;
      float sr = lsum[r];
      sr += __shfl_xor(sr, 1);
      sr += __shfl_xor(sr, 2);
      sr += __shfl_xor(sr, 4);
      sr += __shfl_xor(sr, 8);
      float inv = 1.0f / sr;
      unsigned short* orow = out + (size_t)qg * DM + h * HD + l16;
      #pragma unroll
      for (int db = 0; db < 4; ++db) orow[db * 16] = f2b(o_acc[db][r] * inv);
    }
  } else {
    size_t slotg = (size_t)h * 80 + s;
    float* po = pO + slotg * 4096;
    float* pm = pML + slotg * 128;
    #pragma unroll
    for (int r = 0; r < 4; ++r) {
      int row = w * 16 + g * 4 + r;
      float sr = lsum[r];
      sr += __shfl_xor(sr, 1);
      sr += __shfl_xor(sr, 2);
      sr += __shfl_xor(sr, 4);
      sr += __shfl_xor(sr, 8);
      #pragma unroll
      for (int db = 0; db < 4; ++db) po[row * 64 + db * 16 + l16] = o_acc[db][r];
      if (l16 == 0) { pm[row * 2] = mrun[r]; pm[row * 2 + 1] = sr; }
    }
  }
}

// ---------------- combine partials for qt >= 8 ----------------
__global__ __launch_bounds__(256) void attn_combine_kernel(
    const float* __restrict__ pO, const float* __restrict__ pML,
    unsigned short* __restrict__ out) {
  int h = blockIdx.y;
  int qt = 8 + blockIdx.x;            // 8..31
  int base, cnt;
  if (qt < 16)      { base = 8 + (qt - 8) * 2;  cnt = 2; }
  else if (qt < 24) { base = 24 + (qt - 16) * 3; cnt = 3; }
  else              { base = 48 + (qt - 24) * 4; cnt = 4; }
  int t = threadIdx.x;
  int row = t >> 2, d0 = (t & 3) * 16;
  float m[4], l[4];
  float M = -1e30f;
  for (int c = 0; c < cnt; ++c) {
    const float* pm = pML + ((size_t)h * 80 + base + c) * 128 + row * 2;
    m[c] = pm[0]; l[c] = pm[1];
    M = fmaxf(M, m[c]);
  }
  float o[16];
  #pragma unroll
  for (int j = 0; j < 16; ++j) o[j] = 0.f;
  float wl = 0.f;
  for (int c = 0; c < cnt; ++c) {
    float wc = __expf(m[c] - M);
    wl += wc * l[c];
    const float4* po = (const float4*)(pO + ((size_t)h * 80 + base + c) * 4096 + row * 64 + d0);
    #pragma unroll
    for (int q = 0; q < 4; ++q) {
      float4 v = po[q];
      o[q*4+0] += wc * v.x; o[q*4+1] += wc * v.y;
      o[q*4+2] += wc * v.z; o[q*4+3] += wc * v.w;
    }
  }
  float inv = 1.0f / wl;
  unsigned short* orow = out + (size_t)(qt * 64 + row) * DM + h * HD + d0;
  uint4 s0, s1;
  s0.x = packbf(o[0]*inv,  o[1]*inv);  s0.y = packbf(o[2]*inv,  o[3]*inv);
  s0.z = packbf(o[4]*inv,  o[5]*inv);  s0.w = packbf(o[6]*inv,  o[7]*inv);
  s1.x = packbf(o[8]*inv,  o[9]*inv);  s1.y = packbf(o[10]*inv, o[11]*inv);
  s1.z = packbf(o[12]*inv, o[13]*inv); s1.w = packbf(o[14]*inv, o[15]*inv);
  ((uint4*)orow)[0] = s0; ((uint4*)orow)[1] = s1;
}

extern "C" void kernel_launch(void* const* d_in, const int* in_sizes, int n_in,
                              void* d_out, int out_size, void* d_ws, size_t ws_size,
                              hipStream_t stream) {
  const int*   idx   = (const int*)d_in[0];
  const float* embed = (const float*)d_in[1];
  const float* ln1   = (const float*)d_in[2];
  const float* Wq    = (const float*)d_in[3];
  const float* Wk    = (const float*)d_in[4];
  const float* Wv    = (const float*)d_in[5];
  const float* Wo    = (const float*)d_in[6];
  const float* ln2   = (const float*)d_in[7];
  const float* Wg    = (const float*)d_in[8];
  const float* Wu    = (const float*)d_in[9];
  const float* Wd    = (const float*)d_in[10];
  const float* normf = (const float*)d_in[11];
  float* out = (float*)d_out;
  char* ws = (char*)d_ws;
  (void)in_sizes; (void)n_in; (void)out_size; (void)ws_size;

  // ---- workspace layout ----
  unsigned short* embed_bf = (unsigned short*)ws;
  size_t off = (size_t)VOC * DM * 2;
  unsigned short* wts = (unsigned short*)(ws + off);
  const size_t LW = (size_t)QKVN * DM + (size_t)DM * DM
                  + 2ull * FFD * DM + (size_t)DM * FFD;
  off += LW * 2ull * NL;
  float* xf = (float*)(ws + off);            off += (size_t)TSEQ * DM * 4;
  unsigned short* h_bf = (unsigned short*)(ws + off);    off += (size_t)TSEQ * DM * 2;
  unsigned short* qkv_bf = (unsigned short*)(ws + off);  off += (size_t)TSEQ * QKVN * 2;
  unsigned short* attn_bf = (unsigned short*)(ws + off); off += (size_t)TSEQ * DM * 2;
  // pO (attn partials) overlays m_bf: disjoint lifetimes (attn->combine vs gu8->wd)
  float* pO = (float*)(ws + off);
  unsigned short* m_bf = (unsigned short*)(ws + off);
  off += (size_t)NH * 80 * 4096 * 4;
  float* pML = (float*)(ws + off);           off += (size_t)NH * 80 * 128 * 4;
  float2* rope_tab = (float2*)(ws + off);    off += (size_t)TSEQ * 32 * 8;
  unsigned short* vT = (unsigned short*)(ws + off);      off += (size_t)NKV * HD * TSEQ * 2;

  // ---- prep: embed cast + rope table + mega weight transpose/cast ----
  cast_bf16_kernel<<<(VOC * DM / 4 + 255) / 256, 256, 0, stream>>>(embed, embed_bf, VOC * DM / 4);
  rope_tab_kernel<<<TSEQ * 32 / 256, 256, 0, stream>>>(rope_tab);
  transpose_all_kernel<<<dim3(6144, 1, NL), dim3(32, 8), 0, stream>>>(
      Wq, Wk, Wv, Wo, Wg, Wu, Wd, wts, LW);

  gather_kernel<<<TSEQ, 192, 0, stream>>>(idx, embed, xf);

  for (int l = 0; l < NL; ++l) {
    unsigned short* base = wts + (size_t)l * LW;
    unsigned short* qkvT = base;
    unsigned short* woT  = base + (size_t)QKVN * DM;
    unsigned short* wguT = woT + (size_t)DM * DM;
    unsigned short* wdT  = wguT + 2ull * FFD * DM;

    rmsnorm_kernel<<<TSEQ, 256, 0, stream>>>(xf, ln1 + (size_t)l * DM, h_bf);
    gemm_qkv_kernel<<<(QKVN / 128) * 16, 256, 0, stream>>>(h_bf, qkvT, qkv_bf, vT, rope_tab);
    attn_chunk_kernel<<<dim3(80, NH), 256, 0, stream>>>(qkv_bf, vT, attn_bf, pO, pML);
    attn_combine_kernel<<<dim3(24, NH), 256, 0, stream>>>(pO, pML, attn_bf);
    gemm_p8_kernel<<<dim3((DM / 128) * 16, 3), 512, 0, stream>>>(attn_bf, woT, xf, DM, DM, 256);
    rmsnorm_kernel<<<TSEQ, 256, 0, stream>>>(xf, ln2 + (size_t)l * DM, h_bf);
    gemm_gu8_kernel<<<(FFD / 128) * 16, 512, 0, stream>>>(h_bf, wguT, wguT + (size_t)FFD * DM, m_bf);
    gemm_p8_kernel<<<dim3((DM / 128) * 16, 4), 512, 0, stream>>>(m_bf, wdT, xf, DM, FFD, 512);
  }

  rmsnorm_kernel<<<TSEQ, 256, 0, stream>>>(xf, normf, h_bf);
  gemm_l8_kernel<<<(VOC / 256) * (TSEQ / 256), 512, 0, stream>>>(h_bf, embed_bf, out, VOC, DM);
}

// Round 12
// 695.862 us; speedup vs baseline: 1.7908x; 1.0930x over previous
//
#include <hip/hip_runtime.h>

#define TSEQ 2048
#define DM   768
#define NH   12
#define NKV  4
#define HD   64
#define FFD  2048
#define NL   4
#define VOC  32000
#define QKVN 1280   // 768 q + 256 k + 256 v

typedef __attribute__((ext_vector_type(8))) short short8;
typedef __attribute__((ext_vector_type(4))) float f32x4;

__device__ __forceinline__ unsigned short f2b(float f) {
  unsigned int u = __float_as_uint(f);
  u += 0x7fffu + ((u >> 16) & 1u);
  return (unsigned short)(u >> 16);
}
__device__ __forceinline__ float b2f(unsigned short u) {
  return __uint_as_float(((unsigned int)u) << 16);
}
__device__ __forceinline__ unsigned int packbf(float a, float b) {
  return (unsigned int)f2b(a) | ((unsigned int)f2b(b) << 16);
}

// direct global->LDS async copy, 16B/lane; LDS dest wave-uniform (HW adds lane*16)
__device__ __forceinline__ void gl16(const unsigned short* g, unsigned short* l) {
  __builtin_amdgcn_global_load_lds(
      (const __attribute__((address_space(1))) void*)g,
      (__attribute__((address_space(3))) void*)l, 16, 0, 0);
}

// ------- mega prep: embed cast | rope table | gather | all weight transposes ----
// One launch; flat block decode. All four jobs are independent.
__global__ void mega_prep_kernel(const float* __restrict__ embed, unsigned short* __restrict__ embed_bf,
                                 float2* __restrict__ rope_tab,
                                 const int* __restrict__ idx, float* __restrict__ xf,
                                 const float* __restrict__ Wq, const float* __restrict__ Wk,
                                 const float* __restrict__ Wv, const float* __restrict__ Wo,
                                 const float* __restrict__ Wg, const float* __restrict__ Wu,
                                 const float* __restrict__ Wd, unsigned short* __restrict__ wts,
                                 size_t LW) {
  int blk = blockIdx.x;
  int t = threadIdx.x;
  if (blk < 24000) {                       // embed f32 -> bf16, x4
    int i = blk * 256 + t;                 // over VOC*DM/4
    float4 v = ((const float4*)embed)[i];
    uint2 o; o.x = packbf(v.x, v.y); o.y = packbf(v.z, v.w);
    ((uint2*)embed_bf)[i] = o;
    return;
  }
  if (blk < 24256) {                       // rope table
    int i = (blk - 24000) * 256 + t;       // over TSEQ*32
    int pos = i >> 5, d = i & 31;
    float inv = exp2f(-(float)d * (13.287712379549449f / 32.0f));
    float sv, cv; sincosf((float)pos * inv, &sv, &cv);
    rope_tab[i] = make_float2(cv, sv);
    return;
  }
  if (blk < 26304) {                       // embedding gather
    int row = blk - 24256;
    if (t < 192) {
      int id = idx[row];
      ((float4*)(xf + (size_t)row * DM))[t] = ((const float4*)(embed + (size_t)id * DM))[t];
    }
    return;
  }
  // weight transpose+cast: r in [0, 6144*NL)
  __shared__ float tile[32][33];
  int r = blk - 26304;
  int l = r / 6144; r -= l * 6144;
  const float* src; size_t sstr, doff; int K, N, nx;
  if (r < 576)       { src = Wq; sstr = 589824;  doff = 0;                          K = 768;  N = 768;  nx = 24; }
  else if (r < 768)  { src = Wk; sstr = 196608;  doff = 768ull * 768;               K = 768;  N = 256;  nx = 8;  r -= 576; }
  else if (r < 960)  { src = Wv; sstr = 196608;  doff = 1024ull * 768;              K = 768;  N = 256;  nx = 8;  r -= 768; }
  else if (r < 1536) { src = Wo; sstr = 589824;  doff = (size_t)QKVN * DM;          K = 768;  N = 768;  nx = 24; r -= 960; }
  else if (r < 3072) { src = Wg; sstr = 1572864; doff = (size_t)QKVN * DM + (size_t)DM * DM;
                       K = 768;  N = 2048; nx = 64; r -= 1536; }
  else if (r < 4608) { src = Wu; sstr = 1572864; doff = (size_t)QKVN * DM + (size_t)DM * DM + (size_t)FFD * DM;
                       K = 768;  N = 2048; nx = 64; r -= 3072; }
  else               { src = Wd; sstr = 1572864; doff = (size_t)QKVN * DM + (size_t)DM * DM + 2ull * FFD * DM;
                       K = 2048; N = 768;  nx = 24; r -= 4608; }
  int bx = r % nx, by = r / nx;
  src += (size_t)l * sstr;
  unsigned short* dst = wts + (size_t)l * LW + doff;
  int n0 = bx * 32, k0 = by * 32;
  int tx = t & 31, ty = t >> 5;            // 32 x 8
  #pragma unroll
  for (int i = 0; i < 4; ++i) {
    int rr = ty + i * 8;
    tile[rr][tx] = src[(size_t)(k0 + rr) * N + n0 + tx];
  }
  __syncthreads();
  #pragma unroll
  for (int i = 0; i < 4; ++i) {
    int rr = ty + i * 8;
    dst[(size_t)(n0 + rr) * K + k0 + tx] = f2b(tile[tx][rr]);
  }
}

// ---------------- RMSNorm: f32 in -> bf16 out ----------------
__global__ void rmsnorm_kernel(const float* __restrict__ x,
                               const float* __restrict__ w,
                               unsigned short* __restrict__ out) {
  int row = blockIdx.x; int t = threadIdx.x;  // 256 threads, D=768
  const float* xr = x + (size_t)row * DM;
  float v0 = xr[t], v1 = xr[t + 256], v2 = xr[t + 512];
  float s = v0*v0 + v1*v1 + v2*v2;
  #pragma unroll
  for (int off = 1; off < 64; off <<= 1) s += __shfl_xor(s, off);
  __shared__ float red[4];
  if ((t & 63) == 0) red[t >> 6] = s;
  __syncthreads();
  float tot = red[0] + red[1] + red[2] + red[3];
  float rs = rsqrtf(tot * (1.0f / DM) + 1e-6f);
  unsigned short* orow = out + (size_t)row * DM;
  orow[t]       = f2b(w[t]       * v0 * rs);
  orow[t + 256] = f2b(w[t + 256] * v1 * rs);
  orow[t + 512] = f2b(w[t + 512] * v2 * rs);
}

// ---------------- 256x256 deep-pipelined GEMM (logits): C = A @ Bt^T, f32 out ----
__global__ __launch_bounds__(512, 1) void gemm_l8_kernel(
    const unsigned short* __restrict__ A, const unsigned short* __restrict__ Bt,
    float* __restrict__ C, int N, int K) {
  __shared__ unsigned short lds[2][2][256 * 64];   // [dbuf][A,B][row*64+col]
  const int NT = K >> 6;
  int bid = blockIdx.x, nwg = gridDim.x;
  int wgid = (bid & 7) * (nwg >> 3) + (bid >> 3);
  int m0 = (wgid & 7) * 256;        // 8 m-tiles (TSEQ/256)
  int n0 = (wgid >> 3) * 256;
  int tid = threadIdx.x;
  int lane = tid & 63, w = tid >> 6;
  int wm = w >> 2, wn = w & 3;
  int al = lane & 15, ag = lane >> 4;
  int swz = (al & 7) << 3;          // frag-read swizzle (shorts)

  int rA = tid >> 3;                                  // 0..63
  int cK = ((tid & 7) * 8) ^ ((rA & 7) << 3);         // bf16 col within 64
  const unsigned short* Ag = A + (size_t)(m0 + rA) * K + cK;
  const unsigned short* Bg = Bt + (size_t)(n0 + rA) * K + cK;

  f32x4 acc[8][4];
  #pragma unroll
  for (int i = 0; i < 8; ++i)
    #pragma unroll
    for (int n = 0; n < 4; ++n) acc[i][n] = (f32x4){0.f, 0.f, 0.f, 0.f};

  #define STAGE(kt, c) { \
    size_t ko = (size_t)(kt) * 64; \
    unsigned short* dA = &lds[(c)][0][0] + w * 512; \
    unsigned short* dB = &lds[(c)][1][0] + w * 512; \
    gl16(Ag + (size_t)0   * K + ko, dA);            \
    gl16(Ag + (size_t)64  * K + ko, dA + 4096);     \
    gl16(Ag + (size_t)128 * K + ko, dA + 8192);     \
    gl16(Ag + (size_t)192 * K + ko, dA + 12288);    \
    gl16(Bg + (size_t)0   * K + ko, dB);            \
    gl16(Bg + (size_t)64  * K + ko, dB + 4096);     \
    gl16(Bg + (size_t)128 * K + ko, dB + 8192);     \
    gl16(Bg + (size_t)192 * K + ko, dB + 12288);    \
  }

  STAGE(0, 0);
  STAGE(1, 1);
  asm volatile("s_waitcnt vmcnt(8)" ::: "memory");
  __builtin_amdgcn_s_barrier();

  for (int t = 0; t < NT; ++t) {
    int cur = t & 1;
    const unsigned short* La = &lds[cur][0][0];
    const unsigned short* Lb = &lds[cur][1][0];
    short8 a0[8], b0[4], a1[8], b1[4];
    #pragma unroll
    for (int i = 0; i < 4; ++i)
      a0[i] = *(const short8*)&La[(wm*128 + i*16 + al)*64 + ((ag*8) ^ swz)];
    #pragma unroll
    for (int n = 0; n < 4; ++n)
      b0[n] = *(const short8*)&Lb[(wn*64 + n*16 + al)*64 + ((ag*8) ^ swz)];
    #pragma unroll
    for (int i = 4; i < 8; ++i)
      a0[i] = *(const short8*)&La[(wm*128 + i*16 + al)*64 + ((ag*8) ^ swz)];
    asm volatile("s_waitcnt lgkmcnt(4)" ::: "memory");
    __builtin_amdgcn_sched_barrier(0);
    #pragma unroll
    for (int i = 0; i < 4; ++i)
      #pragma unroll
      for (int n = 0; n < 4; ++n)
        acc[i][n] = __builtin_amdgcn_mfma_f32_16x16x32_bf16(a0[i], b0[n], acc[i][n], 0, 0, 0);
    #pragma unroll
    for (int n = 0; n < 4; ++n)
      b1[n] = *(const short8*)&Lb[(wn*64 + n*16 + al)*64 + ((32 + ag*8) ^ swz)];
    #pragma unroll
    for (int i = 0; i < 4; ++i)
      a1[i] = *(const short8*)&La[(wm*128 + i*16 + al)*64 + ((32 + ag*8) ^ swz)];
    asm volatile("s_waitcnt lgkmcnt(8)" ::: "memory");
    __builtin_amdgcn_sched_barrier(0);
    #pragma unroll
    for (int i = 4; i < 8; ++i)
      #pragma unroll
      for (int n = 0; n < 4; ++n)
        acc[i][n] = __builtin_amdgcn_mfma_f32_16x16x32_bf16(a0[i], b0[n], acc[i][n], 0, 0, 0);
    #pragma unroll
    for (int i = 4; i < 8; ++i)
      a1[i] = *(const short8*)&La[(wm*128 + i*16 + al)*64 + ((32 + ag*8) ^ swz)];
    asm volatile("s_waitcnt lgkmcnt(4)" ::: "memory");
    __builtin_amdgcn_sched_barrier(0);
    #pragma unroll
    for (int i = 0; i < 4; ++i)
      #pragma unroll
      for (int n = 0; n < 4; ++n)
        acc[i][n] = __builtin_amdgcn_mfma_f32_16x16x32_bf16(a1[i], b1[n], acc[i][n], 0, 0, 0);
    asm volatile("s_waitcnt lgkmcnt(0)" ::: "memory");
    __builtin_amdgcn_sched_barrier(0);
    __builtin_amdgcn_s_barrier();
    if (t + 2 < NT) STAGE(t + 2, cur);
    __builtin_amdgcn_s_setprio(1);
    #pragma unroll
    for (int i = 4; i < 8; ++i)
      #pragma unroll
      for (int n = 0; n < 4; ++n)
        acc[i][n] = __builtin_amdgcn_mfma_f32_16x16x32_bf16(a1[i], b1[n], acc[i][n], 0, 0, 0);
    __builtin_amdgcn_s_setprio(0);
    if (t + 2 < NT) { asm volatile("s_waitcnt vmcnt(8)" ::: "memory"); }
    else            { asm volatile("s_waitcnt vmcnt(0)" ::: "memory"); }
    __builtin_amdgcn_s_barrier();
  }
  #undef STAGE

  #pragma unroll
  for (int i = 0; i < 8; ++i)
    #pragma unroll
    for (int r = 0; r < 4; ++r) {
      float* Cr = C + (size_t)(m0 + wm*128 + i*16 + ag*4 + r) * N + n0 + wn*64 + al;
      #pragma unroll
      for (int n = 0; n < 4; ++n) Cr[n * 16] = acc[i][n][r];
    }
}

// ---------------- 128x128 pipelined 8-wave GEMM, split-K, f32 atomicAdd ----------
__global__ __launch_bounds__(512) void gemm_p8_kernel(
    const unsigned short* __restrict__ A, const unsigned short* __restrict__ Bt,
    float* __restrict__ C, int N, int K, int Kc) {
  __shared__ unsigned short lds[2][2][128 * 64];
  const int NT = Kc >> 6;
  int bid = blockIdx.x, nwg = gridDim.x;
  int wgid = (bid & 7) * (nwg >> 3) + (bid >> 3);
  int m0 = (wgid & 15) * 128;
  int n0 = (wgid >> 4) * 128;
  int tid = threadIdx.x;
  int lane = tid & 63, w = tid >> 6;
  int wm = w >> 2, wn = w & 3;
  int al = lane & 15, ag = lane >> 4;
  int swz = (al & 7) << 3;

  size_t koff = (size_t)blockIdx.y * Kc;
  int rp = 8 * w + (lane >> 3);
  int cK = ((lane & 7) * 8) ^ ((lane >> 3) << 3);
  const unsigned short* Ag = A + (size_t)(m0 + rp) * K + koff + cK;
  const unsigned short* Bg = Bt + (size_t)(n0 + rp) * K + koff + cK;

  f32x4 acc[4][2];
  #pragma unroll
  for (int i = 0; i < 4; ++i)
    #pragma unroll
    for (int n = 0; n < 2; ++n) acc[i][n] = (f32x4){0.f, 0.f, 0.f, 0.f};

  #define STAGE(kt, c) { \
    size_t ko = (size_t)(kt) * 64; \
    unsigned short* dA = &lds[(c)][0][0] + w * 512; \
    unsigned short* dB = &lds[(c)][1][0] + w * 512; \
    gl16(Ag + ko,                 dA);        \
    gl16(Ag + (size_t)64*K + ko,  dA + 4096); \
    gl16(Bg + ko,                 dB);        \
    gl16(Bg + (size_t)64*K + ko,  dB + 4096); \
  }

  STAGE(0, 0);
  STAGE(1, 1);
  asm volatile("s_waitcnt vmcnt(4)" ::: "memory");
  __builtin_amdgcn_s_barrier();

  for (int t = 0; t < NT; ++t) {
    int cur = t & 1;
    const unsigned short* La = &lds[cur][0][0];
    const unsigned short* Lb = &lds[cur][1][0];
    short8 a0[4], b0[2], a1[4], b1[2];
    #pragma unroll
    for (int i = 0; i < 4; ++i)
      a0[i] = *(const short8*)&La[(wm*64 + i*16 + al)*64 + ((ag*8) ^ swz)];
    #pragma unroll
    for (int n = 0; n < 2; ++n)
      b0[n] = *(const short8*)&Lb[(wn*32 + n*16 + al)*64 + ((ag*8) ^ swz)];
    #pragma unroll
    for (int i = 0; i < 4; ++i)
      a1[i] = *(const short8*)&La[(wm*64 + i*16 + al)*64 + ((32 + ag*8) ^ swz)];
    #pragma unroll
    for (int n = 0; n < 2; ++n)
      b1[n] = *(const short8*)&Lb[(wn*32 + n*16 + al)*64 + ((32 + ag*8) ^ swz)];
    asm volatile("s_waitcnt lgkmcnt(6)" ::: "memory");
    __builtin_amdgcn_sched_barrier(0);
    #pragma unroll
    for (int i = 0; i < 4; ++i)
      #pragma unroll
      for (int n = 0; n < 2; ++n)
        acc[i][n] = __builtin_amdgcn_mfma_f32_16x16x32_bf16(a0[i], b0[n], acc[i][n], 0, 0, 0);
    asm volatile("s_waitcnt lgkmcnt(0)" ::: "memory");
    __builtin_amdgcn_sched_barrier(0);
    __builtin_amdgcn_s_barrier();
    if (t + 2 < NT) STAGE(t + 2, cur);
    __builtin_amdgcn_s_setprio(1);
    #pragma unroll
    for (int i = 0; i < 4; ++i)
      #pragma unroll
      for (int n = 0; n < 2; ++n)
        acc[i][n] = __builtin_amdgcn_mfma_f32_16x16x32_bf16(a1[i], b1[n], acc[i][n], 0, 0, 0);
    __builtin_amdgcn_s_setprio(0);
    if (t + 2 < NT) { asm volatile("s_waitcnt vmcnt(4)" ::: "memory"); }
    else            { asm volatile("s_waitcnt vmcnt(0)" ::: "memory"); }
    __builtin_amdgcn_s_barrier();
  }
  #undef STAGE

  #pragma unroll
  for (int i = 0; i < 4; ++i)
    #pragma unroll
    for (int r = 0; r < 4; ++r) {
      float* Cr = C + (size_t)(m0 + wm*64 + i*16 + ag*4 + r) * N + n0 + wn*32 + al;
      #pragma unroll
      for (int n = 0; n < 2; ++n) atomicAdd(&Cr[n * 16], acc[i][n][r]);
    }
}

// ---------------- gelu ----------------
__device__ __forceinline__ float gelu_t(float x) {
  float x3 = x * x * x;
  return 0.5f * x * (1.0f + tanhf(0.7978845608028654f * (x + 0.044715f * x3)));
}

// ---- pipelined gate/up GEMM: tile 128 rows x [G128|U128], 8 waves, BK=64 ----
__global__ __launch_bounds__(512) void gemm_gu8_kernel(
    const unsigned short* __restrict__ A, const unsigned short* __restrict__ BtG,
    const unsigned short* __restrict__ BtU, unsigned short* __restrict__ Cm) {
  __shared__ unsigned short lds[2][3][128 * 64];   // [dbuf][A,G,U]
  const int K = DM;
  const int NT = K >> 6;                           // 12
  int bid = blockIdx.x, nwg = gridDim.x;           // 256
  int wgid = (bid & 7) * (nwg >> 3) + (bid >> 3);
  int m0 = (wgid & 15) * 128;
  int n0 = (wgid >> 4) * 128;                      // over FF
  int tid = threadIdx.x;
  int lane = tid & 63, w = tid >> 6;
  int wm = w >> 2, wn = w & 3;
  int al = lane & 15, ag = lane >> 4;
  int swz = (al & 7) << 3;

  int rp = 8 * w + (lane >> 3);
  int cK = ((lane & 7) * 8) ^ ((lane >> 3) << 3);
  const unsigned short* Ag = A + (size_t)(m0 + rp) * K + cK;
  const unsigned short* Gg = BtG + (size_t)(n0 + rp) * K + cK;
  const unsigned short* Ug = BtU + (size_t)(n0 + rp) * K + cK;

  f32x4 accg[4][2], accu[4][2];
  #pragma unroll
  for (int i = 0; i < 4; ++i)
    #pragma unroll
    for (int n = 0; n < 2; ++n) {
      accg[i][n] = (f32x4){0.f, 0.f, 0.f, 0.f};
      accu[i][n] = (f32x4){0.f, 0.f, 0.f, 0.f};
    }

  #define STAGE(kt, c) { \
    size_t ko = (size_t)(kt) * 64; \
    unsigned short* dA = &lds[(c)][0][0] + w * 512; \
    unsigned short* dG = &lds[(c)][1][0] + w * 512; \
    unsigned short* dU = &lds[(c)][2][0] + w * 512; \
    gl16(Ag + ko,                 dA);        \
    gl16(Ag + (size_t)64*K + ko,  dA + 4096); \
    gl16(Gg + ko,                 dG);        \
    gl16(Gg + (size_t)64*K + ko,  dG + 4096); \
    gl16(Ug + ko,                 dU);        \
    gl16(Ug + (size_t)64*K + ko,  dU + 4096); \
  }

  STAGE(0, 0);
  STAGE(1, 1);
  asm volatile("s_waitcnt vmcnt(6)" ::: "memory");
  __builtin_amdgcn_s_barrier();

  for (int t = 0; t < NT; ++t) {
    int cur = t & 1;
    const unsigned short* La = &lds[cur][0][0];
    const unsigned short* Lg = &lds[cur][1][0];
    const unsigned short* Lu = &lds[cur][2][0];
    short8 a0[4], g0[2], u0[2], a1[4], g1[2], u1[2];
    #pragma unroll
    for (int i = 0; i < 4; ++i)
      a0[i] = *(const short8*)&La[(wm*64 + i*16 + al)*64 + ((ag*8) ^ swz)];
    #pragma unroll
    for (int n = 0; n < 2; ++n) {
      g0[n] = *(const short8*)&Lg[(wn*32 + n*16 + al)*64 + ((ag*8) ^ swz)];
      u0[n] = *(const short8*)&Lu[(wn*32 + n*16 + al)*64 + ((ag*8) ^ swz)];
    }
    #pragma unroll
    for (int i = 0; i < 4; ++i)
      a1[i] = *(const short8*)&La[(wm*64 + i*16 + al)*64 + ((32 + ag*8) ^ swz)];
    #pragma unroll
    for (int n = 0; n < 2; ++n) {
      g1[n] = *(const short8*)&Lg[(wn*32 + n*16 + al)*64 + ((32 + ag*8) ^ swz)];
      u1[n] = *(const short8*)&Lu[(wn*32 + n*16 + al)*64 + ((32 + ag*8) ^ swz)];
    }
    asm volatile("s_waitcnt lgkmcnt(8)" ::: "memory");
    __builtin_amdgcn_sched_barrier(0);
    #pragma unroll
    for (int i = 0; i < 4; ++i)
      #pragma unroll
      for (int n = 0; n < 2; ++n) {
        accg[i][n] = __builtin_amdgcn_mfma_f32_16x16x32_bf16(a0[i], g0[n], accg[i][n], 0, 0, 0);
        accu[i][n] = __builtin_amdgcn_mfma_f32_16x16x32_bf16(a0[i], u0[n], accu[i][n], 0, 0, 0);
      }
    asm volatile("s_waitcnt lgkmcnt(0)" ::: "memory");
    __builtin_amdgcn_sched_barrier(0);
    __builtin_amdgcn_s_barrier();
    if (t + 2 < NT) STAGE(t + 2, cur);
    __builtin_amdgcn_s_setprio(1);
    #pragma unroll
    for (int i = 0; i < 4; ++i)
      #pragma unroll
      for (int n = 0; n < 2; ++n) {
        accg[i][n] = __builtin_amdgcn_mfma_f32_16x16x32_bf16(a1[i], g1[n], accg[i][n], 0, 0, 0);
        accu[i][n] = __builtin_amdgcn_mfma_f32_16x16x32_bf16(a1[i], u1[n], accu[i][n], 0, 0, 0);
      }
    __builtin_amdgcn_s_setprio(0);
    if (t + 2 < NT) { asm volatile("s_waitcnt vmcnt(6)" ::: "memory"); }
    else            { asm volatile("s_waitcnt vmcnt(0)" ::: "memory"); }
    __builtin_amdgcn_s_barrier();
  }
  #undef STAGE

  #pragma unroll
  for (int i = 0; i < 4; ++i)
    #pragma unroll
    for (int r = 0; r < 4; ++r) {
      unsigned short* Cr = Cm + (size_t)(m0 + wm*64 + i*16 + ag*4 + r) * FFD + n0 + wn*32 + al;
      #pragma unroll
      for (int n = 0; n < 2; ++n)
        Cr[n * 16] = f2b(gelu_t(accg[i][n][r]) * accu[i][n][r]);
    }
}

// ------- QKV GEMM, p8-pipelined, waves 4Mx2N (wave owns full 64-col head) -------
// Epilogue: q/k cols -> RoPE'd bf16 (pairs wave-local); V cols -> LDS transpose
// -> coalesced vT[(hb)][pos] stores.
__global__ __launch_bounds__(512) void gemm_qkv8_kernel(
    const unsigned short* __restrict__ A, const unsigned short* __restrict__ Bt,
    unsigned short* __restrict__ C, unsigned short* __restrict__ vT,
    const float2* __restrict__ rope_tab) {
  __shared__ unsigned short lds[2][2][128 * 64];
  const int N = QKVN, K = DM;
  const int NT = K >> 6;                       // 12
  int bid = blockIdx.x, nwg = gridDim.x;       // 160
  int wgid = (bid & 7) * (nwg >> 3) + (bid >> 3);
  int m0 = (wgid & 15) * 128;
  int n0 = (wgid >> 4) * 128;
  int tid = threadIdx.x;
  int lane = tid & 63, w = tid >> 6;
  int wm = w >> 1, wn = w & 1;                 // 4M x 2N: wave owns 32 rows x 64 cols
  int al = lane & 15, ag = lane >> 4;
  int swz = (al & 7) << 3;

  int rp = 8 * w + (lane >> 3);
  int cK = ((lane & 7) * 8) ^ ((lane >> 3) << 3);
  const unsigned short* Ag = A + (size_t)(m0 + rp) * K + cK;
  const unsigned short* Bg = Bt + (size_t)(n0 + rp) * K + cK;

  f32x4 acc[2][4];
  #pragma unroll
  for (int i = 0; i < 2; ++i)
    #pragma unroll
    for (int n = 0; n < 4; ++n) acc[i][n] = (f32x4){0.f, 0.f, 0.f, 0.f};

  #define STAGE(kt, c) { \
    size_t ko = (size_t)(kt) * 64; \
    unsigned short* dA = &lds[(c)][0][0] + w * 512; \
    unsigned short* dB = &lds[(c)][1][0] + w * 512; \
    gl16(Ag + ko,                 dA);        \
    gl16(Ag + (size_t)64*K + ko,  dA + 4096); \
    gl16(Bg + ko,                 dB);        \
    gl16(Bg + (size_t)64*K + ko,  dB + 4096); \
  }

  STAGE(0, 0);
  STAGE(1, 1);
  asm volatile("s_waitcnt vmcnt(4)" ::: "memory");
  __builtin_amdgcn_s_barrier();

  for (int t = 0; t < NT; ++t) {
    int cur = t & 1;
    const unsigned short* La = &lds[cur][0][0];
    const unsigned short* Lb = &lds[cur][1][0];
    short8 a0[2], b0[4], a1[2], b1[4];
    #pragma unroll
    for (int i = 0; i < 2; ++i)
      a0[i] = *(const short8*)&La[(wm*32 + i*16 + al)*64 + ((ag*8) ^ swz)];
    #pragma unroll
    for (int n = 0; n < 4; ++n)
      b0[n] = *(const short8*)&Lb[(wn*64 + n*16 + al)*64 + ((ag*8) ^ swz)];
    #pragma unroll
    for (int i = 0; i < 2; ++i)
      a1[i] = *(const short8*)&La[(wm*32 + i*16 + al)*64 + ((32 + ag*8) ^ swz)];
    #pragma unroll
    for (int n = 0; n < 4; ++n)
      b1[n] = *(const short8*)&Lb[(wn*64 + n*16 + al)*64 + ((32 + ag*8) ^ swz)];
    asm volatile("s_waitcnt lgkmcnt(6)" ::: "memory");
    __builtin_amdgcn_sched_barrier(0);
    #pragma unroll
    for (int i = 0; i < 2; ++i)
      #pragma unroll
      for (int n = 0; n < 4; ++n)
        acc[i][n] = __builtin_amdgcn_mfma_f32_16x16x32_bf16(a0[i], b0[n], acc[i][n], 0, 0, 0);
    asm volatile("s_waitcnt lgkmcnt(0)" ::: "memory");
    __builtin_amdgcn_sched_barrier(0);
    __builtin_amdgcn_s_barrier();
    if (t + 2 < NT) STAGE(t + 2, cur);
    __builtin_amdgcn_s_setprio(1);
    #pragma unroll
    for (int i = 0; i < 2; ++i)
      #pragma unroll
      for (int n = 0; n < 4; ++n)
        acc[i][n] = __builtin_amdgcn_mfma_f32_16x16x32_bf16(a1[i], b1[n], acc[i][n], 0, 0, 0);
    __builtin_amdgcn_s_setprio(0);
    if (t + 2 < NT) { asm volatile("s_waitcnt vmcnt(4)" ::: "memory"); }
    else            { asm volatile("s_waitcnt vmcnt(0)" ::: "memory"); }
    __builtin_amdgcn_s_barrier();
  }
  #undef STAGE

  bool qk = (n0 + wn * 64) < 1024;
  if (qk) {
    #pragma unroll
    for (int i = 0; i < 2; ++i)
      #pragma unroll
      for (int r = 0; r < 4; ++r) {
        int pos = m0 + wm*32 + i*16 + ag*4 + r;
        unsigned short* Cr = C + (size_t)pos * N + n0 + wn*64 + al;
        #pragma unroll
        for (int n = 0; n < 2; ++n) {
          int d = n * 16 + al;                 // 0..31 within head
          float2 cs = rope_tab[pos * 32 + d];
          float x1 = acc[i][n][r], x2 = acc[i][n + 2][r];
          Cr[n * 16]       = f2b(x1 * cs.x - x2 * cs.y);
          Cr[(n + 2) * 16] = f2b(x2 * cs.x + x1 * cs.y);
        }
      }
  } else {
    // V: transpose 32pos x 64col quadrant through per-wave LDS scratch,
    // then 16B/lane coalesced stores along pos. Wave-private region: no barrier.
    unsigned short* scr = &lds[0][0][0] + w * 2048;   // 4KB per wave
    #pragma unroll
    for (int i = 0; i < 2; ++i)
      #pragma unroll
      for (int r = 0; r < 4; ++r) {
        int posl = i*16 + ag*4 + r;                   // 0..31
        #pragma unroll
        for (int n = 0; n < 4; ++n)
          scr[(n*16 + al) * 32 + posl] = f2b(acc[i][n][r]);
      }
    asm volatile("s_waitcnt lgkmcnt(0)" ::: "memory");
    int hb0 = n0 + wn * 64 - 1024;
    int pos0 = m0 + wm * 32;
    #pragma unroll
    for (int j = 0; j < 4; ++j) {
      int col = (lane >> 2) + j * 16;                 // 0..63
      int pc  = (lane & 3) * 8;                       // pos chunk
      uint4 v = *(const uint4*)&scr[col * 32 + pc];
      *(uint4*)&vT[(size_t)(hb0 + col) * TSEQ + pos0 + pc] = v;
    }
  }
}

// ---------------- MFMA flash attention chunk, causal, GQA, KV-split -----------
__global__ __launch_bounds__(256) void attn_chunk_kernel(
    const unsigned short* __restrict__ qkv, const unsigned short* __restrict__ vT,
    unsigned short* __restrict__ out, float* __restrict__ pO, float* __restrict__ pML) {
  __shared__ unsigned short Ks[2][64 * 64];
  __shared__ unsigned short Vt[2][64 * 64];
  __shared__ unsigned short Ps[4][16 * 64];
  int s = blockIdx.x, h = blockIdx.y;
  int qt, ci;
  if (s < 8)       { qt = s;                ci = 0; }
  else if (s < 24) { qt = 8 + ((s-8) >> 1); ci = (s-8) & 1; }
  else if (s < 48) { qt = 16 + (s-24) / 3;  ci = (s-24) % 3; }
  else             { qt = 24 + ((s-48) >> 2); ci = (s-48) & 3; }
  int nt = qt + 1;
  int t0 = ci * 8;
  int t1 = t0 + 8; if (t1 > nt) t1 = nt;
  int cnt = (nt + 7) >> 3;
  int r0 = qt * 64;
  int kvh = h / 3;           // N_REP = 3
  int t = threadIdx.x;
  int lane = t & 63, w = t >> 6;
  int l16 = lane & 15, g = lane >> 4;

  int qr = r0 + w * 16 + l16;
  const unsigned short* qrow = qkv + (size_t)qr * QKVN + h * HD;
  short8 aq0 = *(const short8*)(qrow + 8 * g);
  short8 aq1 = *(const short8*)(qrow + 32 + 8 * g);

  int sw = (lane & 7) ^ (lane >> 3);
  int rloc = w * 16 + (lane >> 3);
  const unsigned short* kgb = qkv + (size_t)rloc * QKVN + DM + kvh * HD + 8 * sw;
  const unsigned short* vgb = vT + (size_t)(kvh * 64 + rloc) * TSEQ + 8 * sw;

  #define ASTAGE(kb, c) { \
    unsigned short* kd = &Ks[(c)][0] + w * 1024; \
    unsigned short* vd = &Vt[(c)][0] + w * 1024; \
    gl16(kgb + (size_t)(kb) * QKVN,       kd);       \
    gl16(kgb + (size_t)((kb) + 8) * QKVN, kd + 512); \
    gl16(vgb + (kb),                      vd);       \
    gl16(vgb + (size_t)8 * TSEQ + (kb),   vd + 512); \
  }

  f32x4 o_acc[4];
  float mrun[4], lsum[4];
  #pragma unroll
  for (int i = 0; i < 4; ++i) { o_acc[i] = (f32x4){0.f,0.f,0.f,0.f}; mrun[i] = -1e30f; lsum[i] = 0.f; }

  ASTAGE(t0 * 64, 0);
  for (int kt = t0; kt < t1; ++kt) {
    int cur = (kt - t0) & 1;
    int kb = kt * 64;
    if (kt + 1 < t1) {
      ASTAGE((kt + 1) * 64, cur ^ 1);                     // prefetch next tile
      asm volatile("s_waitcnt vmcnt(4)" ::: "memory");    // current tile's 4 done
    } else {
      asm volatile("s_waitcnt vmcnt(0)" ::: "memory");
    }
    __builtin_amdgcn_s_barrier();

    const unsigned short* Kc = &Ks[cur][0];
    const unsigned short* Vc = &Vt[cur][0];

    f32x4 s_acc[4];
    #pragma unroll
    for (int nb = 0; nb < 4; ++nb) s_acc[nb] = (f32x4){0.f,0.f,0.f,0.f};
    #pragma unroll
    for (int nb = 0; nb < 4; ++nb) {
      int key = nb * 16 + l16;
      short8 bk0 = *(const short8*)&Kc[key * 64 + ((g       ^ (key & 7)) << 3)];
      short8 bk1 = *(const short8*)&Kc[key * 64 + (((4 + g) ^ (key & 7)) << 3)];
      s_acc[nb] = __builtin_amdgcn_mfma_f32_16x16x32_bf16(aq0, bk0, s_acc[nb], 0, 0, 0);
      s_acc[nb] = __builtin_amdgcn_mfma_f32_16x16x32_bf16(aq1, bk1, s_acc[nb], 0, 0, 0);
    }

    bool diag = (kt == qt);
    #pragma unroll
    for (int r = 0; r < 4; ++r) {
      int qg = r0 + w * 16 + g * 4 + r;
      float sv[4];
      #pragma unroll
      for (int nb = 0; nb < 4; ++nb) {
        sv[nb] = s_acc[nb][r] * 0.125f;
        if (diag && (kb + nb * 16 + l16 > qg)) sv[nb] = -1e30f;
      }
      float mx = fmaxf(fmaxf(sv[0], sv[1]), fmaxf(sv[2], sv[3]));
      mx = fmaxf(mx, __shfl_xor(mx, 1));
      mx = fmaxf(mx, __shfl_xor(mx, 2));
      mx = fmaxf(mx, __shfl_xor(mx, 4));
      mx = fmaxf(mx, __shfl_xor(mx, 8));
      if (mx > mrun[r] + 8.0f) {
        float es = __expf(mrun[r] - mx);
        lsum[r] *= es;
        #pragma unroll
        for (int db = 0; db < 4; ++db) o_acc[db][r] *= es;
        mrun[r] = mx;
      }
      float rsum = 0.f;
      #pragma unroll
      for (int nb = 0; nb < 4; ++nb) { sv[nb] = __expf(sv[nb] - mrun[r]); rsum += sv[nb]; }
      lsum[r] += rsum;
      int qloc = g * 4 + r, q7 = qloc & 7;
      #pragma unroll
      for (int nb = 0; nb < 4; ++nb) {
        int key = nb * 16 + l16;
        Ps[w][qloc * 64 + ((((key >> 3) ^ q7) << 3) + (key & 7))] = f2b(sv[nb]);
      }
    }

    #pragma unroll
    for (int kc = 0; kc < 2; ++kc) {
      short8 pa = *(const short8*)&Ps[w][l16 * 64 + (((4 * kc + g) ^ (l16 & 7)) << 3)];
      #pragma unroll
      for (int db = 0; db < 4; ++db) {
        int d = db * 16 + l16;
        short8 bv = *(const short8*)&Vc[d * 64 + (((4 * kc + g) ^ (d & 7)) << 3)];
        o_acc[db] = __builtin_amdgcn_mfma_f32_16x16x32_bf16(pa, bv, o_acc[db], 0, 0, 0);
      }
    }
    __builtin_amdgcn_s_barrier();
  }
  #undef ASTAGE

  if (cnt == 1) {
    #pragma unroll
    for (int r = 0; r < 4; ++r) {
      int qg = r0 + w * 16 + g * 4 + r;
      float sr = lsum[r];
      sr += __shfl_xor(sr, 1);
      sr += __shfl_xor(sr, 2);
      sr += __shfl_xor(sr, 4);
      sr += __shfl_xor(sr, 8);
      float inv = 1.0f / sr;
      unsigned short* orow = out + (size_t)qg * DM + h * HD + l16;
      #pragma unroll
      for (int db = 0; db < 4; ++db) orow[db * 16] = f2b(o_acc[db][r] * inv);
    }
  } else {
    size_t slotg = (size_t)h * 80 + s;
    float* po = pO + slotg * 4096;
    float* pm = pML + slotg * 128;
    #pragma unroll
    for (int r = 0; r < 4; ++r) {
      int row = w * 16 + g * 4 + r;
      float sr = lsum[r];
      sr += __shfl_xor(sr, 1);
      sr += __shfl_xor(sr, 2);
      sr += __shfl_xor(sr, 4);
      sr += __shfl_xor(sr, 8);
      #pragma unroll
      for (int db = 0; db < 4; ++db) po[row * 64 + db * 16 + l16] = o_acc[db][r];
      if (l16 == 0) { pm[row * 2] = mrun[r]; pm[row * 2 + 1] = sr; }
    }
  }
}

// ---------------- combine partials for qt >= 8 ----------------
__global__ __launch_bounds__(256) void attn_combine_kernel(
    const float* __restrict__ pO, const float* __restrict__ pML,
    unsigned short* __restrict__ out) {
  int h = blockIdx.y;
  int qt = 8 + blockIdx.x;            // 8..31
  int base, cnt;
  if (qt < 16)      { base = 8 + (qt - 8) * 2;  cnt = 2; }
  else if (qt < 24) { base = 24 + (qt - 16) * 3; cnt = 3; }
  else              { base = 48 + (qt - 24) * 4; cnt = 4; }
  int t = threadIdx.x;
  int row = t >> 2, d0 = (t & 3) * 16;
  float m[4], l[4];
  float M = -1e30f;
  for (int c = 0; c < cnt; ++c) {
    const float* pm = pML + ((size_t)h * 80 + base + c) * 128 + row * 2;
    m[c] = pm[0]; l[c] = pm[1];
    M = fmaxf(M, m[c]);
  }
  float o[16];
  #pragma unroll
  for (int j = 0; j < 16; ++j) o[j] = 0.f;
  float wl = 0.f;
  for (int c = 0; c < cnt; ++c) {
    float wc = __expf(m[c] - M);
    wl += wc * l[c];
    const float4* po = (const float4*)(pO + ((size_t)h * 80 + base + c) * 4096 + row * 64 + d0);
    #pragma unroll
    for (int q = 0; q < 4; ++q) {
      float4 v = po[q];
      o[q*4+0] += wc * v.x; o[q*4+1] += wc * v.y;
      o[q*4+2] += wc * v.z; o[q*4+3] += wc * v.w;
    }
  }
  float inv = 1.0f / wl;
  unsigned short* orow = out + (size_t)(qt * 64 + row) * DM + h * HD + d0;
  uint4 s0, s1;
  s0.x = packbf(o[0]*inv,  o[1]*inv);  s0.y = packbf(o[2]*inv,  o[3]*inv);
  s0.z = packbf(o[4]*inv,  o[5]*inv);  s0.w = packbf(o[6]*inv,  o[7]*inv);
  s1.x = packbf(o[8]*inv,  o[9]*inv);  s1.y = packbf(o[10]*inv, o[11]*inv);
  s1.z = packbf(o[12]*inv, o[13]*inv); s1.w = packbf(o[14]*inv, o[15]*inv);
  ((uint4*)orow)[0] = s0; ((uint4*)orow)[1] = s1;
}

extern "C" void kernel_launch(void* const* d_in, const int* in_sizes, int n_in,
                              void* d_out, int out_size, void* d_ws, size_t ws_size,
                              hipStream_t stream) {
  const int*   idx   = (const int*)d_in[0];
  const float* embed = (const float*)d_in[1];
  const float* ln1   = (const float*)d_in[2];
  const float* Wq    = (const float*)d_in[3];
  const float* Wk    = (const float*)d_in[4];
  const float* Wv    = (const float*)d_in[5];
  const float* Wo    = (const float*)d_in[6];
  const float* ln2   = (const float*)d_in[7];
  const float* Wg    = (const float*)d_in[8];
  const float* Wu    = (const float*)d_in[9];
  const float* Wd    = (const float*)d_in[10];
  const float* normf = (const float*)d_in[11];
  float* out = (float*)d_out;
  char* ws = (char*)d_ws;
  (void)in_sizes; (void)n_in; (void)out_size; (void)ws_size;

  // ---- workspace layout ----
  unsigned short* embed_bf = (unsigned short*)ws;
  size_t off = (size_t)VOC * DM * 2;
  unsigned short* wts = (unsigned short*)(ws + off);
  const size_t LW = (size_t)QKVN * DM + (size_t)DM * DM
                  + 2ull * FFD * DM + (size_t)DM * FFD;
  off += LW * 2ull * NL;
  float* xf = (float*)(ws + off);            off += (size_t)TSEQ * DM * 4;
  unsigned short* h_bf = (unsigned short*)(ws + off);    off += (size_t)TSEQ * DM * 2;
  unsigned short* qkv_bf = (unsigned short*)(ws + off);  off += (size_t)TSEQ * QKVN * 2;
  unsigned short* attn_bf = (unsigned short*)(ws + off); off += (size_t)TSEQ * DM * 2;
  // pO (attn partials) overlays m_bf: disjoint lifetimes (attn->combine vs gu8->wd)
  float* pO = (float*)(ws + off);
  unsigned short* m_bf = (unsigned short*)(ws + off);
  off += (size_t)NH * 80 * 4096 * 4;
  float* pML = (float*)(ws + off);           off += (size_t)NH * 80 * 128 * 4;
  float2* rope_tab = (float2*)(ws + off);    off += (size_t)TSEQ * 32 * 8;
  unsigned short* vT = (unsigned short*)(ws + off);      off += (size_t)NKV * HD * TSEQ * 2;

  // ---- prep: one mega kernel (cast | rope table | gather | transposes) ----
  mega_prep_kernel<<<26304 + 6144 * NL, 256, 0, stream>>>(
      embed, embed_bf, rope_tab, idx, xf, Wq, Wk, Wv, Wo, Wg, Wu, Wd, wts, LW);

  for (int l = 0; l < NL; ++l) {
    unsigned short* base = wts + (size_t)l * LW;
    unsigned short* qkvT = base;
    unsigned short* woT  = base + (size_t)QKVN * DM;
    unsigned short* wguT = woT + (size_t)DM * DM;
    unsigned short* wdT  = wguT + 2ull * FFD * DM;

    rmsnorm_kernel<<<TSEQ, 256, 0, stream>>>(xf, ln1 + (size_t)l * DM, h_bf);
    gemm_qkv8_kernel<<<(QKVN / 128) * 16, 512, 0, stream>>>(h_bf, qkvT, qkv_bf, vT, rope_tab);
    attn_chunk_kernel<<<dim3(80, NH), 256, 0, stream>>>(qkv_bf, vT, attn_bf, pO, pML);
    attn_combine_kernel<<<dim3(24, NH), 256, 0, stream>>>(pO, pML, attn_bf);
    gemm_p8_kernel<<<dim3((DM / 128) * 16, 3), 512, 0, stream>>>(attn_bf, woT, xf, DM, DM, 256);
    rmsnorm_kernel<<<TSEQ, 256, 0, stream>>>(xf, ln2 + (size_t)l * DM, h_bf);
    gemm_gu8_kernel<<<(FFD / 128) * 16, 512, 0, stream>>>(h_bf, wguT, wguT + (size_t)FFD * DM, m_bf);
    gemm_p8_kernel<<<dim3((DM / 128) * 16, 4), 512, 0, stream>>>(m_bf, wdT, xf, DM, FFD, 512);
  }

  rmsnorm_kernel<<<TSEQ, 256, 0, stream>>>(xf, normf, h_bf);
  gemm_l8_kernel<<<(VOC / 256) * (TSEQ / 256), 512, 0, stream>>>(h_bf, embed_bf, out, VOC, DM);
}